// Round 8
// baseline (1733.416 us; speedup 1.0000x reference)
//
#include <hip/hip_runtime.h>

#define GRID 64
#define NVOX (GRID*GRID*GRID)
#define NCLS 20
#define NSEED 512

// ---------------- weight transposes, one launch ----------------
// w1t[(nb*6+ci)*64+oc] = w1[oc][ci][nb];  w2t[(nb*64+ci)*32+oc] = w2[oc][ci][nb]
__global__ void transpose_all(const float* __restrict__ w1, float* __restrict__ w1t,
                              const float* __restrict__ w2, float* __restrict__ w2t) {
    int t = blockIdx.x * 256 + threadIdx.x;
    if (t < 27 * 6 * 64) {
        int oc = t & 63;
        int r  = t >> 6;            // nb*6 + ci
        int nb = r / 6, ci = r % 6;
        w1t[t] = w1[oc * 162 + ci * 27 + nb];
        return;
    }
    t -= 27 * 6 * 64;
    if (t < 27 * 64 * 32) {
        int oc = t & 31;
        int r  = t >> 5;            // nb*64 + ci
        int nb = r >> 6, ci = r & 63;
        w2t[t] = w2[oc * 1728 + ci * 27 + nb];
    }
}

// ------- conv1 (6->64): Zd=8, og=8-of-64, all-tap LDS weights, cross-ci prefetch -------
// grid 1024 = 8 zg (XCD) x 8 og x 16 yt; og varies fastest.
__global__ __launch_bounds__(256, 4) void conv1_kernel(
    const float* __restrict__ feat,   // [6][NVOX]
    const float* __restrict__ w1t,    // [(nb*6+ci)][64]
    const float* __restrict__ b1,
    float* __restrict__ h1p)          // [32][NVOX][2] channel-pair-major
{
    __shared__ float lw[27 * 6 * 8];  // this og's weights, all taps: 5184 B

    int tid = threadIdx.x;
    int B = blockIdx.x;
    int zg = B & 7;
    int k  = B >> 3;                  // 0..127
    int og = k & 7;                   // oc group of 8 (fastest)
    int yt = k >> 3;                  // 0..15

    for (int t = tid; t < 27 * 6 * 8; t += 256)
        lw[t] = w1t[(t >> 3) * 64 + og * 8 + (t & 7)];
    __syncthreads();                  // the only barrier

    int x  = tid & 63;
    int y  = yt * 4 + (tid >> 6);     // wave-uniform
    int z0 = zg * 8;

    float acc[8][8];
    #pragma unroll
    for (int r = 0; r < 8; ++r)
        #pragma unroll
        for (int o = 0; o < 8; ++o) acc[r][o] = 0.f;

    int zoffv[10]; float mzv[10];
    #pragma unroll
    for (int rz = 0; rz < 10; ++rz) {
        int gz = z0 - 1 + rz;
        int cz = gz < 0 ? 0 : (gz > 63 ? 63 : gz);
        zoffv[rz] = cz * 4096;
        mzv[rz] = ((unsigned)gz < 64u) ? 1.f : 0.f;
    }

#define C1_COMPUTE(VBUF, CI)                                                     \
    {                                                                            \
        _Pragma("unroll")                                                        \
        for (int rz = 0; rz < 10; ++rz) VBUF[rz] *= cm[rz];                      \
        _Pragma("unroll")                                                        \
        for (int dzi = 0; dzi < 3; ++dzi) {                                      \
            const float4* wp = reinterpret_cast<const float4*>(                  \
                &lw[(((dzi * 9 + dydx) * 6) + (CI)) * 8]);                       \
            float4 w0 = wp[0], w1 = wp[1];                                       \
            _Pragma("unroll")                                                    \
            for (int r = 0; r < 8; ++r) {                                        \
                float a = VBUF[r + dzi];                                         \
                acc[r][0] = fmaf(a, w0.x, acc[r][0]);                            \
                acc[r][1] = fmaf(a, w0.y, acc[r][1]);                            \
                acc[r][2] = fmaf(a, w0.z, acc[r][2]);                            \
                acc[r][3] = fmaf(a, w0.w, acc[r][3]);                            \
                acc[r][4] = fmaf(a, w1.x, acc[r][4]);                            \
                acc[r][5] = fmaf(a, w1.y, acc[r][5]);                            \
                acc[r][6] = fmaf(a, w1.z, acc[r][6]);                            \
                acc[r][7] = fmaf(a, w1.w, acc[r][7]);                            \
            }                                                                    \
        }                                                                        \
    }

    #pragma unroll 1
    for (int dydx = 0; dydx < 9; ++dydx) {
        int dy = dydx / 3 - 1;
        int dx = dydx % 3 - 1;
        int ny = y + dy;
        if ((unsigned)ny >= 64u) continue;             // wave-uniform zero-pad skip
        int nx = x + dx;
        float mx = ((unsigned)nx < 64u) ? 1.f : 0.f;
        int cx = nx < 0 ? 0 : (nx > 63 ? 63 : nx);
        int rowvox = ny * 64 + cx;

        float cm[10]; int voff[10];
        #pragma unroll
        for (int rz = 0; rz < 10; ++rz) { cm[rz] = mx * mzv[rz]; voff[rz] = zoffv[rz] + rowvox; }

        float va[10], vb[10];
        #pragma unroll
        for (int rz = 0; rz < 10; ++rz) va[rz] = feat[voff[rz]];   // ci=0

        #pragma unroll 1
        for (int ci = 0; ci < 6; ci += 2) {
            {   // prefetch ci+1
                const float* pb = feat + (size_t)(ci + 1) * NVOX;
                #pragma unroll
                for (int rz = 0; rz < 10; ++rz) vb[rz] = pb[voff[rz]];
            }
            C1_COMPUTE(va, ci)
            if (ci + 2 < 6) {                          // prefetch ci+2
                const float* pa = feat + (size_t)(ci + 2) * NVOX;
                #pragma unroll
                for (int rz = 0; rz < 10; ++rz) va[rz] = pa[voff[rz]];
            }
            C1_COMPUTE(vb, (ci + 1))
        }
    }
#undef C1_COMPUTE

    float bias[8];
    #pragma unroll
    for (int o = 0; o < 8; ++o) bias[o] = b1[og * 8 + o];
    // oc = og*8+o -> pair planes p = og*4 + q (q=0..3)
    #pragma unroll
    for (int zl = 0; zl < 8; ++zl) {
        int vox = ((z0 + zl) * 64 + y) * 64 + x;
        #pragma unroll
        for (int q = 0; q < 4; ++q) {
            float2 s = make_float2(fmaxf(acc[zl][2*q]   + bias[2*q],   0.f),
                                   fmaxf(acc[zl][2*q+1] + bias[2*q+1], 0.f));
            *reinterpret_cast<float2*>(h1p + ((size_t)(og * 4 + q) * NVOX + vox) * 2) = s;
        }
    }
}

// ------- conv2 (64->32): Zd=8, oc=4, all-tap LDS weights, cross-cq prefetch -------
// grid 1024 = 8 zg (XCD) x 8 og x 16 yt; og varies fastest -> data-sharers launch-adjacent.
__global__ __launch_bounds__(256, 4) void conv2_kernel(
    const float* __restrict__ h1p,    // [32][NVOX][2]
    const float* __restrict__ w2t,    // [(nb*64+ci)][32]
    const float* __restrict__ b2,
    float* __restrict__ pf)           // [vox][32] post-relu
{
    __shared__ float lw[27 * 64 * 4];  // this og's weights, all taps: 27648 B

    int tid = threadIdx.x;
    int B = blockIdx.x;
    int zg = B & 7;
    int k  = B >> 3;                   // 0..127
    int og = k & 7;                    // oc group of 4 (fastest)
    int yt = k >> 3;                   // 0..15

    for (int t = tid; t < 27 * 64 * 4; t += 256)
        lw[t] = w2t[(t >> 2) * 32 + og * 4 + (t & 3)];
    __syncthreads();                   // the only barrier

    int x  = tid & 63;
    int y  = yt * 4 + (tid >> 6);      // wave-uniform
    int z0 = zg * 8;

    float acc[8][4];
    #pragma unroll
    for (int r = 0; r < 8; ++r)
        #pragma unroll
        for (int o = 0; o < 4; ++o) acc[r][o] = 0.f;

    int zoffv[10]; float mzv[10];
    #pragma unroll
    for (int rz = 0; rz < 10; ++rz) {
        int gz = z0 - 1 + rz;
        int cz = gz < 0 ? 0 : (gz > 63 ? 63 : gz);
        zoffv[rz] = cz * 4096;
        mzv[rz] = ((unsigned)gz < 64u) ? 1.f : 0.f;
    }

#define C2_COMPUTE(VBUF, CQ)                                                     \
    {                                                                            \
        _Pragma("unroll")                                                        \
        for (int rz = 0; rz < 10; ++rz) { VBUF[rz].x *= cm[rz]; VBUF[rz].y *= cm[rz]; } \
        _Pragma("unroll")                                                        \
        for (int dzi = 0; dzi < 3; ++dzi) {                                      \
            const float4* wp = reinterpret_cast<const float4*>(                  \
                &lw[(((dzi * 9 + dydx) * 64) + (CQ) * 2) * 4]);                  \
            float4 w0 = wp[0];                                                   \
            float4 w1 = wp[1];                                                   \
            _Pragma("unroll")                                                    \
            for (int r = 0; r < 8; ++r) {                                        \
                float2 a = VBUF[r + dzi];                                        \
                acc[r][0] = fmaf(a.x, w0.x, acc[r][0]);                          \
                acc[r][1] = fmaf(a.x, w0.y, acc[r][1]);                          \
                acc[r][2] = fmaf(a.x, w0.z, acc[r][2]);                          \
                acc[r][3] = fmaf(a.x, w0.w, acc[r][3]);                          \
                acc[r][0] = fmaf(a.y, w1.x, acc[r][0]);                          \
                acc[r][1] = fmaf(a.y, w1.y, acc[r][1]);                          \
                acc[r][2] = fmaf(a.y, w1.z, acc[r][2]);                          \
                acc[r][3] = fmaf(a.y, w1.w, acc[r][3]);                          \
            }                                                                    \
        }                                                                        \
    }

    #pragma unroll 1
    for (int dydx = 0; dydx < 9; ++dydx) {
        int dy = dydx / 3 - 1;
        int dx = dydx % 3 - 1;
        int ny = y + dy;
        if ((unsigned)ny >= 64u) continue;             // wave-uniform zero-pad skip
        int nx = x + dx;
        float mx = ((unsigned)nx < 64u) ? 1.f : 0.f;
        int cx = nx < 0 ? 0 : (nx > 63 ? 63 : nx);
        int rowvox = ny * 64 + cx;

        float cm[10]; int voff[10];
        #pragma unroll
        for (int rz = 0; rz < 10; ++rz) { cm[rz] = mx * mzv[rz]; voff[rz] = zoffv[rz] + rowvox; }

        float2 va[10], vb[10];
        #pragma unroll
        for (int rz = 0; rz < 10; ++rz)
            va[rz] = *reinterpret_cast<const float2*>(h1p + (size_t)voff[rz] * 2);   // cq=0

        #pragma unroll 1
        for (int cq = 0; cq < 32; cq += 2) {
            {   // prefetch cq+1
                const float* pb = h1p + (size_t)(cq + 1) * (NVOX * 2);
                #pragma unroll
                for (int rz = 0; rz < 10; ++rz)
                    vb[rz] = *reinterpret_cast<const float2*>(pb + (size_t)voff[rz] * 2);
            }
            C2_COMPUTE(va, cq)
            if (cq + 2 < 32) {                         // prefetch cq+2
                const float* pa = h1p + (size_t)(cq + 2) * (NVOX * 2);
                #pragma unroll
                for (int rz = 0; rz < 10; ++rz)
                    va[rz] = *reinterpret_cast<const float2*>(pa + (size_t)voff[rz] * 2);
            }
            C2_COMPUTE(vb, (cq + 1))
        }
    }
#undef C2_COMPUTE

    float bias[4];
    #pragma unroll
    for (int o = 0; o < 4; ++o) bias[o] = b2[og * 4 + o];
    #pragma unroll
    for (int zl = 0; zl < 8; ++zl) {
        int vox = ((z0 + zl) * 64 + y) * 64 + x;
        float4 s = make_float4(fmaxf(acc[zl][0] + bias[0], 0.f), fmaxf(acc[zl][1] + bias[1], 0.f),
                               fmaxf(acc[zl][2] + bias[2], 0.f), fmaxf(acc[zl][3] + bias[3], 0.f));
        *reinterpret_cast<float4*>(pf + (size_t)vox * 32 + og * 4) = s;
    }
}

// ------- epilogue: heads + argmax + argmin over seeds + mismatch scatter -------
__global__ __launch_bounds__(256) void epilogue_kernel(
    const float* __restrict__ pf,     // [vox][32] post-relu
    const float* __restrict__ points, // [N][3]
    const float* __restrict__ ann,    // [512][4]
    const float* __restrict__ sem_w, const float* __restrict__ sem_b,
    const float* __restrict__ off_w, const float* __restrict__ off_b,
    float* __restrict__ out_logits,   // [N][20]
    float* __restrict__ out_off,      // [N][3]
    int* __restrict__ iv_out,         // [N]
    int* __restrict__ bad_seed)       // [512]
{
    __shared__ float4 sseed[NSEED];
    for (int i = threadIdx.x; i < NSEED; i += 256) {
        float4 a = *reinterpret_cast<const float4*>(ann + i * 4);
        sseed[i] = make_float4(a.x, a.y, a.z, a.x*a.x + a.y*a.y + a.z*a.z);
    }
    __syncthreads();

    int vox = blockIdx.x * 256 + threadIdx.x;

    float f[32];
    #pragma unroll
    for (int q = 0; q < 8; ++q) {
        float4 v = *reinterpret_cast<const float4*>(pf + (size_t)vox * 32 + q * 4);
        f[q*4+0] = v.x; f[q*4+1] = v.y; f[q*4+2] = v.z; f[q*4+3] = v.w;
    }

    // semantic head + argmax (strict > = first occurrence)
    float best = -1e30f; int am = 0;
    #pragma unroll
    for (int cc = 0; cc < NCLS; ++cc) {
        float l = sem_b[cc];
        #pragma unroll
        for (int q = 0; q < 32; ++q) l = fmaf(f[q], sem_w[cc * 32 + q], l);
        out_logits[(size_t)vox * NCLS + cc] = l;
        if (l > best) { best = l; am = cc; }
    }

    // offset head
    float off[3];
    #pragma unroll
    for (int k3 = 0; k3 < 3; ++k3) {
        float l = off_b[k3];
        #pragma unroll
        for (int q = 0; q < 32; ++q) l = fmaf(f[q], off_w[k3 * 32 + q], l);
        out_off[(size_t)vox * 3 + k3] = l;
        off[k3] = l;
    }

    float px = points[(size_t)vox * 3 + 0] + off[0];
    float py = points[(size_t)vox * 3 + 1] + off[1];
    float pz = points[(size_t)vox * 3 + 2] + off[2];
    float pp = px * px + py * py + pz * pz;

    float bd2 = 1e30f; int bj = 0;
    #pragma unroll 4
    for (int j = 0; j < NSEED; ++j) {
        float4 s = sseed[j];                    // broadcast, conflict-free
        float dot = px * s.x + py * s.y + pz * s.z;
        float d2  = pp + s.w - 2.0f * dot;
        if (d2 < bd2) { bd2 = d2; bj = j; }     // strict < = first occurrence
    }
    float mind = sqrtf(fmaxf(bd2, 0.f));
    bool valid = mind < 1.5f;

    int slab = (int)ann[bj * 4 + 3];
    if (valid && am != slab) atomicOr(&bad_seed[bj], 1);
    iv_out[vox] = valid ? bj : -1;
}

// ---------------- finalize pseudo labels ----------------
__global__ void finalize_kernel(const int* __restrict__ iv,
                                const int* __restrict__ bad,
                                float* __restrict__ pl) {
    int t = blockIdx.x * 256 + threadIdx.x;
    if (t >= NVOX) return;
    int v = iv[t];
    float r = -1.0f;
    if (v >= 0 && bad[v] == 0) r = (float)v;
    pl[t] = r;
}

extern "C" void kernel_launch(void* const* d_in, const int* in_sizes, int n_in,
                              void* d_out, int out_size, void* d_ws, size_t ws_size,
                              hipStream_t stream) {
    const float* points   = (const float*)d_in[0];
    const float* features = (const float*)d_in[1];
    const float* ann      = (const float*)d_in[2];
    const float* w1       = (const float*)d_in[3];
    const float* b1       = (const float*)d_in[4];
    const float* w2       = (const float*)d_in[5];
    const float* b2       = (const float*)d_in[6];
    const float* sem_w    = (const float*)d_in[7];
    const float* sem_b    = (const float*)d_in[8];
    const float* off_w    = (const float*)d_in[9];
    const float* off_b    = (const float*)d_in[10];

    float* out        = (float*)d_out;
    float* out_logits = out;
    float* out_off    = out + (size_t)NVOX * NCLS;   // N*20
    float* out_pl     = out + (size_t)NVOX * 23;     // N*23

    // workspace layout (bytes, 256-aligned)
    char*  ws  = (char*)d_ws;
    float* w1t = (float*)(ws);                 //    41472 B
    float* w2t = (float*)(ws + 41472);         //   221184 B
    int*   bad = (int*)  (ws + 262656);        //     2048 B
    int*   iv  = (int*)  (ws + 264704);        //  1048576 B
    float* pf  = (float*)(ws + 1313280);       // 33554432 B
    float* h1p = (float*)(ws + 34867712);      // 67108864 B  (total ~97.3 MB)

    hipMemsetAsync(bad, 0, NSEED * sizeof(int), stream);
    transpose_all<<<257, 256, 0, stream>>>(w1, w1t, w2, w2t);
    conv1_kernel<<<1024, 256, 0, stream>>>(features, w1t, b1, h1p);
    conv2_kernel<<<1024, 256, 0, stream>>>(h1p, w2t, b2, pf);
    epilogue_kernel<<<1024, 256, 0, stream>>>(pf, points, ann,
        sem_w, sem_b, off_w, off_b, out_logits, out_off, iv, bad);
    finalize_kernel<<<1024, 256, 0, stream>>>(iv, bad, out_pl);
}

// Round 9
// 600.130 us; speedup vs baseline: 2.8884x; 2.8884x over previous
//
#include <hip/hip_runtime.h>

#define GRID 64
#define NVOX (GRID*GRID*GRID)
#define NCLS 20
#define NSEED 512

// ---------------- weight transposes, one launch ----------------
// w1t[(nb*6+ci)*64+oc] = w1[oc][ci][nb];  w2t[(nb*64+ci)*32+oc] = w2[oc][ci][nb]
__global__ void transpose_all(const float* __restrict__ w1, float* __restrict__ w1t,
                              const float* __restrict__ w2, float* __restrict__ w2t) {
    int t = blockIdx.x * 256 + threadIdx.x;
    if (t < 27 * 6 * 64) {
        int oc = t & 63;
        int r  = t >> 6;            // nb*6 + ci
        int nb = r / 6, ci = r % 6;
        w1t[t] = w1[oc * 162 + ci * 27 + nb];
        return;
    }
    t -= 27 * 6 * 64;
    if (t < 27 * 64 * 32) {
        int oc = t & 31;
        int r  = t >> 5;            // nb*64 + ci
        int nb = r >> 6, ci = r & 63;
        w2t[t] = w2[oc * 1728 + ci * 27 + nb];
    }
}

// ------- conv1 (6->64): Zd=4, oc=16, all-tap LDS weights (10.4KB) -------
// grid 1024 = 8 zg (XCD) x [og fastest(4) x zt(2) x yt(16)]
__global__ __launch_bounds__(256, 4) void conv1_kernel(
    const float* __restrict__ feat,   // [6][NVOX]
    const float* __restrict__ w1t,    // [(nb*6+ci)][64]
    const float* __restrict__ b1,
    float* __restrict__ h1p)          // [32][NVOX][2] channel-pair-major
{
    __shared__ float lw[27 * 6 * 16]; // 10368 B

    int tid = threadIdx.x;
    int B = blockIdx.x;
    int zg = B & 7;
    int k  = B >> 3;                  // 0..127
    int og = k & 3;                   // oc group of 16 (fastest)
    int zt = (k >> 2) & 1;
    int yt = (k >> 3) & 15;

    for (int t = tid; t < 27 * 6 * 16; t += 256)
        lw[t] = w1t[(t >> 4) * 64 + og * 16 + (t & 15)];
    __syncthreads();                  // the only barrier

    int x  = tid & 63;
    int y  = yt * 4 + (tid >> 6);     // wave-uniform
    int z0 = zg * 8 + zt * 4;

    float acc[4][16];
    #pragma unroll
    for (int r = 0; r < 4; ++r)
        #pragma unroll
        for (int o = 0; o < 16; ++o) acc[r][o] = 0.f;

    int zoffv[6]; float mzv[6];
    #pragma unroll
    for (int rz = 0; rz < 6; ++rz) {
        int gz = z0 - 1 + rz;
        int cz = gz < 0 ? 0 : (gz > 63 ? 63 : gz);
        zoffv[rz] = cz * 4096;
        mzv[rz] = ((unsigned)gz < 64u) ? 1.f : 0.f;
    }

    #pragma unroll 1
    for (int dydx = 0; dydx < 9; ++dydx) {
        int dy = dydx / 3 - 1;
        int dx = dydx % 3 - 1;
        int ny = y + dy;
        if ((unsigned)ny >= 64u) continue;             // wave-uniform zero-pad skip
        int nx = x + dx;
        float mx = ((unsigned)nx < 64u) ? 1.f : 0.f;
        int cx = nx < 0 ? 0 : (nx > 63 ? 63 : nx);
        int rowvox = ny * 64 + cx;

        float cm[6]; int voff[6];
        #pragma unroll
        for (int rz = 0; rz < 6; ++rz) { cm[rz] = mx * mzv[rz]; voff[rz] = zoffv[rz] + rowvox; }

        #pragma unroll 1
        for (int ci = 0; ci < 6; ++ci) {
            const float* plane = feat + (size_t)ci * NVOX;
            float v[6];
            #pragma unroll
            for (int rz = 0; rz < 6; ++rz) v[rz] = plane[voff[rz]] * cm[rz];
            #pragma unroll
            for (int dzi = 0; dzi < 3; ++dzi) {
                const float4* wp = reinterpret_cast<const float4*>(
                    &lw[(((dzi * 9 + dydx) * 6) + ci) * 16]);
                float4 w0 = wp[0], w1 = wp[1], w2 = wp[2], w3 = wp[3];
                #pragma unroll
                for (int r = 0; r < 4; ++r) {
                    float a = v[r + dzi];
                    acc[r][0]  = fmaf(a, w0.x, acc[r][0]);
                    acc[r][1]  = fmaf(a, w0.y, acc[r][1]);
                    acc[r][2]  = fmaf(a, w0.z, acc[r][2]);
                    acc[r][3]  = fmaf(a, w0.w, acc[r][3]);
                    acc[r][4]  = fmaf(a, w1.x, acc[r][4]);
                    acc[r][5]  = fmaf(a, w1.y, acc[r][5]);
                    acc[r][6]  = fmaf(a, w1.z, acc[r][6]);
                    acc[r][7]  = fmaf(a, w1.w, acc[r][7]);
                    acc[r][8]  = fmaf(a, w2.x, acc[r][8]);
                    acc[r][9]  = fmaf(a, w2.y, acc[r][9]);
                    acc[r][10] = fmaf(a, w2.z, acc[r][10]);
                    acc[r][11] = fmaf(a, w2.w, acc[r][11]);
                    acc[r][12] = fmaf(a, w3.x, acc[r][12]);
                    acc[r][13] = fmaf(a, w3.y, acc[r][13]);
                    acc[r][14] = fmaf(a, w3.z, acc[r][14]);
                    acc[r][15] = fmaf(a, w3.w, acc[r][15]);
                }
            }
        }
    }

    float bias[16];
    #pragma unroll
    for (int o = 0; o < 16; ++o) bias[o] = b1[og * 16 + o];
    // oc = og*16+o -> pair planes p = og*8 + q (q=0..7)
    #pragma unroll
    for (int zl = 0; zl < 4; ++zl) {
        int vox = ((z0 + zl) * 64 + y) * 64 + x;
        #pragma unroll
        for (int q = 0; q < 8; ++q) {
            float2 s = make_float2(fmaxf(acc[zl][2*q]   + bias[2*q],   0.f),
                                   fmaxf(acc[zl][2*q+1] + bias[2*q+1], 0.f));
            *reinterpret_cast<float2*>(h1p + ((size_t)(og * 8 + q) * NVOX + vox) * 2) = s;
        }
    }
}

// ------- conv2 (64->32): Zd=4, oc=8, 3-stage LDS weights (18KB, stage = fixed dy) -------
// grid 1024 = 8 zg (XCD) x [og fastest(4) x zt(2) x yt(16)]
__global__ __launch_bounds__(256, 4) void conv2_kernel(
    const float* __restrict__ h1p,    // [32][NVOX][2]
    const float* __restrict__ w2t,    // [(nb*64+ci)][32]
    const float* __restrict__ b2,
    float* __restrict__ pf)           // [vox][32] post-relu
{
    __shared__ float lw[9 * 64 * 8];  // stage tile: [(dl*3+dzi)*64+ci][8oc] = 18432 B

    int tid = threadIdx.x;
    int B = blockIdx.x;
    int zg = B & 7;
    int k  = B >> 3;                   // 0..127
    int og = k & 3;                    // oc group of 8 (fastest)
    int zt = (k >> 2) & 1;
    int yt = (k >> 3) & 15;

    int x  = tid & 63;
    int y  = yt * 4 + (tid >> 6);      // wave-uniform
    int z0 = zg * 8 + zt * 4;

    float acc[4][8];
    #pragma unroll
    for (int r = 0; r < 4; ++r)
        #pragma unroll
        for (int o = 0; o < 8; ++o) acc[r][o] = 0.f;

    int zoffv[6]; float mzv[6];
    #pragma unroll
    for (int rz = 0; rz < 6; ++rz) {
        int gz = z0 - 1 + rz;
        int cz = gz < 0 ? 0 : (gz > 63 ? 63 : gz);
        zoffv[rz] = cz * 4096;
        mzv[rz] = ((unsigned)gz < 64u) ? 1.f : 0.f;
    }

    #pragma unroll 1
    for (int s = 0; s < 3; ++s) {      // stage s <=> dy = s-1
        if (s > 0) __syncthreads();    // previous stage's readers done
        // load 9-tap weight slice: nb = dzi*9 + s*3 + dl
        for (int t = tid; t < 9 * 64 * 8; t += 256) {
            int o    = t & 7;
            int rest = t >> 3;         // 0..575
            int ci   = rest & 63;
            int tapl = rest >> 6;      // dl*3 + dzi
            int dl   = tapl / 3, dzi = tapl - dl * 3;
            int nb   = dzi * 9 + s * 3 + dl;
            lw[t] = w2t[(size_t)(nb * 64 + ci) * 32 + og * 8 + o];
        }
        __syncthreads();               // weights ready

        int ny = y + s - 1;
        if ((unsigned)ny >= 64u) continue;             // wave-uniform (only edge waves skip)

        #pragma unroll 1
        for (int dl = 0; dl < 3; ++dl) {
            int nx = x + dl - 1;
            float mx = ((unsigned)nx < 64u) ? 1.f : 0.f;
            int cx = nx < 0 ? 0 : (nx > 63 ? 63 : nx);
            int rowvox = ny * 64 + cx;

            float cm[6]; int voff[6];
            #pragma unroll
            for (int rz = 0; rz < 6; ++rz) { cm[rz] = mx * mzv[rz]; voff[rz] = zoffv[rz] + rowvox; }

            #pragma unroll 1
            for (int cq = 0; cq < 32; ++cq) {          // ci pairs
                const float* plane = h1p + (size_t)cq * (NVOX * 2);
                float2 v[6];
                #pragma unroll
                for (int rz = 0; rz < 6; ++rz) {
                    float2 t2 = *reinterpret_cast<const float2*>(plane + (size_t)voff[rz] * 2);
                    v[rz] = make_float2(t2.x * cm[rz], t2.y * cm[rz]);
                }
                #pragma unroll
                for (int dzi = 0; dzi < 3; ++dzi) {
                    const float4* wp = reinterpret_cast<const float4*>(
                        &lw[(((dl * 3 + dzi) * 64) + cq * 2) * 8]);
                    float4 w0 = wp[0], w1 = wp[1];     // ci0: oc0-3, oc4-7
                    float4 w2 = wp[2], w3 = wp[3];     // ci1: oc0-3, oc4-7
                    #pragma unroll
                    for (int r = 0; r < 4; ++r) {
                        float2 a = v[r + dzi];
                        acc[r][0] = fmaf(a.x, w0.x, acc[r][0]);
                        acc[r][1] = fmaf(a.x, w0.y, acc[r][1]);
                        acc[r][2] = fmaf(a.x, w0.z, acc[r][2]);
                        acc[r][3] = fmaf(a.x, w0.w, acc[r][3]);
                        acc[r][4] = fmaf(a.x, w1.x, acc[r][4]);
                        acc[r][5] = fmaf(a.x, w1.y, acc[r][5]);
                        acc[r][6] = fmaf(a.x, w1.z, acc[r][6]);
                        acc[r][7] = fmaf(a.x, w1.w, acc[r][7]);
                        acc[r][0] = fmaf(a.y, w2.x, acc[r][0]);
                        acc[r][1] = fmaf(a.y, w2.y, acc[r][1]);
                        acc[r][2] = fmaf(a.y, w2.z, acc[r][2]);
                        acc[r][3] = fmaf(a.y, w2.w, acc[r][3]);
                        acc[r][4] = fmaf(a.y, w3.x, acc[r][4]);
                        acc[r][5] = fmaf(a.y, w3.y, acc[r][5]);
                        acc[r][6] = fmaf(a.y, w3.z, acc[r][6]);
                        acc[r][7] = fmaf(a.y, w3.w, acc[r][7]);
                    }
                }
            }
        }
    }

    float bias[8];
    #pragma unroll
    for (int o = 0; o < 8; ++o) bias[o] = b2[og * 8 + o];
    #pragma unroll
    for (int zl = 0; zl < 4; ++zl) {
        int vox = ((z0 + zl) * 64 + y) * 64 + x;
        float* dst = pf + (size_t)vox * 32 + og * 8;
        float4 s0 = make_float4(fmaxf(acc[zl][0] + bias[0], 0.f), fmaxf(acc[zl][1] + bias[1], 0.f),
                                fmaxf(acc[zl][2] + bias[2], 0.f), fmaxf(acc[zl][3] + bias[3], 0.f));
        float4 s1 = make_float4(fmaxf(acc[zl][4] + bias[4], 0.f), fmaxf(acc[zl][5] + bias[5], 0.f),
                                fmaxf(acc[zl][6] + bias[6], 0.f), fmaxf(acc[zl][7] + bias[7], 0.f));
        *reinterpret_cast<float4*>(dst)     = s0;
        *reinterpret_cast<float4*>(dst + 4) = s1;
    }
}

// ------- epilogue: heads + argmax + argmin over seeds + mismatch scatter -------
__global__ __launch_bounds__(256) void epilogue_kernel(
    const float* __restrict__ pf,     // [vox][32] post-relu
    const float* __restrict__ points, // [N][3]
    const float* __restrict__ ann,    // [512][4]
    const float* __restrict__ sem_w, const float* __restrict__ sem_b,
    const float* __restrict__ off_w, const float* __restrict__ off_b,
    float* __restrict__ out_logits,   // [N][20]
    float* __restrict__ out_off,      // [N][3]
    int* __restrict__ iv_out,         // [N]
    int* __restrict__ bad_seed)       // [512]
{
    __shared__ float4 sseed[NSEED];
    for (int i = threadIdx.x; i < NSEED; i += 256) {
        float4 a = *reinterpret_cast<const float4*>(ann + i * 4);
        sseed[i] = make_float4(a.x, a.y, a.z, a.x*a.x + a.y*a.y + a.z*a.z);
    }
    __syncthreads();

    int vox = blockIdx.x * 256 + threadIdx.x;

    float f[32];
    #pragma unroll
    for (int q = 0; q < 8; ++q) {
        float4 v = *reinterpret_cast<const float4*>(pf + (size_t)vox * 32 + q * 4);
        f[q*4+0] = v.x; f[q*4+1] = v.y; f[q*4+2] = v.z; f[q*4+3] = v.w;
    }

    // semantic head + argmax (strict > = first occurrence)
    float best = -1e30f; int am = 0;
    #pragma unroll
    for (int cc = 0; cc < NCLS; ++cc) {
        float l = sem_b[cc];
        #pragma unroll
        for (int q = 0; q < 32; ++q) l = fmaf(f[q], sem_w[cc * 32 + q], l);
        out_logits[(size_t)vox * NCLS + cc] = l;
        if (l > best) { best = l; am = cc; }
    }

    // offset head
    float off[3];
    #pragma unroll
    for (int k3 = 0; k3 < 3; ++k3) {
        float l = off_b[k3];
        #pragma unroll
        for (int q = 0; q < 32; ++q) l = fmaf(f[q], off_w[k3 * 32 + q], l);
        out_off[(size_t)vox * 3 + k3] = l;
        off[k3] = l;
    }

    float px = points[(size_t)vox * 3 + 0] + off[0];
    float py = points[(size_t)vox * 3 + 1] + off[1];
    float pz = points[(size_t)vox * 3 + 2] + off[2];
    float pp = px * px + py * py + pz * pz;

    float bd2 = 1e30f; int bj = 0;
    #pragma unroll 4
    for (int j = 0; j < NSEED; ++j) {
        float4 s = sseed[j];                    // broadcast, conflict-free
        float dot = px * s.x + py * s.y + pz * s.z;
        float d2  = pp + s.w - 2.0f * dot;
        if (d2 < bd2) { bd2 = d2; bj = j; }     // strict < = first occurrence
    }
    float mind = sqrtf(fmaxf(bd2, 0.f));
    bool valid = mind < 1.5f;

    int slab = (int)ann[bj * 4 + 3];
    if (valid && am != slab) atomicOr(&bad_seed[bj], 1);
    iv_out[vox] = valid ? bj : -1;
}

// ---------------- finalize pseudo labels ----------------
__global__ void finalize_kernel(const int* __restrict__ iv,
                                const int* __restrict__ bad,
                                float* __restrict__ pl) {
    int t = blockIdx.x * 256 + threadIdx.x;
    if (t >= NVOX) return;
    int v = iv[t];
    float r = -1.0f;
    if (v >= 0 && bad[v] == 0) r = (float)v;
    pl[t] = r;
}

extern "C" void kernel_launch(void* const* d_in, const int* in_sizes, int n_in,
                              void* d_out, int out_size, void* d_ws, size_t ws_size,
                              hipStream_t stream) {
    const float* points   = (const float*)d_in[0];
    const float* features = (const float*)d_in[1];
    const float* ann      = (const float*)d_in[2];
    const float* w1       = (const float*)d_in[3];
    const float* b1       = (const float*)d_in[4];
    const float* w2       = (const float*)d_in[5];
    const float* b2       = (const float*)d_in[6];
    const float* sem_w    = (const float*)d_in[7];
    const float* sem_b    = (const float*)d_in[8];
    const float* off_w    = (const float*)d_in[9];
    const float* off_b    = (const float*)d_in[10];

    float* out        = (float*)d_out;
    float* out_logits = out;
    float* out_off    = out + (size_t)NVOX * NCLS;   // N*20
    float* out_pl     = out + (size_t)NVOX * 23;     // N*23

    // workspace layout (bytes, 256-aligned)
    char*  ws  = (char*)d_ws;
    float* w1t = (float*)(ws);                 //    41472 B
    float* w2t = (float*)(ws + 41472);         //   221184 B
    int*   bad = (int*)  (ws + 262656);        //     2048 B
    int*   iv  = (int*)  (ws + 264704);        //  1048576 B
    float* pf  = (float*)(ws + 1313280);       // 33554432 B
    float* h1p = (float*)(ws + 34867712);      // 67108864 B  (total ~97.3 MB)

    hipMemsetAsync(bad, 0, NSEED * sizeof(int), stream);
    transpose_all<<<257, 256, 0, stream>>>(w1, w1t, w2, w2t);
    conv1_kernel<<<1024, 256, 0, stream>>>(features, w1t, b1, h1p);
    conv2_kernel<<<1024, 256, 0, stream>>>(h1p, w2t, b2, pf);
    epilogue_kernel<<<1024, 256, 0, stream>>>(pf, points, ann,
        sem_w, sem_b, off_w, off_b, out_logits, out_off, iv, bad);
    finalize_kernel<<<1024, 256, 0, stream>>>(iv, bad, out_pl);
}

// Round 10
// 469.562 us; speedup vs baseline: 3.6916x; 1.2781x over previous
//
#include <hip/hip_runtime.h>

#define GRID 64
#define NVOX (GRID*GRID*GRID)
#define NCLS 20
#define NSEED 512

typedef __attribute__((ext_vector_type(8))) short short8_t;
typedef __attribute__((ext_vector_type(4))) float float4_t;

__device__ __forceinline__ unsigned short f32_to_bf16_rne(float f) {
    unsigned int x = __float_as_uint(f);
    unsigned int r = (x + 0x7fffu + ((x >> 16) & 1u)) >> 16;
    return (unsigned short)r;
}
__device__ __forceinline__ float bf16_to_f32(unsigned short u) {
    return __uint_as_float(((unsigned int)u) << 16);
}

// ---------------- w1 transpose: w1t[(nb*6+ci)*64+oc] = w1[oc][ci][nb] ----------------
__global__ void transpose_w1(const float* __restrict__ w1, float* __restrict__ w1t) {
    int t = blockIdx.x * 256 + threadIdx.x;
    if (t >= 27 * 6 * 64) return;
    int oc = t & 63;
    int r  = t >> 6;            // nb*6 + ci
    int nb = r / 6, ci = r % 6;
    w1t[t] = w1[oc * 162 + ci * 27 + nb];
}

// ------- build conv2 weight MFMA fragments (hi/lo bf16), 216 frags x 1KB -------
// frag f = ((nb*2+s)*2+t)*2+hl ; lane l elem j: B[ci=s*32+(l>>4)*8+j][oc=t*16+(l&15)]
__global__ void build_bfrags(const float* __restrict__ w2, unsigned short* __restrict__ bfr) {
    int t = blockIdx.x * 256 + threadIdx.x;      // over 216*64
    if (t >= 216 * 64) return;
    int l  = t & 63;
    int f  = t >> 6;
    int hl = f & 1;
    int tt = (f >> 1) & 1;
    int s  = (f >> 2) & 1;
    int nb = f >> 3;
    int lr = l & 15, lg = l >> 4;
    int oc = tt * 16 + lr;
    short8_t out;
    #pragma unroll
    for (int j = 0; j < 8; ++j) {
        int ci = s * 32 + lg * 8 + j;
        float wv = w2[oc * 1728 + ci * 27 + nb];
        unsigned short hi = f32_to_bf16_rne(wv);
        if (hl == 0) out[j] = (short)hi;
        else         out[j] = (short)f32_to_bf16_rne(wv - bf16_to_f32(hi));
    }
    *reinterpret_cast<short8_t*>(bfr + f * 512 + l * 8) = out;
}

// ------- conv1 (6->64): Zd=4, oc=16, all-tap LDS weights; emits hi/lo bf16 [vox][64] -------
__global__ __launch_bounds__(256, 4) void conv1_kernel(
    const float* __restrict__ feat,   // [6][NVOX]
    const float* __restrict__ w1t,    // [(nb*6+ci)][64]
    const float* __restrict__ b1,
    unsigned short* __restrict__ h1hi, // [vox][64] bf16 bits
    unsigned short* __restrict__ h1lo)
{
    __shared__ float lw[27 * 6 * 16]; // 10368 B

    int tid = threadIdx.x;
    int B = blockIdx.x;
    int zg = B & 7;
    int k  = B >> 3;
    int og = k & 3;                   // oc group of 16
    int zt = (k >> 2) & 1;
    int yt = (k >> 3) & 15;

    for (int t = tid; t < 27 * 6 * 16; t += 256)
        lw[t] = w1t[(t >> 4) * 64 + og * 16 + (t & 15)];
    __syncthreads();                  // the only barrier

    int x  = tid & 63;
    int y  = yt * 4 + (tid >> 6);     // wave-uniform
    int z0 = zg * 8 + zt * 4;

    float acc[4][16];
    #pragma unroll
    for (int r = 0; r < 4; ++r)
        #pragma unroll
        for (int o = 0; o < 16; ++o) acc[r][o] = 0.f;

    int zoffv[6]; float mzv[6];
    #pragma unroll
    for (int rz = 0; rz < 6; ++rz) {
        int gz = z0 - 1 + rz;
        int cz = gz < 0 ? 0 : (gz > 63 ? 63 : gz);
        zoffv[rz] = cz * 4096;
        mzv[rz] = ((unsigned)gz < 64u) ? 1.f : 0.f;
    }

    #pragma unroll 1
    for (int dydx = 0; dydx < 9; ++dydx) {
        int dy = dydx / 3 - 1;
        int dx = dydx % 3 - 1;
        int ny = y + dy;
        if ((unsigned)ny >= 64u) continue;             // wave-uniform zero-pad skip
        int nx = x + dx;
        float mx = ((unsigned)nx < 64u) ? 1.f : 0.f;
        int cx = nx < 0 ? 0 : (nx > 63 ? 63 : nx);
        int rowvox = ny * 64 + cx;

        float cm[6]; int voff[6];
        #pragma unroll
        for (int rz = 0; rz < 6; ++rz) { cm[rz] = mx * mzv[rz]; voff[rz] = zoffv[rz] + rowvox; }

        #pragma unroll 1
        for (int ci = 0; ci < 6; ++ci) {
            const float* plane = feat + (size_t)ci * NVOX;
            float v[6];
            #pragma unroll
            for (int rz = 0; rz < 6; ++rz) v[rz] = plane[voff[rz]] * cm[rz];
            #pragma unroll
            for (int dzi = 0; dzi < 3; ++dzi) {
                const float4* wp = reinterpret_cast<const float4*>(
                    &lw[(((dzi * 9 + dydx) * 6) + ci) * 16]);
                float4 w0 = wp[0], w1 = wp[1], w2 = wp[2], w3 = wp[3];
                #pragma unroll
                for (int r = 0; r < 4; ++r) {
                    float a = v[r + dzi];
                    acc[r][0]  = fmaf(a, w0.x, acc[r][0]);
                    acc[r][1]  = fmaf(a, w0.y, acc[r][1]);
                    acc[r][2]  = fmaf(a, w0.z, acc[r][2]);
                    acc[r][3]  = fmaf(a, w0.w, acc[r][3]);
                    acc[r][4]  = fmaf(a, w1.x, acc[r][4]);
                    acc[r][5]  = fmaf(a, w1.y, acc[r][5]);
                    acc[r][6]  = fmaf(a, w1.z, acc[r][6]);
                    acc[r][7]  = fmaf(a, w1.w, acc[r][7]);
                    acc[r][8]  = fmaf(a, w2.x, acc[r][8]);
                    acc[r][9]  = fmaf(a, w2.y, acc[r][9]);
                    acc[r][10] = fmaf(a, w2.z, acc[r][10]);
                    acc[r][11] = fmaf(a, w2.w, acc[r][11]);
                    acc[r][12] = fmaf(a, w3.x, acc[r][12]);
                    acc[r][13] = fmaf(a, w3.y, acc[r][13]);
                    acc[r][14] = fmaf(a, w3.z, acc[r][14]);
                    acc[r][15] = fmaf(a, w3.w, acc[r][15]);
                }
            }
        }
    }

    float bias[16];
    #pragma unroll
    for (int o = 0; o < 16; ++o) bias[o] = b1[og * 16 + o];

    #pragma unroll
    for (int zl = 0; zl < 4; ++zl) {
        int vox = ((z0 + zl) * 64 + y) * 64 + x;
        short8_t hi0, hi1, lo0, lo1;
        #pragma unroll
        for (int o = 0; o < 8; ++o) {
            float h = fmaxf(acc[zl][o] + bias[o], 0.f);
            unsigned short uh = f32_to_bf16_rne(h);
            hi0[o] = (short)uh;
            lo0[o] = (short)f32_to_bf16_rne(h - bf16_to_f32(uh));
        }
        #pragma unroll
        for (int o = 8; o < 16; ++o) {
            float h = fmaxf(acc[zl][o] + bias[o], 0.f);
            unsigned short uh = f32_to_bf16_rne(h);
            hi1[o - 8] = (short)uh;
            lo1[o - 8] = (short)f32_to_bf16_rne(h - bf16_to_f32(uh));
        }
        int base = vox * 64 + og * 16;
        *reinterpret_cast<short8_t*>(h1hi + base)     = hi0;
        *reinterpret_cast<short8_t*>(h1hi + base + 8) = hi1;
        *reinterpret_cast<short8_t*>(h1lo + base)     = lo0;
        *reinterpret_cast<short8_t*>(h1lo + base + 8) = lo1;
    }
}

// ------- conv2 (64->32) via MFMA split-bf16: wave = 32 vox x 32 oc, no LDS -------
// grid 2048 = 8 zg (XCD) x 8 zl x 32 yt. Block: 2 y-rows x 64 x; wave w: y=yt*2+(w&1), x0=(w>>1)*32.
__global__ __launch_bounds__(256) void conv2_mfma_kernel(
    const unsigned short* __restrict__ h1hi, // [vox][64] bf16
    const unsigned short* __restrict__ h1lo,
    const unsigned short* __restrict__ bfr,  // [27][2s][2t][2hl][64][8] bf16
    const float* __restrict__ b2,
    float* __restrict__ pf)                  // [vox][32] post-relu f32
{
    int tid = threadIdx.x;
    int w   = tid >> 6;
    int l   = tid & 63;
    int B   = blockIdx.x;
    int zg  = B & 7;
    int zl  = (B >> 3) & 7;
    int yt  = B >> 6;                 // 0..31
    int z   = zg * 8 + zl;
    int y   = yt * 2 + (w & 1);
    int x0  = (w >> 1) * 32;

    int lr = l & 15;                  // A-row lane / B-col lane
    int lg = l >> 4;                  // k-group

    const short8_t zero8 = (short8_t)0;
    float4_t acc[2][2];               // [voxtile][octile]
    #pragma unroll
    for (int a = 0; a < 2; ++a)
        #pragma unroll
        for (int b = 0; b < 2; ++b) acc[a][b] = (float4_t)0.f;

    #pragma unroll 1
    for (int nb = 0; nb < 27; ++nb) {
        int dz = nb / 9 - 1;
        int rem = nb % 9;
        int dy = rem / 3 - 1, dx = rem % 3 - 1;
        int nz = z + dz; if ((unsigned)nz >= 64u) continue;   // wave-uniform (zero pad)
        int ny = y + dy; if ((unsigned)ny >= 64u) continue;   // wave-uniform
        int rowv = (nz * 64 + ny) * 64;

        int xl0 = x0 + lr + dx;
        int xl1 = xl0 + 16;
        bool ok0 = (unsigned)xl0 < 64u;
        bool ok1 = (unsigned)xl1 < 64u;
        int cx0 = xl0 < 0 ? 0 : (xl0 > 63 ? 63 : xl0);
        int cx1 = xl1 < 0 ? 0 : (xl1 > 63 ? 63 : xl1);
        int base0 = (rowv + cx0) * 64 + lg * 8;
        int base1 = (rowv + cx1) * 64 + lg * 8;

        const unsigned short* bt = bfr + nb * 4096 + l * 8;
        #pragma unroll
        for (int s = 0; s < 2; ++s) {
            const unsigned short* bs = bt + s * 2048;
            short8_t bh0 = *reinterpret_cast<const short8_t*>(bs);          // t0 hi
            short8_t bl0 = *reinterpret_cast<const short8_t*>(bs + 512);    // t0 lo
            short8_t bh1 = *reinterpret_cast<const short8_t*>(bs + 1024);   // t1 hi
            short8_t bl1 = *reinterpret_cast<const short8_t*>(bs + 1536);   // t1 lo

            short8_t ah0 = ok0 ? *reinterpret_cast<const short8_t*>(h1hi + base0 + s * 32) : zero8;
            short8_t al0 = ok0 ? *reinterpret_cast<const short8_t*>(h1lo + base0 + s * 32) : zero8;
            acc[0][0] = __builtin_amdgcn_mfma_f32_16x16x32_bf16(ah0, bh0, acc[0][0], 0, 0, 0);
            acc[0][0] = __builtin_amdgcn_mfma_f32_16x16x32_bf16(al0, bh0, acc[0][0], 0, 0, 0);
            acc[0][0] = __builtin_amdgcn_mfma_f32_16x16x32_bf16(ah0, bl0, acc[0][0], 0, 0, 0);
            acc[0][1] = __builtin_amdgcn_mfma_f32_16x16x32_bf16(ah0, bh1, acc[0][1], 0, 0, 0);
            acc[0][1] = __builtin_amdgcn_mfma_f32_16x16x32_bf16(al0, bh1, acc[0][1], 0, 0, 0);
            acc[0][1] = __builtin_amdgcn_mfma_f32_16x16x32_bf16(ah0, bl1, acc[0][1], 0, 0, 0);

            short8_t ah1 = ok1 ? *reinterpret_cast<const short8_t*>(h1hi + base1 + s * 32) : zero8;
            short8_t al1 = ok1 ? *reinterpret_cast<const short8_t*>(h1lo + base1 + s * 32) : zero8;
            acc[1][0] = __builtin_amdgcn_mfma_f32_16x16x32_bf16(ah1, bh0, acc[1][0], 0, 0, 0);
            acc[1][0] = __builtin_amdgcn_mfma_f32_16x16x32_bf16(al1, bh0, acc[1][0], 0, 0, 0);
            acc[1][0] = __builtin_amdgcn_mfma_f32_16x16x32_bf16(ah1, bl0, acc[1][0], 0, 0, 0);
            acc[1][1] = __builtin_amdgcn_mfma_f32_16x16x32_bf16(ah1, bh1, acc[1][1], 0, 0, 0);
            acc[1][1] = __builtin_amdgcn_mfma_f32_16x16x32_bf16(al1, bh1, acc[1][1], 0, 0, 0);
            acc[1][1] = __builtin_amdgcn_mfma_f32_16x16x32_bf16(ah1, bl1, acc[1][1], 0, 0, 0);
        }
    }

    // bias + relu + store: D row (vox) = lg*4+r, col (oc) = lr
    int vbase = (z * 64 + y) * 64 + x0;
    #pragma unroll
    for (int vt = 0; vt < 2; ++vt) {
        #pragma unroll
        for (int t = 0; t < 2; ++t) {
            float bias = b2[t * 16 + lr];
            #pragma unroll
            for (int r = 0; r < 4; ++r) {
                int xv = vbase + vt * 16 + lg * 4 + r;
                pf[(size_t)xv * 32 + t * 16 + lr] = fmaxf(acc[vt][t][r] + bias, 0.f);
            }
        }
    }
}

// ------- epilogue: heads + argmax + argmin over seeds + mismatch scatter -------
__global__ __launch_bounds__(256) void epilogue_kernel(
    const float* __restrict__ pf,     // [vox][32] post-relu
    const float* __restrict__ points, // [N][3]
    const float* __restrict__ ann,    // [512][4]
    const float* __restrict__ sem_w, const float* __restrict__ sem_b,
    const float* __restrict__ off_w, const float* __restrict__ off_b,
    float* __restrict__ out_logits,   // [N][20]
    float* __restrict__ out_off,      // [N][3]
    int* __restrict__ iv_out,         // [N]
    int* __restrict__ bad_seed)       // [512]
{
    __shared__ float4 sseed[NSEED];
    for (int i = threadIdx.x; i < NSEED; i += 256) {
        float4 a = *reinterpret_cast<const float4*>(ann + i * 4);
        sseed[i] = make_float4(a.x, a.y, a.z, a.x*a.x + a.y*a.y + a.z*a.z);
    }
    __syncthreads();

    int vox = blockIdx.x * 256 + threadIdx.x;

    float f[32];
    #pragma unroll
    for (int q = 0; q < 8; ++q) {
        float4 v = *reinterpret_cast<const float4*>(pf + (size_t)vox * 32 + q * 4);
        f[q*4+0] = v.x; f[q*4+1] = v.y; f[q*4+2] = v.z; f[q*4+3] = v.w;
    }

    // semantic head + argmax (strict > = first occurrence)
    float best = -1e30f; int am = 0;
    #pragma unroll
    for (int cc = 0; cc < NCLS; ++cc) {
        float l = sem_b[cc];
        #pragma unroll
        for (int q = 0; q < 32; ++q) l = fmaf(f[q], sem_w[cc * 32 + q], l);
        out_logits[(size_t)vox * NCLS + cc] = l;
        if (l > best) { best = l; am = cc; }
    }

    // offset head
    float off[3];
    #pragma unroll
    for (int k3 = 0; k3 < 3; ++k3) {
        float l = off_b[k3];
        #pragma unroll
        for (int q = 0; q < 32; ++q) l = fmaf(f[q], off_w[k3 * 32 + q], l);
        out_off[(size_t)vox * 3 + k3] = l;
        off[k3] = l;
    }

    float px = points[(size_t)vox * 3 + 0] + off[0];
    float py = points[(size_t)vox * 3 + 1] + off[1];
    float pz = points[(size_t)vox * 3 + 2] + off[2];
    float pp = px * px + py * py + pz * pz;

    float bd2 = 1e30f; int bj = 0;
    #pragma unroll 4
    for (int j = 0; j < NSEED; ++j) {
        float4 s = sseed[j];                    // broadcast, conflict-free
        float dot = px * s.x + py * s.y + pz * s.z;
        float d2  = pp + s.w - 2.0f * dot;
        if (d2 < bd2) { bd2 = d2; bj = j; }     // strict < = first occurrence
    }
    float mind = sqrtf(fmaxf(bd2, 0.f));
    bool valid = mind < 1.5f;

    int slab = (int)ann[bj * 4 + 3];
    if (valid && am != slab) atomicOr(&bad_seed[bj], 1);
    iv_out[vox] = valid ? bj : -1;
}

// ---------------- finalize pseudo labels ----------------
__global__ void finalize_kernel(const int* __restrict__ iv,
                                const int* __restrict__ bad,
                                float* __restrict__ pl) {
    int t = blockIdx.x * 256 + threadIdx.x;
    if (t >= NVOX) return;
    int v = iv[t];
    float r = -1.0f;
    if (v >= 0 && bad[v] == 0) r = (float)v;
    pl[t] = r;
}

extern "C" void kernel_launch(void* const* d_in, const int* in_sizes, int n_in,
                              void* d_out, int out_size, void* d_ws, size_t ws_size,
                              hipStream_t stream) {
    const float* points   = (const float*)d_in[0];
    const float* features = (const float*)d_in[1];
    const float* ann      = (const float*)d_in[2];
    const float* w1       = (const float*)d_in[3];
    const float* b1       = (const float*)d_in[4];
    const float* w2       = (const float*)d_in[5];
    const float* b2       = (const float*)d_in[6];
    const float* sem_w    = (const float*)d_in[7];
    const float* sem_b    = (const float*)d_in[8];
    const float* off_w    = (const float*)d_in[9];
    const float* off_b    = (const float*)d_in[10];

    float* out        = (float*)d_out;
    float* out_logits = out;
    float* out_off    = out + (size_t)NVOX * NCLS;   // N*20
    float* out_pl     = out + (size_t)NVOX * 23;     // N*23

    // workspace layout (bytes; total = 101976576, same as prior rounds)
    char*  ws  = (char*)d_ws;
    float*          w1t  = (float*)         (ws);             //    41472 B
    int*            bad  = (int*)           (ws + 41472);     //     2048 B
    unsigned short* bfr  = (unsigned short*)(ws + 43520);     //   221184 B
    int*            iv   = (int*)           (ws + 264704);    //  1048576 B
    float*          pf   = (float*)         (ws + 1313280);   // 33554432 B
    unsigned short* h1hi = (unsigned short*)(ws + 34867712);  // 33554432 B
    unsigned short* h1lo = (unsigned short*)(ws + 68422144);  // 33554432 B

    hipMemsetAsync(bad, 0, NSEED * sizeof(int), stream);
    transpose_w1<<<41, 256, 0, stream>>>(w1, w1t);
    build_bfrags<<<54, 256, 0, stream>>>(w2, bfr);
    conv1_kernel<<<1024, 256, 0, stream>>>(features, w1t, b1, h1hi, h1lo);
    conv2_mfma_kernel<<<2048, 256, 0, stream>>>(h1hi, h1lo, bfr, b2, pf);
    epilogue_kernel<<<1024, 256, 0, stream>>>(pf, points, ann,
        sem_w, sem_b, off_w, off_b, out_logits, out_off, iv, bad);
    finalize_kernel<<<1024, 256, 0, stream>>>(iv, bad, out_pl);
}

// Round 11
// 322.597 us; speedup vs baseline: 5.3733x; 1.4556x over previous
//
#include <hip/hip_runtime.h>

#define GRID 64
#define NVOX (GRID*GRID*GRID)
#define NCLS 20
#define NSEED 512

typedef __attribute__((ext_vector_type(8))) short short8_t;
typedef __attribute__((ext_vector_type(4))) float float4_t;

__device__ __forceinline__ unsigned short f32_to_bf16_rne(float f) {
    unsigned int x = __float_as_uint(f);
    unsigned int r = (x + 0x7fffu + ((x >> 16) & 1u)) >> 16;
    return (unsigned short)r;
}
__device__ __forceinline__ float bf16_to_f32(unsigned short u) {
    return __uint_as_float(((unsigned int)u) << 16);
}

// ---------------- w1 transpose: w1t[(nb*6+ci)*64+oc] = w1[oc][ci][nb] ----------------
__global__ void transpose_w1(const float* __restrict__ w1, float* __restrict__ w1t) {
    int t = blockIdx.x * 256 + threadIdx.x;
    if (t >= 27 * 6 * 64) return;
    int oc = t & 63;
    int r  = t >> 6;            // nb*6 + ci
    int nb = r / 6, ci = r % 6;
    w1t[t] = w1[oc * 162 + ci * 27 + nb];
}

// ------- build conv2 weight MFMA fragments (hi/lo bf16), 216 frags x 1KB -------
// frag f = ((nb*2+s)*2+t)*2+hl ; lane l elem j: B[ci=s*32+(l>>4)*8+j][oc=t*16+(l&15)]
__global__ void build_bfrags(const float* __restrict__ w2, unsigned short* __restrict__ bfr) {
    int t = blockIdx.x * 256 + threadIdx.x;      // over 216*64
    if (t >= 216 * 64) return;
    int l  = t & 63;
    int f  = t >> 6;
    int hl = f & 1;
    int tt = (f >> 1) & 1;
    int s  = (f >> 2) & 1;
    int nb = f >> 3;
    int lr = l & 15, lg = l >> 4;
    int oc = tt * 16 + lr;
    short8_t out;
    #pragma unroll
    for (int j = 0; j < 8; ++j) {
        int ci = s * 32 + lg * 8 + j;
        float wv = w2[oc * 1728 + ci * 27 + nb];
        unsigned short hi = f32_to_bf16_rne(wv);
        if (hl == 0) out[j] = (short)hi;
        else         out[j] = (short)f32_to_bf16_rne(wv - bf16_to_f32(hi));
    }
    *reinterpret_cast<short8_t*>(bfr + f * 512 + l * 8) = out;
}

// ------- conv1 (6->64): Zd=4, oc=16, all-tap LDS weights; emits A-fragment-layout hi/lo bf16 -------
// h1 frag layout per (z,y) plane (4096 elems): [xt(4)][s(2)][cc(4)][xl(16)][8ci]
__global__ __launch_bounds__(256, 4) void conv1_kernel(
    const float* __restrict__ feat,   // [6][NVOX]
    const float* __restrict__ w1t,    // [(nb*6+ci)][64]
    const float* __restrict__ b1,
    unsigned short* __restrict__ h1hi,
    unsigned short* __restrict__ h1lo)
{
    __shared__ float lw[27 * 6 * 16]; // 10368 B

    int tid = threadIdx.x;
    int B = blockIdx.x;
    int zg = B & 7;
    int k  = B >> 3;
    int og = k & 3;                   // oc group of 16
    int zt = (k >> 2) & 1;
    int yt = (k >> 3) & 15;

    for (int t = tid; t < 27 * 6 * 16; t += 256)
        lw[t] = w1t[(t >> 4) * 64 + og * 16 + (t & 15)];
    __syncthreads();                  // the only barrier

    int x  = tid & 63;
    int y  = yt * 4 + (tid >> 6);     // wave-uniform
    int z0 = zg * 8 + zt * 4;

    float acc[4][16];
    #pragma unroll
    for (int r = 0; r < 4; ++r)
        #pragma unroll
        for (int o = 0; o < 16; ++o) acc[r][o] = 0.f;

    int zoffv[6]; float mzv[6];
    #pragma unroll
    for (int rz = 0; rz < 6; ++rz) {
        int gz = z0 - 1 + rz;
        int cz = gz < 0 ? 0 : (gz > 63 ? 63 : gz);
        zoffv[rz] = cz * 4096;
        mzv[rz] = ((unsigned)gz < 64u) ? 1.f : 0.f;
    }

    #pragma unroll 1
    for (int dydx = 0; dydx < 9; ++dydx) {
        int dy = dydx / 3 - 1;
        int dx = dydx % 3 - 1;
        int ny = y + dy;
        if ((unsigned)ny >= 64u) continue;             // wave-uniform zero-pad skip
        int nx = x + dx;
        float mx = ((unsigned)nx < 64u) ? 1.f : 0.f;
        int cx = nx < 0 ? 0 : (nx > 63 ? 63 : nx);
        int rowvox = ny * 64 + cx;

        float cm[6]; int voff[6];
        #pragma unroll
        for (int rz = 0; rz < 6; ++rz) { cm[rz] = mx * mzv[rz]; voff[rz] = zoffv[rz] + rowvox; }

        #pragma unroll 1
        for (int ci = 0; ci < 6; ++ci) {
            const float* plane = feat + (size_t)ci * NVOX;
            float v[6];
            #pragma unroll
            for (int rz = 0; rz < 6; ++rz) v[rz] = plane[voff[rz]] * cm[rz];
            #pragma unroll
            for (int dzi = 0; dzi < 3; ++dzi) {
                const float4* wp = reinterpret_cast<const float4*>(
                    &lw[(((dzi * 9 + dydx) * 6) + ci) * 16]);
                float4 w0 = wp[0], w1 = wp[1], w2 = wp[2], w3 = wp[3];
                #pragma unroll
                for (int r = 0; r < 4; ++r) {
                    float a = v[r + dzi];
                    acc[r][0]  = fmaf(a, w0.x, acc[r][0]);
                    acc[r][1]  = fmaf(a, w0.y, acc[r][1]);
                    acc[r][2]  = fmaf(a, w0.z, acc[r][2]);
                    acc[r][3]  = fmaf(a, w0.w, acc[r][3]);
                    acc[r][4]  = fmaf(a, w1.x, acc[r][4]);
                    acc[r][5]  = fmaf(a, w1.y, acc[r][5]);
                    acc[r][6]  = fmaf(a, w1.z, acc[r][6]);
                    acc[r][7]  = fmaf(a, w1.w, acc[r][7]);
                    acc[r][8]  = fmaf(a, w2.x, acc[r][8]);
                    acc[r][9]  = fmaf(a, w2.y, acc[r][9]);
                    acc[r][10] = fmaf(a, w2.z, acc[r][10]);
                    acc[r][11] = fmaf(a, w2.w, acc[r][11]);
                    acc[r][12] = fmaf(a, w3.x, acc[r][12]);
                    acc[r][13] = fmaf(a, w3.y, acc[r][13]);
                    acc[r][14] = fmaf(a, w3.z, acc[r][14]);
                    acc[r][15] = fmaf(a, w3.w, acc[r][15]);
                }
            }
        }
    }

    float bias[16];
    #pragma unroll
    for (int o = 0; o < 16; ++o) bias[o] = b1[og * 16 + o];

    // frag-layout store: ci = og*16+o; s = og>>1; cc = (og*2 + (o>>3)) & 3
    int s1 = og >> 1;
    int c0 = (og * 2) & 3;
    int c1 = (og * 2 + 1) & 3;
    #pragma unroll
    for (int zl = 0; zl < 4; ++zl) {
        size_t zy = ((size_t)((z0 + zl) * 64 + y)) * 4096;
        size_t base  = zy + (size_t)(x >> 4) * 1024 + (size_t)s1 * 512 + (size_t)(x & 15) * 8;
        short8_t hi0, hi1, lo0, lo1;
        #pragma unroll
        for (int o = 0; o < 8; ++o) {
            float h = fmaxf(acc[zl][o] + bias[o], 0.f);
            unsigned short uh = f32_to_bf16_rne(h);
            hi0[o] = (short)uh;
            lo0[o] = (short)f32_to_bf16_rne(h - bf16_to_f32(uh));
        }
        #pragma unroll
        for (int o = 8; o < 16; ++o) {
            float h = fmaxf(acc[zl][o] + bias[o], 0.f);
            unsigned short uh = f32_to_bf16_rne(h);
            hi1[o - 8] = (short)uh;
            lo1[o - 8] = (short)f32_to_bf16_rne(h - bf16_to_f32(uh));
        }
        *reinterpret_cast<short8_t*>(h1hi + base + c0 * 128) = hi0;
        *reinterpret_cast<short8_t*>(h1hi + base + c1 * 128) = hi1;
        *reinterpret_cast<short8_t*>(h1lo + base + c0 * 128) = lo0;
        *reinterpret_cast<short8_t*>(h1lo + base + c1 * 128) = lo1;
    }
}

// ------- conv2 (64->32) via MFMA split-bf16, fragment-layout A (coalesced loads) -------
// grid 2048 = 8 zg (XCD, fastest) x 32 yt x 8 zl (slowest -> L2 z-window)
__global__ __launch_bounds__(256) void conv2_mfma_kernel(
    const unsigned short* __restrict__ h1hi, // frag layout
    const unsigned short* __restrict__ h1lo,
    const unsigned short* __restrict__ bfr,  // [27][2s][2t][2hl][64][8] bf16
    const float* __restrict__ b2,
    float* __restrict__ pf)                  // [vox][32] post-relu f32
{
    int tid = threadIdx.x;
    int w   = tid >> 6;
    int l   = tid & 63;
    int B   = blockIdx.x;
    int zg  = B & 7;
    int yt  = (B >> 3) & 31;
    int zl  = B >> 8;                 // 0..7 slowest
    int z   = zg * 8 + zl;
    int y   = yt * 2 + (w & 1);
    int x0  = (w >> 1) * 32;

    int lr = l & 15;
    int lg = l >> 4;

    // per-lane A offsets within a (z,y) plane for vt(2) x dxm(3), + validity masks
    int aoff[2][3]; bool aok[2][3];
    #pragma unroll
    for (int vt = 0; vt < 2; ++vt)
        #pragma unroll
        for (int dxm = 0; dxm < 3; ++dxm) {
            int v = x0 + vt * 16 + lr + dxm - 1;
            aok[vt][dxm] = (unsigned)v < 64u;
            int vc = v < 0 ? 0 : (v > 63 ? 63 : v);
            aoff[vt][dxm] = (vc >> 4) * 1024 + lg * 128 + (vc & 15) * 8;
        }

    const short8_t zero8 = (short8_t)0;
    float4_t acc[2][2];
    #pragma unroll
    for (int a = 0; a < 2; ++a)
        #pragma unroll
        for (int b = 0; b < 2; ++b) acc[a][b] = (float4_t)0.f;

    #pragma unroll 1
    for (int dzi = 0; dzi < 3; ++dzi) {
        int nz = z + dzi - 1;
        if ((unsigned)nz >= 64u) continue;            // wave-uniform
        #pragma unroll 1
        for (int dyi = 0; dyi < 3; ++dyi) {
            int ny = y + dyi - 1;
            if ((unsigned)ny >= 64u) continue;        // wave-uniform
            size_t zy = (size_t)(nz * 64 + ny) * 4096;
            #pragma unroll
            for (int dxm = 0; dxm < 3; ++dxm) {       // compile-time dxm (rule #20)
                int nb = dzi * 9 + dyi * 3 + dxm;
                const unsigned short* bt = bfr + nb * 4096 + l * 8;
                #pragma unroll
                for (int s = 0; s < 2; ++s) {
                    const unsigned short* bs = bt + s * 2048;
                    short8_t bh0 = *reinterpret_cast<const short8_t*>(bs);
                    short8_t bl0 = *reinterpret_cast<const short8_t*>(bs + 512);
                    short8_t bh1 = *reinterpret_cast<const short8_t*>(bs + 1024);
                    short8_t bl1 = *reinterpret_cast<const short8_t*>(bs + 1536);

                    const unsigned short* ph = h1hi + zy + s * 512;
                    const unsigned short* pl_ = h1lo + zy + s * 512;

                    short8_t ah0 = aok[0][dxm] ? *reinterpret_cast<const short8_t*>(ph + aoff[0][dxm]) : zero8;
                    short8_t al0 = aok[0][dxm] ? *reinterpret_cast<const short8_t*>(pl_ + aoff[0][dxm]) : zero8;
                    short8_t ah1 = aok[1][dxm] ? *reinterpret_cast<const short8_t*>(ph + aoff[1][dxm]) : zero8;
                    short8_t al1 = aok[1][dxm] ? *reinterpret_cast<const short8_t*>(pl_ + aoff[1][dxm]) : zero8;

                    acc[0][0] = __builtin_amdgcn_mfma_f32_16x16x32_bf16(ah0, bh0, acc[0][0], 0, 0, 0);
                    acc[0][0] = __builtin_amdgcn_mfma_f32_16x16x32_bf16(al0, bh0, acc[0][0], 0, 0, 0);
                    acc[0][0] = __builtin_amdgcn_mfma_f32_16x16x32_bf16(ah0, bl0, acc[0][0], 0, 0, 0);
                    acc[0][1] = __builtin_amdgcn_mfma_f32_16x16x32_bf16(ah0, bh1, acc[0][1], 0, 0, 0);
                    acc[0][1] = __builtin_amdgcn_mfma_f32_16x16x32_bf16(al0, bh1, acc[0][1], 0, 0, 0);
                    acc[0][1] = __builtin_amdgcn_mfma_f32_16x16x32_bf16(ah0, bl1, acc[0][1], 0, 0, 0);

                    acc[1][0] = __builtin_amdgcn_mfma_f32_16x16x32_bf16(ah1, bh0, acc[1][0], 0, 0, 0);
                    acc[1][0] = __builtin_amdgcn_mfma_f32_16x16x32_bf16(al1, bh0, acc[1][0], 0, 0, 0);
                    acc[1][0] = __builtin_amdgcn_mfma_f32_16x16x32_bf16(ah1, bl0, acc[1][0], 0, 0, 0);
                    acc[1][1] = __builtin_amdgcn_mfma_f32_16x16x32_bf16(ah1, bh1, acc[1][1], 0, 0, 0);
                    acc[1][1] = __builtin_amdgcn_mfma_f32_16x16x32_bf16(al1, bh1, acc[1][1], 0, 0, 0);
                    acc[1][1] = __builtin_amdgcn_mfma_f32_16x16x32_bf16(ah1, bl1, acc[1][1], 0, 0, 0);
                }
            }
        }
    }

    // bias + relu + store: D row (vox) = lg*4+r, col (oc) = lr
    int vbase = (z * 64 + y) * 64 + x0;
    #pragma unroll
    for (int vt = 0; vt < 2; ++vt) {
        #pragma unroll
        for (int t = 0; t < 2; ++t) {
            float bias = b2[t * 16 + lr];
            #pragma unroll
            for (int r = 0; r < 4; ++r) {
                int xv = vbase + vt * 16 + lg * 4 + r;
                pf[(size_t)xv * 32 + t * 16 + lr] = fmaxf(acc[vt][t][r] + bias, 0.f);
            }
        }
    }
}

// ------- epilogue: heads + argmax + argmin over seeds + mismatch scatter -------
__global__ __launch_bounds__(256) void epilogue_kernel(
    const float* __restrict__ pf,     // [vox][32] post-relu
    const float* __restrict__ points, // [N][3]
    const float* __restrict__ ann,    // [512][4]
    const float* __restrict__ sem_w, const float* __restrict__ sem_b,
    const float* __restrict__ off_w, const float* __restrict__ off_b,
    float* __restrict__ out_logits,   // [N][20]
    float* __restrict__ out_off,      // [N][3]
    int* __restrict__ iv_out,         // [N]
    int* __restrict__ bad_seed)       // [512]
{
    __shared__ float4 sseed[NSEED];
    for (int i = threadIdx.x; i < NSEED; i += 256) {
        float4 a = *reinterpret_cast<const float4*>(ann + i * 4);
        sseed[i] = make_float4(a.x, a.y, a.z, a.x*a.x + a.y*a.y + a.z*a.z);
    }
    __syncthreads();

    int vox = blockIdx.x * 256 + threadIdx.x;

    float f[32];
    #pragma unroll
    for (int q = 0; q < 8; ++q) {
        float4 v = *reinterpret_cast<const float4*>(pf + (size_t)vox * 32 + q * 4);
        f[q*4+0] = v.x; f[q*4+1] = v.y; f[q*4+2] = v.z; f[q*4+3] = v.w;
    }

    // semantic head + argmax (strict > = first occurrence)
    float best = -1e30f; int am = 0;
    #pragma unroll
    for (int cc = 0; cc < NCLS; ++cc) {
        float l = sem_b[cc];
        #pragma unroll
        for (int q = 0; q < 32; ++q) l = fmaf(f[q], sem_w[cc * 32 + q], l);
        out_logits[(size_t)vox * NCLS + cc] = l;
        if (l > best) { best = l; am = cc; }
    }

    // offset head
    float off[3];
    #pragma unroll
    for (int k3 = 0; k3 < 3; ++k3) {
        float l = off_b[k3];
        #pragma unroll
        for (int q = 0; q < 32; ++q) l = fmaf(f[q], off_w[k3 * 32 + q], l);
        out_off[(size_t)vox * 3 + k3] = l;
        off[k3] = l;
    }

    float px = points[(size_t)vox * 3 + 0] + off[0];
    float py = points[(size_t)vox * 3 + 1] + off[1];
    float pz = points[(size_t)vox * 3 + 2] + off[2];
    float pp = px * px + py * py + pz * pz;

    float bd2 = 1e30f; int bj = 0;
    #pragma unroll 4
    for (int j = 0; j < NSEED; ++j) {
        float4 s = sseed[j];                    // broadcast, conflict-free
        float dot = px * s.x + py * s.y + pz * s.z;
        float d2  = pp + s.w - 2.0f * dot;
        if (d2 < bd2) { bd2 = d2; bj = j; }     // strict < = first occurrence
    }
    float mind = sqrtf(fmaxf(bd2, 0.f));
    bool valid = mind < 1.5f;

    int slab = (int)ann[bj * 4 + 3];
    if (valid && am != slab) atomicOr(&bad_seed[bj], 1);
    iv_out[vox] = valid ? bj : -1;
}

// ---------------- finalize pseudo labels ----------------
__global__ void finalize_kernel(const int* __restrict__ iv,
                                const int* __restrict__ bad,
                                float* __restrict__ pl) {
    int t = blockIdx.x * 256 + threadIdx.x;
    if (t >= NVOX) return;
    int v = iv[t];
    float r = -1.0f;
    if (v >= 0 && bad[v] == 0) r = (float)v;
    pl[t] = r;
}

extern "C" void kernel_launch(void* const* d_in, const int* in_sizes, int n_in,
                              void* d_out, int out_size, void* d_ws, size_t ws_size,
                              hipStream_t stream) {
    const float* points   = (const float*)d_in[0];
    const float* features = (const float*)d_in[1];
    const float* ann      = (const float*)d_in[2];
    const float* w1       = (const float*)d_in[3];
    const float* b1       = (const float*)d_in[4];
    const float* w2       = (const float*)d_in[5];
    const float* b2       = (const float*)d_in[6];
    const float* sem_w    = (const float*)d_in[7];
    const float* sem_b    = (const float*)d_in[8];
    const float* off_w    = (const float*)d_in[9];
    const float* off_b    = (const float*)d_in[10];

    float* out        = (float*)d_out;
    float* out_logits = out;
    float* out_off    = out + (size_t)NVOX * NCLS;   // N*20
    float* out_pl     = out + (size_t)NVOX * 23;     // N*23

    // workspace layout (bytes; total ~97.3 MB)
    char*  ws  = (char*)d_ws;
    float*          w1t  = (float*)         (ws);             //    41472 B
    int*            bad  = (int*)           (ws + 41472);     //     2048 B
    unsigned short* bfr  = (unsigned short*)(ws + 43520);     //   221184 B
    int*            iv   = (int*)           (ws + 264704);    //  1048576 B
    float*          pf   = (float*)         (ws + 1313280);   // 33554432 B
    unsigned short* h1hi = (unsigned short*)(ws + 34867712);  // 33554432 B
    unsigned short* h1lo = (unsigned short*)(ws + 68422144);  // 33554432 B

    hipMemsetAsync(bad, 0, NSEED * sizeof(int), stream);
    transpose_w1<<<41, 256, 0, stream>>>(w1, w1t);
    build_bfrags<<<54, 256, 0, stream>>>(w2, bfr);
    conv1_kernel<<<1024, 256, 0, stream>>>(features, w1t, b1, h1hi, h1lo);
    conv2_mfma_kernel<<<2048, 256, 0, stream>>>(h1hi, h1lo, bfr, b2, pf);
    epilogue_kernel<<<1024, 256, 0, stream>>>(pf, points, ann,
        sem_w, sem_b, off_w, off_b, out_logits, out_off, iv, bad);
    finalize_kernel<<<1024, 256, 0, stream>>>(iv, bad, out_pl);
}

// Round 12
// 273.745 us; speedup vs baseline: 6.3322x; 1.1785x over previous
//
#include <hip/hip_runtime.h>

#define GRID 64
#define NVOX (GRID*GRID*GRID)
#define NCLS 20
#define NSEED 512

typedef __attribute__((ext_vector_type(8))) short short8_t;
typedef __attribute__((ext_vector_type(4))) float float4_t;

__device__ __forceinline__ unsigned short f32_to_bf16_rne(float f) {
    unsigned int x = __float_as_uint(f);
    unsigned int r = (x + 0x7fffu + ((x >> 16) & 1u)) >> 16;
    return (unsigned short)r;
}
__device__ __forceinline__ float bf16_to_f32(unsigned short u) {
    return __uint_as_float(((unsigned int)u) << 16);
}

// ---------------- w1 transpose: w1t[(nb*6+ci)*64+oc] = w1[oc][ci][nb] ----------------
__global__ void transpose_w1(const float* __restrict__ w1, float* __restrict__ w1t) {
    int t = blockIdx.x * 256 + threadIdx.x;
    if (t >= 27 * 6 * 64) return;
    int oc = t & 63;
    int r  = t >> 6;            // nb*6 + ci
    int nb = r / 6, ci = r % 6;
    w1t[t] = w1[oc * 162 + ci * 27 + nb];
}

// ------- build conv2 weight MFMA fragments (hi/lo bf16), 216 frags x 1KB -------
// frag f = ((nb*2+s)*2+t)*2+hl ; lane l elem j: B[ci=s*32+(l>>4)*8+j][oc=t*16+(l&15)]
__global__ void build_bfrags(const float* __restrict__ w2, unsigned short* __restrict__ bfr) {
    int t = blockIdx.x * 256 + threadIdx.x;      // over 216*64
    if (t >= 216 * 64) return;
    int l  = t & 63;
    int f  = t >> 6;
    int hl = f & 1;
    int tt = (f >> 1) & 1;
    int s  = (f >> 2) & 1;
    int nb = f >> 3;
    int lr = l & 15, lg = l >> 4;
    int oc = tt * 16 + lr;
    short8_t out;
    #pragma unroll
    for (int j = 0; j < 8; ++j) {
        int ci = s * 32 + lg * 8 + j;
        float wv = w2[oc * 1728 + ci * 27 + nb];
        unsigned short hi = f32_to_bf16_rne(wv);
        if (hl == 0) out[j] = (short)hi;
        else         out[j] = (short)f32_to_bf16_rne(wv - bf16_to_f32(hi));
    }
    *reinterpret_cast<short8_t*>(bfr + f * 512 + l * 8) = out;
}

// ------- conv1 (6->64): Zd=4, oc=16, all-tap LDS weights; batched loads; emits bf16-hi frag layout -------
// h1 frag layout per (z,y) plane (4096 elems): [xt(4)][s(2)][cc(4)][xl(16)][8ci]
__global__ __launch_bounds__(256, 4) void conv1_kernel(
    const float* __restrict__ feat,   // [6][NVOX]
    const float* __restrict__ w1t,    // [(nb*6+ci)][64]
    const float* __restrict__ b1,
    unsigned short* __restrict__ h1hi)
{
    __shared__ float lw[27 * 6 * 16]; // 10368 B

    int tid = threadIdx.x;
    int B = blockIdx.x;
    int zg = B & 7;
    int k  = B >> 3;
    int og = k & 3;                   // oc group of 16
    int zt = (k >> 2) & 1;
    int yt = (k >> 3) & 15;

    for (int t = tid; t < 27 * 6 * 16; t += 256)
        lw[t] = w1t[(t >> 4) * 64 + og * 16 + (t & 15)];
    __syncthreads();                  // the only barrier

    int x  = tid & 63;
    int y  = yt * 4 + (tid >> 6);     // wave-uniform
    int z0 = zg * 8 + zt * 4;

    float acc[4][16];
    #pragma unroll
    for (int r = 0; r < 4; ++r)
        #pragma unroll
        for (int o = 0; o < 16; ++o) acc[r][o] = 0.f;

    int zoffv[6]; float mzv[6];
    #pragma unroll
    for (int rz = 0; rz < 6; ++rz) {
        int gz = z0 - 1 + rz;
        int cz = gz < 0 ? 0 : (gz > 63 ? 63 : gz);
        zoffv[rz] = cz * 4096;
        mzv[rz] = ((unsigned)gz < 64u) ? 1.f : 0.f;
    }

    #pragma unroll 1
    for (int dydx = 0; dydx < 9; ++dydx) {
        int dy = dydx / 3 - 1;
        int dx = dydx % 3 - 1;
        int ny = y + dy;
        if ((unsigned)ny >= 64u) continue;             // wave-uniform zero-pad skip
        int nx = x + dx;
        float mx = ((unsigned)nx < 64u) ? 1.f : 0.f;
        int cx = nx < 0 ? 0 : (nx > 63 ? 63 : nx);
        int rowvox = ny * 64 + cx;

        float cm[6]; int voff[6];
        #pragma unroll
        for (int rz = 0; rz < 6; ++rz) { cm[rz] = mx * mzv[rz]; voff[rz] = zoffv[rz] + rowvox; }

        // 2 half-batches of 3 ci: 18 loads issued per window, then FMA
        #pragma unroll
        for (int cb = 0; cb < 2; ++cb) {
            float v[3][6];
            #pragma unroll
            for (int ci = 0; ci < 3; ++ci) {
                const float* plane = feat + (size_t)(cb * 3 + ci) * NVOX;
                #pragma unroll
                for (int rz = 0; rz < 6; ++rz) v[ci][rz] = plane[voff[rz]];
            }
            #pragma unroll
            for (int ci = 0; ci < 3; ++ci)
                #pragma unroll
                for (int rz = 0; rz < 6; ++rz) v[ci][rz] *= cm[rz];
            #pragma unroll
            for (int ci = 0; ci < 3; ++ci) {
                #pragma unroll
                for (int dzi = 0; dzi < 3; ++dzi) {
                    const float4* wp = reinterpret_cast<const float4*>(
                        &lw[(((dzi * 9 + dydx) * 6) + cb * 3 + ci) * 16]);
                    float4 w0 = wp[0], w1 = wp[1], w2 = wp[2], w3 = wp[3];
                    #pragma unroll
                    for (int r = 0; r < 4; ++r) {
                        float a = v[ci][r + dzi];
                        acc[r][0]  = fmaf(a, w0.x, acc[r][0]);
                        acc[r][1]  = fmaf(a, w0.y, acc[r][1]);
                        acc[r][2]  = fmaf(a, w0.z, acc[r][2]);
                        acc[r][3]  = fmaf(a, w0.w, acc[r][3]);
                        acc[r][4]  = fmaf(a, w1.x, acc[r][4]);
                        acc[r][5]  = fmaf(a, w1.y, acc[r][5]);
                        acc[r][6]  = fmaf(a, w1.z, acc[r][6]);
                        acc[r][7]  = fmaf(a, w1.w, acc[r][7]);
                        acc[r][8]  = fmaf(a, w2.x, acc[r][8]);
                        acc[r][9]  = fmaf(a, w2.y, acc[r][9]);
                        acc[r][10] = fmaf(a, w2.z, acc[r][10]);
                        acc[r][11] = fmaf(a, w2.w, acc[r][11]);
                        acc[r][12] = fmaf(a, w3.x, acc[r][12]);
                        acc[r][13] = fmaf(a, w3.y, acc[r][13]);
                        acc[r][14] = fmaf(a, w3.z, acc[r][14]);
                        acc[r][15] = fmaf(a, w3.w, acc[r][15]);
                    }
                }
            }
        }
    }

    float bias[16];
    #pragma unroll
    for (int o = 0; o < 16; ++o) bias[o] = b1[og * 16 + o];

    // frag-layout store (hi only): s = og>>1; cc = (og*2 + (o>>3)) & 3
    int s1 = og >> 1;
    int c0 = (og * 2) & 3;
    int c1 = (og * 2 + 1) & 3;
    #pragma unroll
    for (int zl = 0; zl < 4; ++zl) {
        size_t zy = ((size_t)((z0 + zl) * 64 + y)) * 4096;
        size_t base  = zy + (size_t)(x >> 4) * 1024 + (size_t)s1 * 512 + (size_t)(x & 15) * 8;
        short8_t hi0, hi1;
        #pragma unroll
        for (int o = 0; o < 8; ++o)
            hi0[o] = (short)f32_to_bf16_rne(fmaxf(acc[zl][o] + bias[o], 0.f));
        #pragma unroll
        for (int o = 8; o < 16; ++o)
            hi1[o - 8] = (short)f32_to_bf16_rne(fmaxf(acc[zl][o] + bias[o], 0.f));
        *reinterpret_cast<short8_t*>(h1hi + base + c0 * 128) = hi0;
        *reinterpret_cast<short8_t*>(h1hi + base + c1 * 128) = hi1;
    }
}

// ------- conv2 (64->32) via MFMA, A=bf16-hi, B=split hi/lo; wave = 64 vox x 32 oc -------
// grid 1024 = 8 zg (XCD, fastest) x 16 yt x 8 zl (slowest -> L2 z-window)
__global__ __launch_bounds__(256) void conv2_mfma_kernel(
    const unsigned short* __restrict__ h1hi, // frag layout
    const unsigned short* __restrict__ bfr,  // [27][2s][2t][2hl][64][8] bf16
    const float* __restrict__ b2,
    float* __restrict__ pf)                  // [vox][32] post-relu f32
{
    int tid = threadIdx.x;
    int w   = tid >> 6;
    int l   = tid & 63;
    int B   = blockIdx.x;
    int zg  = B & 7;
    int yt  = (B >> 3) & 15;
    int zl  = B >> 7;                 // 0..7 slowest
    int z   = zg * 8 + zl;
    int y   = yt * 4 + w;             // wave-uniform

    int lr = l & 15;
    int lg = l >> 4;

    // per-lane A offsets within a (z,y) plane for vt(4) x dxm(3), + validity
    int aoff[4][3]; bool aok[4][3];
    #pragma unroll
    for (int vt = 0; vt < 4; ++vt)
        #pragma unroll
        for (int dxm = 0; dxm < 3; ++dxm) {
            int v = vt * 16 + lr + dxm - 1;
            aok[vt][dxm] = (unsigned)v < 64u;
            int vc = v < 0 ? 0 : (v > 63 ? 63 : v);
            aoff[vt][dxm] = (vc >> 4) * 1024 + lg * 128 + (vc & 15) * 8;
        }

    const short8_t zero8 = (short8_t)0;
    float4_t acc[4][2];
    #pragma unroll
    for (int a = 0; a < 4; ++a)
        #pragma unroll
        for (int b = 0; b < 2; ++b) acc[a][b] = (float4_t)0.f;

    #pragma unroll 1
    for (int dzi = 0; dzi < 3; ++dzi) {
        int nz = z + dzi - 1;
        if ((unsigned)nz >= 64u) continue;            // wave-uniform
        #pragma unroll 1
        for (int dyi = 0; dyi < 3; ++dyi) {
            int ny = y + dyi - 1;
            if ((unsigned)ny >= 64u) continue;        // wave-uniform
            size_t zy = (size_t)(nz * 64 + ny) * 4096;
            #pragma unroll
            for (int dxm = 0; dxm < 3; ++dxm) {       // compile-time (rule #20)
                int nb = dzi * 9 + dyi * 3 + dxm;
                const unsigned short* bt = bfr + nb * 4096 + l * 8;
                #pragma unroll
                for (int s = 0; s < 2; ++s) {
                    const unsigned short* bs = bt + s * 2048;
                    short8_t bh0 = *reinterpret_cast<const short8_t*>(bs);
                    short8_t bl0 = *reinterpret_cast<const short8_t*>(bs + 512);
                    short8_t bh1 = *reinterpret_cast<const short8_t*>(bs + 1024);
                    short8_t bl1 = *reinterpret_cast<const short8_t*>(bs + 1536);

                    const unsigned short* ph = h1hi + zy + s * 512;
                    short8_t a0 = aok[0][dxm] ? *reinterpret_cast<const short8_t*>(ph + aoff[0][dxm]) : zero8;
                    short8_t a1 = aok[1][dxm] ? *reinterpret_cast<const short8_t*>(ph + aoff[1][dxm]) : zero8;
                    short8_t a2 = aok[2][dxm] ? *reinterpret_cast<const short8_t*>(ph + aoff[2][dxm]) : zero8;
                    short8_t a3 = aok[3][dxm] ? *reinterpret_cast<const short8_t*>(ph + aoff[3][dxm]) : zero8;

                    acc[0][0] = __builtin_amdgcn_mfma_f32_16x16x32_bf16(a0, bh0, acc[0][0], 0, 0, 0);
                    acc[0][0] = __builtin_amdgcn_mfma_f32_16x16x32_bf16(a0, bl0, acc[0][0], 0, 0, 0);
                    acc[0][1] = __builtin_amdgcn_mfma_f32_16x16x32_bf16(a0, bh1, acc[0][1], 0, 0, 0);
                    acc[0][1] = __builtin_amdgcn_mfma_f32_16x16x32_bf16(a0, bl1, acc[0][1], 0, 0, 0);

                    acc[1][0] = __builtin_amdgcn_mfma_f32_16x16x32_bf16(a1, bh0, acc[1][0], 0, 0, 0);
                    acc[1][0] = __builtin_amdgcn_mfma_f32_16x16x32_bf16(a1, bl0, acc[1][0], 0, 0, 0);
                    acc[1][1] = __builtin_amdgcn_mfma_f32_16x16x32_bf16(a1, bh1, acc[1][1], 0, 0, 0);
                    acc[1][1] = __builtin_amdgcn_mfma_f32_16x16x32_bf16(a1, bl1, acc[1][1], 0, 0, 0);

                    acc[2][0] = __builtin_amdgcn_mfma_f32_16x16x32_bf16(a2, bh0, acc[2][0], 0, 0, 0);
                    acc[2][0] = __builtin_amdgcn_mfma_f32_16x16x32_bf16(a2, bl0, acc[2][0], 0, 0, 0);
                    acc[2][1] = __builtin_amdgcn_mfma_f32_16x16x32_bf16(a2, bh1, acc[2][1], 0, 0, 0);
                    acc[2][1] = __builtin_amdgcn_mfma_f32_16x16x32_bf16(a2, bl1, acc[2][1], 0, 0, 0);

                    acc[3][0] = __builtin_amdgcn_mfma_f32_16x16x32_bf16(a3, bh0, acc[3][0], 0, 0, 0);
                    acc[3][0] = __builtin_amdgcn_mfma_f32_16x16x32_bf16(a3, bl0, acc[3][0], 0, 0, 0);
                    acc[3][1] = __builtin_amdgcn_mfma_f32_16x16x32_bf16(a3, bh1, acc[3][1], 0, 0, 0);
                    acc[3][1] = __builtin_amdgcn_mfma_f32_16x16x32_bf16(a3, bl1, acc[3][1], 0, 0, 0);
                }
            }
        }
    }

    // bias + relu + store: D row (vox within 16-tile) = lg*4+r, col (oc) = lr
    int vbase = (z * 64 + y) * 64;
    #pragma unroll
    for (int vt = 0; vt < 4; ++vt) {
        #pragma unroll
        for (int t = 0; t < 2; ++t) {
            float bias = b2[t * 16 + lr];
            #pragma unroll
            for (int r = 0; r < 4; ++r) {
                int xv = vbase + vt * 16 + lg * 4 + r;
                pf[(size_t)xv * 32 + t * 16 + lr] = fmaxf(acc[vt][t][r] + bias, 0.f);
            }
        }
    }
}

// ------- epilogue: heads + argmax + argmin over seeds + mismatch scatter -------
__global__ __launch_bounds__(256) void epilogue_kernel(
    const float* __restrict__ pf,     // [vox][32] post-relu
    const float* __restrict__ points, // [N][3]
    const float* __restrict__ ann,    // [512][4]
    const float* __restrict__ sem_w, const float* __restrict__ sem_b,
    const float* __restrict__ off_w, const float* __restrict__ off_b,
    float* __restrict__ out_logits,   // [N][20]
    float* __restrict__ out_off,      // [N][3]
    int* __restrict__ iv_out,         // [N]
    int* __restrict__ bad_seed)       // [512]
{
    __shared__ float4 sseed[NSEED];
    for (int i = threadIdx.x; i < NSEED; i += 256) {
        float4 a = *reinterpret_cast<const float4*>(ann + i * 4);
        sseed[i] = make_float4(a.x, a.y, a.z, a.x*a.x + a.y*a.y + a.z*a.z);
    }
    __syncthreads();

    int vox = blockIdx.x * 256 + threadIdx.x;

    float f[32];
    #pragma unroll
    for (int q = 0; q < 8; ++q) {
        float4 v = *reinterpret_cast<const float4*>(pf + (size_t)vox * 32 + q * 4);
        f[q*4+0] = v.x; f[q*4+1] = v.y; f[q*4+2] = v.z; f[q*4+3] = v.w;
    }

    // semantic head + argmax (strict > = first occurrence)
    float best = -1e30f; int am = 0;
    #pragma unroll
    for (int cc = 0; cc < NCLS; ++cc) {
        float l = sem_b[cc];
        #pragma unroll
        for (int q = 0; q < 32; ++q) l = fmaf(f[q], sem_w[cc * 32 + q], l);
        out_logits[(size_t)vox * NCLS + cc] = l;
        if (l > best) { best = l; am = cc; }
    }

    // offset head
    float off[3];
    #pragma unroll
    for (int k3 = 0; k3 < 3; ++k3) {
        float l = off_b[k3];
        #pragma unroll
        for (int q = 0; q < 32; ++q) l = fmaf(f[q], off_w[k3 * 32 + q], l);
        out_off[(size_t)vox * 3 + k3] = l;
        off[k3] = l;
    }

    float px = points[(size_t)vox * 3 + 0] + off[0];
    float py = points[(size_t)vox * 3 + 1] + off[1];
    float pz = points[(size_t)vox * 3 + 2] + off[2];
    float pp = px * px + py * py + pz * pz;

    float bd2 = 1e30f; int bj = 0;
    #pragma unroll 4
    for (int j = 0; j < NSEED; ++j) {
        float4 s = sseed[j];                    // broadcast, conflict-free
        float dot = px * s.x + py * s.y + pz * s.z;
        float d2  = pp + s.w - 2.0f * dot;
        if (d2 < bd2) { bd2 = d2; bj = j; }     // strict < = first occurrence
    }
    float mind = sqrtf(fmaxf(bd2, 0.f));
    bool valid = mind < 1.5f;

    int slab = (int)ann[bj * 4 + 3];
    if (valid && am != slab) atomicOr(&bad_seed[bj], 1);
    iv_out[vox] = valid ? bj : -1;
}

// ---------------- finalize pseudo labels ----------------
__global__ void finalize_kernel(const int* __restrict__ iv,
                                const int* __restrict__ bad,
                                float* __restrict__ pl) {
    int t = blockIdx.x * 256 + threadIdx.x;
    if (t >= NVOX) return;
    int v = iv[t];
    float r = -1.0f;
    if (v >= 0 && bad[v] == 0) r = (float)v;
    pl[t] = r;
}

extern "C" void kernel_launch(void* const* d_in, const int* in_sizes, int n_in,
                              void* d_out, int out_size, void* d_ws, size_t ws_size,
                              hipStream_t stream) {
    const float* points   = (const float*)d_in[0];
    const float* features = (const float*)d_in[1];
    const float* ann      = (const float*)d_in[2];
    const float* w1       = (const float*)d_in[3];
    const float* b1       = (const float*)d_in[4];
    const float* w2       = (const float*)d_in[5];
    const float* b2       = (const float*)d_in[6];
    const float* sem_w    = (const float*)d_in[7];
    const float* sem_b    = (const float*)d_in[8];
    const float* off_w    = (const float*)d_in[9];
    const float* off_b    = (const float*)d_in[10];

    float* out        = (float*)d_out;
    float* out_logits = out;
    float* out_off    = out + (size_t)NVOX * NCLS;   // N*20
    float* out_pl     = out + (size_t)NVOX * 23;     // N*23

    // workspace layout (bytes)
    char*  ws  = (char*)d_ws;
    float*          w1t  = (float*)         (ws);             //    41472 B
    int*            bad  = (int*)           (ws + 41472);     //     2048 B
    unsigned short* bfr  = (unsigned short*)(ws + 43520);     //   221184 B
    int*            iv   = (int*)           (ws + 264704);    //  1048576 B
    float*          pf   = (float*)         (ws + 1313280);   // 33554432 B
    unsigned short* h1hi = (unsigned short*)(ws + 34867712);  // 33554432 B

    hipMemsetAsync(bad, 0, NSEED * sizeof(int), stream);
    transpose_w1<<<41, 256, 0, stream>>>(w1, w1t);
    build_bfrags<<<54, 256, 0, stream>>>(w2, bfr);
    conv1_kernel<<<1024, 256, 0, stream>>>(features, w1t, b1, h1hi);
    conv2_mfma_kernel<<<1024, 256, 0, stream>>>(h1hi, bfr, b2, pf);
    epilogue_kernel<<<1024, 256, 0, stream>>>(pf, points, ann,
        sem_w, sem_b, off_w, off_b, out_logits, out_off, iv, bad);
    finalize_kernel<<<1024, 256, 0, stream>>>(iv, bad, out_pl);
}

// Round 13
// 273.655 us; speedup vs baseline: 6.3343x; 1.0003x over previous
//
#include <hip/hip_runtime.h>

#define GRID 64
#define NVOX (GRID*GRID*GRID)
#define NCLS 20
#define NSEED 512

typedef __attribute__((ext_vector_type(8))) short short8_t;
typedef __attribute__((ext_vector_type(4))) float float4_t;

__device__ __forceinline__ unsigned short f32_to_bf16_rne(float f) {
    unsigned int x = __float_as_uint(f);
    unsigned int r = (x + 0x7fffu + ((x >> 16) & 1u)) >> 16;
    return (unsigned short)r;
}
__device__ __forceinline__ float bf16_to_f32(unsigned short u) {
    return __uint_as_float(((unsigned int)u) << 16);
}

// ---------------- w1 transpose: w1t[(nb*6+ci)*64+oc] = w1[oc][ci][nb] ----------------
__global__ void transpose_w1(const float* __restrict__ w1, float* __restrict__ w1t) {
    int t = blockIdx.x * 256 + threadIdx.x;
    if (t >= 27 * 6 * 64) return;
    int oc = t & 63;
    int r  = t >> 6;            // nb*6 + ci
    int nb = r / 6, ci = r % 6;
    w1t[t] = w1[oc * 162 + ci * 27 + nb];
}

// ------- build conv2 weight MFMA fragments (hi/lo bf16), 216 frags x 1KB -------
// frag f = ((nb*2+s)*2+t)*2+hl ; lane l elem j: B[ci=s*32+(l>>4)*8+j][oc=t*16+(l&15)]
__global__ void build_bfrags(const float* __restrict__ w2, unsigned short* __restrict__ bfr) {
    int t = blockIdx.x * 256 + threadIdx.x;      // over 216*64
    if (t >= 216 * 64) return;
    int l  = t & 63;
    int f  = t >> 6;
    int hl = f & 1;
    int tt = (f >> 1) & 1;
    int s  = (f >> 2) & 1;
    int nb = f >> 3;
    int lr = l & 15, lg = l >> 4;
    int oc = tt * 16 + lr;
    short8_t out;
    #pragma unroll
    for (int j = 0; j < 8; ++j) {
        int ci = s * 32 + lg * 8 + j;
        float wv = w2[oc * 1728 + ci * 27 + nb];
        unsigned short hi = f32_to_bf16_rne(wv);
        if (hl == 0) out[j] = (short)hi;
        else         out[j] = (short)f32_to_bf16_rne(wv - bf16_to_f32(hi));
    }
    *reinterpret_cast<short8_t*>(bfr + f * 512 + l * 8) = out;
}

// ------- conv1 (6->64): Zd=4, oc=16, all-tap LDS weights; batched loads; emits bf16-hi frag layout -------
// h1 frag layout per (z,y) plane (4096 elems): [xt(4)][s(2)][cc(4)][xl(16)][8ci]
__global__ __launch_bounds__(256, 4) void conv1_kernel(
    const float* __restrict__ feat,   // [6][NVOX]
    const float* __restrict__ w1t,    // [(nb*6+ci)][64]
    const float* __restrict__ b1,
    unsigned short* __restrict__ h1hi)
{
    __shared__ float lw[27 * 6 * 16]; // 10368 B

    int tid = threadIdx.x;
    int B = blockIdx.x;
    int zg = B & 7;
    int k  = B >> 3;
    int og = k & 3;                   // oc group of 16
    int zt = (k >> 2) & 1;
    int yt = (k >> 3) & 15;

    for (int t = tid; t < 27 * 6 * 16; t += 256)
        lw[t] = w1t[(t >> 4) * 64 + og * 16 + (t & 15)];
    __syncthreads();                  // the only barrier

    int x  = tid & 63;
    int y  = yt * 4 + (tid >> 6);     // wave-uniform
    int z0 = zg * 8 + zt * 4;

    float acc[4][16];
    #pragma unroll
    for (int r = 0; r < 4; ++r)
        #pragma unroll
        for (int o = 0; o < 16; ++o) acc[r][o] = 0.f;

    int zoffv[6]; float mzv[6];
    #pragma unroll
    for (int rz = 0; rz < 6; ++rz) {
        int gz = z0 - 1 + rz;
        int cz = gz < 0 ? 0 : (gz > 63 ? 63 : gz);
        zoffv[rz] = cz * 4096;
        mzv[rz] = ((unsigned)gz < 64u) ? 1.f : 0.f;
    }

    #pragma unroll 1
    for (int dydx = 0; dydx < 9; ++dydx) {
        int dy = dydx / 3 - 1;
        int dx = dydx % 3 - 1;
        int ny = y + dy;
        if ((unsigned)ny >= 64u) continue;             // wave-uniform zero-pad skip
        int nx = x + dx;
        float mx = ((unsigned)nx < 64u) ? 1.f : 0.f;
        int cx = nx < 0 ? 0 : (nx > 63 ? 63 : nx);
        int rowvox = ny * 64 + cx;

        float cm[6]; int voff[6];
        #pragma unroll
        for (int rz = 0; rz < 6; ++rz) { cm[rz] = mx * mzv[rz]; voff[rz] = zoffv[rz] + rowvox; }

        // 2 half-batches of 3 ci: 18 loads issued per window, then FMA
        #pragma unroll
        for (int cb = 0; cb < 2; ++cb) {
            float v[3][6];
            #pragma unroll
            for (int ci = 0; ci < 3; ++ci) {
                const float* plane = feat + (size_t)(cb * 3 + ci) * NVOX;
                #pragma unroll
                for (int rz = 0; rz < 6; ++rz) v[ci][rz] = plane[voff[rz]];
            }
            #pragma unroll
            for (int ci = 0; ci < 3; ++ci)
                #pragma unroll
                for (int rz = 0; rz < 6; ++rz) v[ci][rz] *= cm[rz];
            #pragma unroll
            for (int ci = 0; ci < 3; ++ci) {
                #pragma unroll
                for (int dzi = 0; dzi < 3; ++dzi) {
                    const float4* wp = reinterpret_cast<const float4*>(
                        &lw[(((dzi * 9 + dydx) * 6) + cb * 3 + ci) * 16]);
                    float4 w0 = wp[0], w1 = wp[1], w2 = wp[2], w3 = wp[3];
                    #pragma unroll
                    for (int r = 0; r < 4; ++r) {
                        float a = v[ci][r + dzi];
                        acc[r][0]  = fmaf(a, w0.x, acc[r][0]);
                        acc[r][1]  = fmaf(a, w0.y, acc[r][1]);
                        acc[r][2]  = fmaf(a, w0.z, acc[r][2]);
                        acc[r][3]  = fmaf(a, w0.w, acc[r][3]);
                        acc[r][4]  = fmaf(a, w1.x, acc[r][4]);
                        acc[r][5]  = fmaf(a, w1.y, acc[r][5]);
                        acc[r][6]  = fmaf(a, w1.z, acc[r][6]);
                        acc[r][7]  = fmaf(a, w1.w, acc[r][7]);
                        acc[r][8]  = fmaf(a, w2.x, acc[r][8]);
                        acc[r][9]  = fmaf(a, w2.y, acc[r][9]);
                        acc[r][10] = fmaf(a, w2.z, acc[r][10]);
                        acc[r][11] = fmaf(a, w2.w, acc[r][11]);
                        acc[r][12] = fmaf(a, w3.x, acc[r][12]);
                        acc[r][13] = fmaf(a, w3.y, acc[r][13]);
                        acc[r][14] = fmaf(a, w3.z, acc[r][14]);
                        acc[r][15] = fmaf(a, w3.w, acc[r][15]);
                    }
                }
            }
        }
    }

    float bias[16];
    #pragma unroll
    for (int o = 0; o < 16; ++o) bias[o] = b1[og * 16 + o];

    // frag-layout store (hi only): s = og>>1; cc = (og*2 + (o>>3)) & 3
    int s1 = og >> 1;
    int c0 = (og * 2) & 3;
    int c1 = (og * 2 + 1) & 3;
    #pragma unroll
    for (int zl = 0; zl < 4; ++zl) {
        size_t zy = ((size_t)((z0 + zl) * 64 + y)) * 4096;
        size_t base  = zy + (size_t)(x >> 4) * 1024 + (size_t)s1 * 512 + (size_t)(x & 15) * 8;
        short8_t hi0, hi1;
        #pragma unroll
        for (int o = 0; o < 8; ++o)
            hi0[o] = (short)f32_to_bf16_rne(fmaxf(acc[zl][o] + bias[o], 0.f));
        #pragma unroll
        for (int o = 8; o < 16; ++o)
            hi1[o - 8] = (short)f32_to_bf16_rne(fmaxf(acc[zl][o] + bias[o], 0.f));
        *reinterpret_cast<short8_t*>(h1hi + base + c0 * 128) = hi0;
        *reinterpret_cast<short8_t*>(h1hi + base + c1 * 128) = hi1;
    }
}

// ------- conv2 (64->32) via MFMA, A=bf16-hi, B=split hi/lo; wave = 64 vox x 32 oc -------
// grid 1024 = 8 zg (XCD, fastest) x 16 yt x 8 zl (slowest -> L2 z-window)
__global__ __launch_bounds__(256) void conv2_mfma_kernel(
    const unsigned short* __restrict__ h1hi, // frag layout
    const unsigned short* __restrict__ bfr,  // [27][2s][2t][2hl][64][8] bf16
    const float* __restrict__ b2,
    float* __restrict__ pf)                  // [vox][32] post-relu f32
{
    int tid = threadIdx.x;
    int w   = tid >> 6;
    int l   = tid & 63;
    int B   = blockIdx.x;
    int zg  = B & 7;
    int yt  = (B >> 3) & 15;
    int zl  = B >> 7;                 // 0..7 slowest
    int z   = zg * 8 + zl;
    int y   = yt * 4 + w;             // wave-uniform

    int lr = l & 15;
    int lg = l >> 4;

    // per-lane A offsets within a (z,y) plane for vt(4) x dxm(3), + validity
    int aoff[4][3]; bool aok[4][3];
    #pragma unroll
    for (int vt = 0; vt < 4; ++vt)
        #pragma unroll
        for (int dxm = 0; dxm < 3; ++dxm) {
            int v = vt * 16 + lr + dxm - 1;
            aok[vt][dxm] = (unsigned)v < 64u;
            int vc = v < 0 ? 0 : (v > 63 ? 63 : v);
            aoff[vt][dxm] = (vc >> 4) * 1024 + lg * 128 + (vc & 15) * 8;
        }

    const short8_t zero8 = (short8_t)0;
    float4_t acc[4][2];
    #pragma unroll
    for (int a = 0; a < 4; ++a)
        #pragma unroll
        for (int b = 0; b < 2; ++b) acc[a][b] = (float4_t)0.f;

    #pragma unroll 1
    for (int dzi = 0; dzi < 3; ++dzi) {
        int nz = z + dzi - 1;
        if ((unsigned)nz >= 64u) continue;            // wave-uniform
        #pragma unroll 1
        for (int dyi = 0; dyi < 3; ++dyi) {
            int ny = y + dyi - 1;
            if ((unsigned)ny >= 64u) continue;        // wave-uniform
            size_t zy = (size_t)(nz * 64 + ny) * 4096;
            #pragma unroll
            for (int dxm = 0; dxm < 3; ++dxm) {       // compile-time (rule #20)
                int nb = dzi * 9 + dyi * 3 + dxm;
                const unsigned short* bt = bfr + nb * 4096 + l * 8;
                #pragma unroll
                for (int s = 0; s < 2; ++s) {
                    const unsigned short* bs = bt + s * 2048;
                    short8_t bh0 = *reinterpret_cast<const short8_t*>(bs);
                    short8_t bl0 = *reinterpret_cast<const short8_t*>(bs + 512);
                    short8_t bh1 = *reinterpret_cast<const short8_t*>(bs + 1024);
                    short8_t bl1 = *reinterpret_cast<const short8_t*>(bs + 1536);

                    const unsigned short* ph = h1hi + zy + s * 512;
                    short8_t a0 = aok[0][dxm] ? *reinterpret_cast<const short8_t*>(ph + aoff[0][dxm]) : zero8;
                    short8_t a1 = aok[1][dxm] ? *reinterpret_cast<const short8_t*>(ph + aoff[1][dxm]) : zero8;
                    short8_t a2 = aok[2][dxm] ? *reinterpret_cast<const short8_t*>(ph + aoff[2][dxm]) : zero8;
                    short8_t a3 = aok[3][dxm] ? *reinterpret_cast<const short8_t*>(ph + aoff[3][dxm]) : zero8;

                    acc[0][0] = __builtin_amdgcn_mfma_f32_16x16x32_bf16(a0, bh0, acc[0][0], 0, 0, 0);
                    acc[0][0] = __builtin_amdgcn_mfma_f32_16x16x32_bf16(a0, bl0, acc[0][0], 0, 0, 0);
                    acc[0][1] = __builtin_amdgcn_mfma_f32_16x16x32_bf16(a0, bh1, acc[0][1], 0, 0, 0);
                    acc[0][1] = __builtin_amdgcn_mfma_f32_16x16x32_bf16(a0, bl1, acc[0][1], 0, 0, 0);

                    acc[1][0] = __builtin_amdgcn_mfma_f32_16x16x32_bf16(a1, bh0, acc[1][0], 0, 0, 0);
                    acc[1][0] = __builtin_amdgcn_mfma_f32_16x16x32_bf16(a1, bl0, acc[1][0], 0, 0, 0);
                    acc[1][1] = __builtin_amdgcn_mfma_f32_16x16x32_bf16(a1, bh1, acc[1][1], 0, 0, 0);
                    acc[1][1] = __builtin_amdgcn_mfma_f32_16x16x32_bf16(a1, bl1, acc[1][1], 0, 0, 0);

                    acc[2][0] = __builtin_amdgcn_mfma_f32_16x16x32_bf16(a2, bh0, acc[2][0], 0, 0, 0);
                    acc[2][0] = __builtin_amdgcn_mfma_f32_16x16x32_bf16(a2, bl0, acc[2][0], 0, 0, 0);
                    acc[2][1] = __builtin_amdgcn_mfma_f32_16x16x32_bf16(a2, bh1, acc[2][1], 0, 0, 0);
                    acc[2][1] = __builtin_amdgcn_mfma_f32_16x16x32_bf16(a2, bl1, acc[2][1], 0, 0, 0);

                    acc[3][0] = __builtin_amdgcn_mfma_f32_16x16x32_bf16(a3, bh0, acc[3][0], 0, 0, 0);
                    acc[3][0] = __builtin_amdgcn_mfma_f32_16x16x32_bf16(a3, bl0, acc[3][0], 0, 0, 0);
                    acc[3][1] = __builtin_amdgcn_mfma_f32_16x16x32_bf16(a3, bh1, acc[3][1], 0, 0, 0);
                    acc[3][1] = __builtin_amdgcn_mfma_f32_16x16x32_bf16(a3, bl1, acc[3][1], 0, 0, 0);
                }
            }
        }
    }

    // bias + relu + store: D row (vox within 16-tile) = lg*4+r, col (oc) = lr
    int vbase = (z * 64 + y) * 64;
    #pragma unroll
    for (int vt = 0; vt < 4; ++vt) {
        #pragma unroll
        for (int t = 0; t < 2; ++t) {
            float bias = b2[t * 16 + lr];
            #pragma unroll
            for (int r = 0; r < 4; ++r) {
                int xv = vbase + vt * 16 + lg * 4 + r;
                pf[(size_t)xv * 32 + t * 16 + lr] = fmaxf(acc[vt][t][r] + bias, 0.f);
            }
        }
    }
}

// ------- epilogue v2: 2 voxels/thread, LDS head weights, batched pf loads, float4 logit stores -------
__global__ __launch_bounds__(256) void epilogue_kernel(
    const float* __restrict__ pf,     // [vox][32] post-relu
    const float* __restrict__ points, // [N][3]
    const float* __restrict__ ann,    // [512][4]
    const float* __restrict__ sem_w, const float* __restrict__ sem_b,
    const float* __restrict__ off_w, const float* __restrict__ off_b,
    float* __restrict__ out_logits,   // [N][20]
    float* __restrict__ out_off,      // [N][3]
    int* __restrict__ iv_out,         // [N]
    int* __restrict__ bad_seed)       // [512]
{
    __shared__ float4 sseed[NSEED];   // 8192 B
    __shared__ float  shw[764];       // sem_w[640], sem_b@640, off_w@660, off_b@756

    int tid = threadIdx.x;
    for (int i = tid; i < NSEED; i += 256) {
        float4 a = *reinterpret_cast<const float4*>(ann + i * 4);
        sseed[i] = make_float4(a.x, a.y, a.z, a.x*a.x + a.y*a.y + a.z*a.z);
    }
    for (int i = tid; i < 640; i += 256) shw[i] = sem_w[i];
    if (tid < NCLS) shw[640 + tid] = sem_b[tid];
    if (tid < 96)   shw[660 + tid] = off_w[tid];
    if (tid < 3)    shw[756 + tid] = off_b[tid];
    __syncthreads();

    int vA = blockIdx.x * 512 + tid;
    int vB = vA + 256;

    // batched pf loads: 16 b128 issued together
    float fA[32], fB[32];
    {
        float4 ra[8], rb[8];
        #pragma unroll
        for (int q = 0; q < 8; ++q) ra[q] = *reinterpret_cast<const float4*>(pf + (size_t)vA * 32 + q * 4);
        #pragma unroll
        for (int q = 0; q < 8; ++q) rb[q] = *reinterpret_cast<const float4*>(pf + (size_t)vB * 32 + q * 4);
        #pragma unroll
        for (int q = 0; q < 8; ++q) {
            fA[q*4+0] = ra[q].x; fA[q*4+1] = ra[q].y; fA[q*4+2] = ra[q].z; fA[q*4+3] = ra[q].w;
            fB[q*4+0] = rb[q].x; fB[q*4+1] = rb[q].y; fB[q*4+2] = rb[q].z; fB[q*4+3] = rb[q].w;
        }
    }

    // semantic heads (LDS broadcast weights); logits buffered, stored as float4 after
    float lA[20], lB[20];
    float bestA = -1e30f, bestB = -1e30f; int amA = 0, amB = 0;
    #pragma unroll
    for (int cc = 0; cc < NCLS; ++cc) {
        float a = shw[640 + cc], b = a;
        #pragma unroll
        for (int q = 0; q < 32; ++q) {
            float wv = shw[cc * 32 + q];
            a = fmaf(fA[q], wv, a);
            b = fmaf(fB[q], wv, b);
        }
        lA[cc] = a; lB[cc] = b;
        if (a > bestA) { bestA = a; amA = cc; }   // strict > = first occurrence
        if (b > bestB) { bestB = b; amB = cc; }
    }
    #pragma unroll
    for (int q5 = 0; q5 < 5; ++q5) {
        *reinterpret_cast<float4*>(out_logits + (size_t)vA * NCLS + q5 * 4) =
            make_float4(lA[q5*4], lA[q5*4+1], lA[q5*4+2], lA[q5*4+3]);
        *reinterpret_cast<float4*>(out_logits + (size_t)vB * NCLS + q5 * 4) =
            make_float4(lB[q5*4], lB[q5*4+1], lB[q5*4+2], lB[q5*4+3]);
    }

    // offset heads
    float offA[3], offB[3];
    #pragma unroll
    for (int k3 = 0; k3 < 3; ++k3) {
        float a = shw[756 + k3], b = a;
        #pragma unroll
        for (int q = 0; q < 32; ++q) {
            float wv = shw[660 + k3 * 32 + q];
            a = fmaf(fA[q], wv, a);
            b = fmaf(fB[q], wv, b);
        }
        out_off[(size_t)vA * 3 + k3] = a; offA[k3] = a;
        out_off[(size_t)vB * 3 + k3] = b; offB[k3] = b;
    }

    float pxA = points[(size_t)vA * 3 + 0] + offA[0];
    float pyA = points[(size_t)vA * 3 + 1] + offA[1];
    float pzA = points[(size_t)vA * 3 + 2] + offA[2];
    float pxB = points[(size_t)vB * 3 + 0] + offB[0];
    float pyB = points[(size_t)vB * 3 + 1] + offB[1];
    float pzB = points[(size_t)vB * 3 + 2] + offB[2];
    float cA = pxA*pxA + pyA*pyA + pzA*pzA;     // pp
    float cB = pxB*pxB + pyB*pyB + pzB*pzB;
    float mxA = -2.f*pxA, myA = -2.f*pyA, mzA = -2.f*pzA;
    float mxB = -2.f*pxB, myB = -2.f*pyB, mzB = -2.f*pzB;

    // seed argmin: one ds_read feeds two voxels' chains
    float bdA = 1e30f, bdB = 1e30f; int bjA = 0, bjB = 0;
    #pragma unroll 8
    for (int j = 0; j < NSEED; ++j) {
        float4 s = sseed[j];                    // broadcast, conflict-free
        float dA = fmaf(mxA, s.x, fmaf(myA, s.y, fmaf(mzA, s.z, cA + s.w)));
        float dB = fmaf(mxB, s.x, fmaf(myB, s.y, fmaf(mzB, s.z, cB + s.w)));
        if (dA < bdA) { bdA = dA; bjA = j; }    // strict < = first occurrence
        if (dB < bdB) { bdB = dB; bjB = j; }
    }
    bool validA = sqrtf(fmaxf(bdA, 0.f)) < 1.5f;
    bool validB = sqrtf(fmaxf(bdB, 0.f)) < 1.5f;

    int slabA = (int)ann[bjA * 4 + 3];
    int slabB = (int)ann[bjB * 4 + 3];
    if (validA && amA != slabA) atomicOr(&bad_seed[bjA], 1);
    if (validB && amB != slabB) atomicOr(&bad_seed[bjB], 1);
    iv_out[vA] = validA ? bjA : -1;
    iv_out[vB] = validB ? bjB : -1;
}

// ---------------- finalize pseudo labels ----------------
__global__ void finalize_kernel(const int* __restrict__ iv,
                                const int* __restrict__ bad,
                                float* __restrict__ pl) {
    int t = blockIdx.x * 256 + threadIdx.x;
    if (t >= NVOX) return;
    int v = iv[t];
    float r = -1.0f;
    if (v >= 0 && bad[v] == 0) r = (float)v;
    pl[t] = r;
}

extern "C" void kernel_launch(void* const* d_in, const int* in_sizes, int n_in,
                              void* d_out, int out_size, void* d_ws, size_t ws_size,
                              hipStream_t stream) {
    const float* points   = (const float*)d_in[0];
    const float* features = (const float*)d_in[1];
    const float* ann      = (const float*)d_in[2];
    const float* w1       = (const float*)d_in[3];
    const float* b1       = (const float*)d_in[4];
    const float* w2       = (const float*)d_in[5];
    const float* b2       = (const float*)d_in[6];
    const float* sem_w    = (const float*)d_in[7];
    const float* sem_b    = (const float*)d_in[8];
    const float* off_w    = (const float*)d_in[9];
    const float* off_b    = (const float*)d_in[10];

    float* out        = (float*)d_out;
    float* out_logits = out;
    float* out_off    = out + (size_t)NVOX * NCLS;   // N*20
    float* out_pl     = out + (size_t)NVOX * 23;     // N*23

    // workspace layout (bytes)
    char*  ws  = (char*)d_ws;
    float*          w1t  = (float*)         (ws);             //    41472 B
    int*            bad  = (int*)           (ws + 41472);     //     2048 B
    unsigned short* bfr  = (unsigned short*)(ws + 43520);     //   221184 B
    int*            iv   = (int*)           (ws + 264704);    //  1048576 B
    float*          pf   = (float*)         (ws + 1313280);   // 33554432 B
    unsigned short* h1hi = (unsigned short*)(ws + 34867712);  // 33554432 B

    hipMemsetAsync(bad, 0, NSEED * sizeof(int), stream);
    transpose_w1<<<41, 256, 0, stream>>>(w1, w1t);
    build_bfrags<<<54, 256, 0, stream>>>(w2, bfr);
    conv1_kernel<<<1024, 256, 0, stream>>>(features, w1t, b1, h1hi);
    conv2_mfma_kernel<<<1024, 256, 0, stream>>>(h1hi, bfr, b2, pf);
    epilogue_kernel<<<512, 256, 0, stream>>>(pf, points, ann,
        sem_w, sem_b, off_w, off_b, out_logits, out_off, iv, bad);
    finalize_kernel<<<1024, 256, 0, stream>>>(iv, bad, out_pl);
}

// Round 14
// 266.374 us; speedup vs baseline: 6.5074x; 1.0273x over previous
//
#include <hip/hip_runtime.h>

#define GRID 64
#define NVOX (GRID*GRID*GRID)
#define NCLS 20
#define NSEED 512

typedef __attribute__((ext_vector_type(8))) short short8_t;
typedef __attribute__((ext_vector_type(4))) float float4_t;

__device__ __forceinline__ unsigned short f32_to_bf16_rne(float f) {
    unsigned int x = __float_as_uint(f);
    unsigned int r = (x + 0x7fffu + ((x >> 16) & 1u)) >> 16;
    return (unsigned short)r;
}
__device__ __forceinline__ float bf16_to_f32(unsigned short u) {
    return __uint_as_float(((unsigned int)u) << 16);
}

// ------- w1 transpose + seed table prep -------
// t < 10368: w1t[(nb*6+ci)*64+oc] = w1[oc][ci][nb]
// t in [10368,10880): seedtab[i] = (x,y,z,|s|^2), slabtab[i] = label
__global__ void transpose_w1(const float* __restrict__ w1, float* __restrict__ w1t,
                             const float* __restrict__ ann, float* __restrict__ seedtab,
                             int* __restrict__ slabtab) {
    int t = blockIdx.x * 256 + threadIdx.x;
    if (t < 27 * 6 * 64) {
        int oc = t & 63;
        int r  = t >> 6;            // nb*6 + ci
        int nb = r / 6, ci = r % 6;
        w1t[t] = w1[oc * 162 + ci * 27 + nb];
        return;
    }
    int i = t - 27 * 6 * 64;
    if (i < NSEED) {
        float a0 = ann[i*4+0], a1 = ann[i*4+1], a2 = ann[i*4+2];
        *reinterpret_cast<float4*>(seedtab + i * 4) =
            make_float4(a0, a1, a2, a0*a0 + a1*a1 + a2*a2);
        slabtab[i] = (int)ann[i*4+3];
    }
}

// ------- build conv2 weight MFMA fragments (hi/lo bf16), 216 frags x 1KB -------
// frag f = ((nb*2+s)*2+t)*2+hl ; lane l elem j: B[ci=s*32+(l>>4)*8+j][oc=t*16+(l&15)]
__global__ void build_bfrags(const float* __restrict__ w2, unsigned short* __restrict__ bfr) {
    int t = blockIdx.x * 256 + threadIdx.x;      // over 216*64
    if (t >= 216 * 64) return;
    int l  = t & 63;
    int f  = t >> 6;
    int hl = f & 1;
    int tt = (f >> 1) & 1;
    int s  = (f >> 2) & 1;
    int nb = f >> 3;
    int lr = l & 15, lg = l >> 4;
    int oc = tt * 16 + lr;
    short8_t out;
    #pragma unroll
    for (int j = 0; j < 8; ++j) {
        int ci = s * 32 + lg * 8 + j;
        float wv = w2[oc * 1728 + ci * 27 + nb];
        unsigned short hi = f32_to_bf16_rne(wv);
        if (hl == 0) out[j] = (short)hi;
        else         out[j] = (short)f32_to_bf16_rne(wv - bf16_to_f32(hi));
    }
    *reinterpret_cast<short8_t*>(bfr + f * 512 + l * 8) = out;
}

// ------- conv1 (6->64): Zd=4, oc=16, all-tap LDS weights; batched loads; emits bf16-hi frag layout -------
// h1 frag layout per (z,y) plane (4096 elems): [xt(4)][s(2)][cc(4)][xl(16)][8ci]
__global__ __launch_bounds__(256, 4) void conv1_kernel(
    const float* __restrict__ feat,   // [6][NVOX]
    const float* __restrict__ w1t,    // [(nb*6+ci)][64]
    const float* __restrict__ b1,
    unsigned short* __restrict__ h1hi)
{
    __shared__ float lw[27 * 6 * 16]; // 10368 B

    int tid = threadIdx.x;
    int B = blockIdx.x;
    int zg = B & 7;
    int k  = B >> 3;
    int og = k & 3;                   // oc group of 16
    int zt = (k >> 2) & 1;
    int yt = (k >> 3) & 15;

    for (int t = tid; t < 27 * 6 * 16; t += 256)
        lw[t] = w1t[(t >> 4) * 64 + og * 16 + (t & 15)];
    __syncthreads();                  // the only barrier

    int x  = tid & 63;
    int y  = yt * 4 + (tid >> 6);     // wave-uniform
    int z0 = zg * 8 + zt * 4;

    float acc[4][16];
    #pragma unroll
    for (int r = 0; r < 4; ++r)
        #pragma unroll
        for (int o = 0; o < 16; ++o) acc[r][o] = 0.f;

    int zoffv[6]; float mzv[6];
    #pragma unroll
    for (int rz = 0; rz < 6; ++rz) {
        int gz = z0 - 1 + rz;
        int cz = gz < 0 ? 0 : (gz > 63 ? 63 : gz);
        zoffv[rz] = cz * 4096;
        mzv[rz] = ((unsigned)gz < 64u) ? 1.f : 0.f;
    }

    #pragma unroll 1
    for (int dydx = 0; dydx < 9; ++dydx) {
        int dy = dydx / 3 - 1;
        int dx = dydx % 3 - 1;
        int ny = y + dy;
        if ((unsigned)ny >= 64u) continue;             // wave-uniform zero-pad skip
        int nx = x + dx;
        float mx = ((unsigned)nx < 64u) ? 1.f : 0.f;
        int cx = nx < 0 ? 0 : (nx > 63 ? 63 : nx);
        int rowvox = ny * 64 + cx;

        float cm[6]; int voff[6];
        #pragma unroll
        for (int rz = 0; rz < 6; ++rz) { cm[rz] = mx * mzv[rz]; voff[rz] = zoffv[rz] + rowvox; }

        // 2 half-batches of 3 ci: 18 loads issued per window, then FMA
        #pragma unroll
        for (int cb = 0; cb < 2; ++cb) {
            float v[3][6];
            #pragma unroll
            for (int ci = 0; ci < 3; ++ci) {
                const float* plane = feat + (size_t)(cb * 3 + ci) * NVOX;
                #pragma unroll
                for (int rz = 0; rz < 6; ++rz) v[ci][rz] = plane[voff[rz]];
            }
            #pragma unroll
            for (int ci = 0; ci < 3; ++ci)
                #pragma unroll
                for (int rz = 0; rz < 6; ++rz) v[ci][rz] *= cm[rz];
            #pragma unroll
            for (int ci = 0; ci < 3; ++ci) {
                #pragma unroll
                for (int dzi = 0; dzi < 3; ++dzi) {
                    const float4* wp = reinterpret_cast<const float4*>(
                        &lw[(((dzi * 9 + dydx) * 6) + cb * 3 + ci) * 16]);
                    float4 w0 = wp[0], w1 = wp[1], w2 = wp[2], w3 = wp[3];
                    #pragma unroll
                    for (int r = 0; r < 4; ++r) {
                        float a = v[ci][r + dzi];
                        acc[r][0]  = fmaf(a, w0.x, acc[r][0]);
                        acc[r][1]  = fmaf(a, w0.y, acc[r][1]);
                        acc[r][2]  = fmaf(a, w0.z, acc[r][2]);
                        acc[r][3]  = fmaf(a, w0.w, acc[r][3]);
                        acc[r][4]  = fmaf(a, w1.x, acc[r][4]);
                        acc[r][5]  = fmaf(a, w1.y, acc[r][5]);
                        acc[r][6]  = fmaf(a, w1.z, acc[r][6]);
                        acc[r][7]  = fmaf(a, w1.w, acc[r][7]);
                        acc[r][8]  = fmaf(a, w2.x, acc[r][8]);
                        acc[r][9]  = fmaf(a, w2.y, acc[r][9]);
                        acc[r][10] = fmaf(a, w2.z, acc[r][10]);
                        acc[r][11] = fmaf(a, w2.w, acc[r][11]);
                        acc[r][12] = fmaf(a, w3.x, acc[r][12]);
                        acc[r][13] = fmaf(a, w3.y, acc[r][13]);
                        acc[r][14] = fmaf(a, w3.z, acc[r][14]);
                        acc[r][15] = fmaf(a, w3.w, acc[r][15]);
                    }
                }
            }
        }
    }

    float bias[16];
    #pragma unroll
    for (int o = 0; o < 16; ++o) bias[o] = b1[og * 16 + o];

    // frag-layout store (hi only): s = og>>1; cc = (og*2 + (o>>3)) & 3
    int s1 = og >> 1;
    int c0 = (og * 2) & 3;
    int c1 = (og * 2 + 1) & 3;
    #pragma unroll
    for (int zl = 0; zl < 4; ++zl) {
        size_t zy = ((size_t)((z0 + zl) * 64 + y)) * 4096;
        size_t base  = zy + (size_t)(x >> 4) * 1024 + (size_t)s1 * 512 + (size_t)(x & 15) * 8;
        short8_t hi0, hi1;
        #pragma unroll
        for (int o = 0; o < 8; ++o)
            hi0[o] = (short)f32_to_bf16_rne(fmaxf(acc[zl][o] + bias[o], 0.f));
        #pragma unroll
        for (int o = 8; o < 16; ++o)
            hi1[o - 8] = (short)f32_to_bf16_rne(fmaxf(acc[zl][o] + bias[o], 0.f));
        *reinterpret_cast<short8_t*>(h1hi + base + c0 * 128) = hi0;
        *reinterpret_cast<short8_t*>(h1hi + base + c1 * 128) = hi1;
    }
}

// ------- conv2 (64->32) MFMA + FUSED epilogue (LDS pf transpose; SGPR seed scan) -------
// grid 1024 = 8 zg (XCD, fastest) x 16 yt x 8 zl (slowest)
__global__ __launch_bounds__(256) void conv2_fused_kernel(
    const unsigned short* __restrict__ h1hi, // frag layout
    const unsigned short* __restrict__ bfr,  // [27][2s][2t][2hl][64][8] bf16
    const float* __restrict__ b2,
    const float* __restrict__ seedtab,       // [512][4] (x,y,z,|s|^2)
    const int* __restrict__ slabtab,         // [512]
    const float* __restrict__ points,
    const float* __restrict__ sem_w, const float* __restrict__ sem_b,
    const float* __restrict__ off_w, const float* __restrict__ off_b,
    float* __restrict__ out_logits,
    float* __restrict__ out_off,
    int* __restrict__ iv_out,
    int* __restrict__ bad_seed)
{
    __shared__ float pfs[256 * 36];   // [vl][36] padded, 36864 B
    __shared__ float shw[764];        // sem_w[640], sem_b@640, off_w@660, off_b@756

    int tid = threadIdx.x;
    for (int i = tid; i < 640; i += 256) shw[i] = sem_w[i];
    if (tid < NCLS) shw[640 + tid] = sem_b[tid];
    if (tid < 96)   shw[660 + tid] = off_w[tid];
    if (tid < 3)    shw[756 + tid] = off_b[tid];

    int w   = tid >> 6;
    int l   = tid & 63;
    int B   = blockIdx.x;
    int zg  = B & 7;
    int yt  = (B >> 3) & 15;
    int zl  = B >> 7;                 // 0..7 slowest
    int z   = zg * 8 + zl;
    int y   = yt * 4 + w;             // wave-uniform

    int lr = l & 15;
    int lg = l >> 4;

    // per-lane A offsets within a (z,y) plane for vt(4) x dxm(3), + validity
    int aoff[4][3]; bool aok[4][3];
    #pragma unroll
    for (int vt = 0; vt < 4; ++vt)
        #pragma unroll
        for (int dxm = 0; dxm < 3; ++dxm) {
            int v = vt * 16 + lr + dxm - 1;
            aok[vt][dxm] = (unsigned)v < 64u;
            int vc = v < 0 ? 0 : (v > 63 ? 63 : v);
            aoff[vt][dxm] = (vc >> 4) * 1024 + lg * 128 + (vc & 15) * 8;
        }

    const short8_t zero8 = (short8_t)0;
    float4_t acc[4][2];
    #pragma unroll
    for (int a = 0; a < 4; ++a)
        #pragma unroll
        for (int b = 0; b < 2; ++b) acc[a][b] = (float4_t)0.f;

    #pragma unroll 1
    for (int dzi = 0; dzi < 3; ++dzi) {
        int nz = z + dzi - 1;
        if ((unsigned)nz >= 64u) continue;            // wave-uniform
        #pragma unroll 1
        for (int dyi = 0; dyi < 3; ++dyi) {
            int ny = y + dyi - 1;
            if ((unsigned)ny >= 64u) continue;        // wave-uniform
            size_t zy = (size_t)(nz * 64 + ny) * 4096;
            #pragma unroll
            for (int dxm = 0; dxm < 3; ++dxm) {       // compile-time (rule #20)
                int nb = dzi * 9 + dyi * 3 + dxm;
                const unsigned short* bt = bfr + nb * 4096 + l * 8;
                #pragma unroll
                for (int s = 0; s < 2; ++s) {
                    const unsigned short* bs = bt + s * 2048;
                    short8_t bh0 = *reinterpret_cast<const short8_t*>(bs);
                    short8_t bl0 = *reinterpret_cast<const short8_t*>(bs + 512);
                    short8_t bh1 = *reinterpret_cast<const short8_t*>(bs + 1024);
                    short8_t bl1 = *reinterpret_cast<const short8_t*>(bs + 1536);

                    const unsigned short* ph = h1hi + zy + s * 512;
                    short8_t a0 = aok[0][dxm] ? *reinterpret_cast<const short8_t*>(ph + aoff[0][dxm]) : zero8;
                    short8_t a1 = aok[1][dxm] ? *reinterpret_cast<const short8_t*>(ph + aoff[1][dxm]) : zero8;
                    short8_t a2 = aok[2][dxm] ? *reinterpret_cast<const short8_t*>(ph + aoff[2][dxm]) : zero8;
                    short8_t a3 = aok[3][dxm] ? *reinterpret_cast<const short8_t*>(ph + aoff[3][dxm]) : zero8;

                    acc[0][0] = __builtin_amdgcn_mfma_f32_16x16x32_bf16(a0, bh0, acc[0][0], 0, 0, 0);
                    acc[0][0] = __builtin_amdgcn_mfma_f32_16x16x32_bf16(a0, bl0, acc[0][0], 0, 0, 0);
                    acc[0][1] = __builtin_amdgcn_mfma_f32_16x16x32_bf16(a0, bh1, acc[0][1], 0, 0, 0);
                    acc[0][1] = __builtin_amdgcn_mfma_f32_16x16x32_bf16(a0, bl1, acc[0][1], 0, 0, 0);

                    acc[1][0] = __builtin_amdgcn_mfma_f32_16x16x32_bf16(a1, bh0, acc[1][0], 0, 0, 0);
                    acc[1][0] = __builtin_amdgcn_mfma_f32_16x16x32_bf16(a1, bl0, acc[1][0], 0, 0, 0);
                    acc[1][1] = __builtin_amdgcn_mfma_f32_16x16x32_bf16(a1, bh1, acc[1][1], 0, 0, 0);
                    acc[1][1] = __builtin_amdgcn_mfma_f32_16x16x32_bf16(a1, bl1, acc[1][1], 0, 0, 0);

                    acc[2][0] = __builtin_amdgcn_mfma_f32_16x16x32_bf16(a2, bh0, acc[2][0], 0, 0, 0);
                    acc[2][0] = __builtin_amdgcn_mfma_f32_16x16x32_bf16(a2, bl0, acc[2][0], 0, 0, 0);
                    acc[2][1] = __builtin_amdgcn_mfma_f32_16x16x32_bf16(a2, bh1, acc[2][1], 0, 0, 0);
                    acc[2][1] = __builtin_amdgcn_mfma_f32_16x16x32_bf16(a2, bl1, acc[2][1], 0, 0, 0);

                    acc[3][0] = __builtin_amdgcn_mfma_f32_16x16x32_bf16(a3, bh0, acc[3][0], 0, 0, 0);
                    acc[3][0] = __builtin_amdgcn_mfma_f32_16x16x32_bf16(a3, bl0, acc[3][0], 0, 0, 0);
                    acc[3][1] = __builtin_amdgcn_mfma_f32_16x16x32_bf16(a3, bh1, acc[3][1], 0, 0, 0);
                    acc[3][1] = __builtin_amdgcn_mfma_f32_16x16x32_bf16(a3, bl1, acc[3][1], 0, 0, 0);
                }
            }
        }
    }

    // ---- bias + relu -> LDS transpose buffer (write conflicts 2-way = free) ----
    #pragma unroll
    for (int vt = 0; vt < 4; ++vt) {
        #pragma unroll
        for (int t = 0; t < 2; ++t) {
            float bias = b2[t * 16 + lr];
            #pragma unroll
            for (int r = 0; r < 4; ++r) {
                int vl = w * 64 + vt * 16 + lg * 4 + r;
                pfs[vl * 36 + t * 16 + lr] = fmaxf(acc[vt][t][r] + bias, 0.f);
            }
        }
    }
    __syncthreads();

    // ---- per-thread epilogue: voxel vl = tid ----
    int ex = tid & 63, ey = yt * 4 + (tid >> 6);
    int vox = (z * 64 + ey) * 64 + ex;

    float f[32];
    #pragma unroll
    for (int q = 0; q < 8; ++q) {
        float4 v4 = *reinterpret_cast<const float4*>(&pfs[tid * 36 + q * 4]);
        f[q*4+0] = v4.x; f[q*4+1] = v4.y; f[q*4+2] = v4.z; f[q*4+3] = v4.w;
    }

    // semantic head + argmax (strict > = first occurrence)
    float lbuf[20];
    float best = -1e30f; int am = 0;
    #pragma unroll
    for (int cc = 0; cc < NCLS; ++cc) {
        float a = shw[640 + cc];
        #pragma unroll
        for (int q = 0; q < 32; ++q) a = fmaf(f[q], shw[cc * 32 + q], a);
        lbuf[cc] = a;
        if (a > best) { best = a; am = cc; }
    }
    #pragma unroll
    for (int q5 = 0; q5 < 5; ++q5)
        *reinterpret_cast<float4*>(out_logits + (size_t)vox * NCLS + q5 * 4) =
            make_float4(lbuf[q5*4], lbuf[q5*4+1], lbuf[q5*4+2], lbuf[q5*4+3]);

    // offset head
    float off[3];
    #pragma unroll
    for (int k3 = 0; k3 < 3; ++k3) {
        float a = shw[756 + k3];
        #pragma unroll
        for (int q = 0; q < 32; ++q) a = fmaf(f[q], shw[660 + k3 * 32 + q], a);
        out_off[(size_t)vox * 3 + k3] = a;
        off[k3] = a;
    }

    float px = points[(size_t)vox * 3 + 0] + off[0];
    float py = points[(size_t)vox * 3 + 1] + off[1];
    float pz = points[(size_t)vox * 3 + 2] + off[2];
    float c  = px*px + py*py + pz*pz;
    float mx = -2.f*px, my = -2.f*py, mz = -2.f*pz;

    // seed scan via wave-uniform loads (scalar pipe), strict < = first occurrence
    float bd = 1e30f; int bj = 0;
    #pragma unroll 4
    for (int j = 0; j < NSEED; ++j) {
        float4 s = *reinterpret_cast<const float4*>(seedtab + j * 4);  // uniform -> s_load
        float d = fmaf(mx, s.x, fmaf(my, s.y, fmaf(mz, s.z, c + s.w)));
        if (d < bd) { bd = d; bj = j; }
    }
    bool valid = sqrtf(fmaxf(bd, 0.f)) < 1.5f;

    int slab = slabtab[bj];
    if (valid && am != slab) atomicOr(&bad_seed[bj], 1);
    iv_out[vox] = valid ? bj : -1;
}

// ---------------- finalize pseudo labels ----------------
__global__ void finalize_kernel(const int* __restrict__ iv,
                                const int* __restrict__ bad,
                                float* __restrict__ pl) {
    int t = blockIdx.x * 256 + threadIdx.x;
    if (t >= NVOX) return;
    int v = iv[t];
    float r = -1.0f;
    if (v >= 0 && bad[v] == 0) r = (float)v;
    pl[t] = r;
}

extern "C" void kernel_launch(void* const* d_in, const int* in_sizes, int n_in,
                              void* d_out, int out_size, void* d_ws, size_t ws_size,
                              hipStream_t stream) {
    const float* points   = (const float*)d_in[0];
    const float* features = (const float*)d_in[1];
    const float* ann      = (const float*)d_in[2];
    const float* w1       = (const float*)d_in[3];
    const float* b1       = (const float*)d_in[4];
    const float* w2       = (const float*)d_in[5];
    const float* b2       = (const float*)d_in[6];
    const float* sem_w    = (const float*)d_in[7];
    const float* sem_b    = (const float*)d_in[8];
    const float* off_w    = (const float*)d_in[9];
    const float* off_b    = (const float*)d_in[10];

    float* out        = (float*)d_out;
    float* out_logits = out;
    float* out_off    = out + (size_t)NVOX * NCLS;   // N*20
    float* out_pl     = out + (size_t)NVOX * 23;     // N*23

    // workspace layout (bytes)
    char*  ws  = (char*)d_ws;
    float*          w1t     = (float*)         (ws);             //    41472 B
    int*            bad     = (int*)           (ws + 41472);     //     2048 B
    unsigned short* bfr     = (unsigned short*)(ws + 43520);     //   221184 B
    int*            iv      = (int*)           (ws + 264704);    //  1048576 B
    float*          seedtab = (float*)         (ws + 1313280);   //     8192 B
    int*            slabtab = (int*)           (ws + 1321472);   //     2048 B
    unsigned short* h1hi    = (unsigned short*)(ws + 34867712);  // 33554432 B

    hipMemsetAsync(bad, 0, NSEED * sizeof(int), stream);
    transpose_w1<<<43, 256, 0, stream>>>(w1, w1t, ann, seedtab, slabtab);
    build_bfrags<<<54, 256, 0, stream>>>(w2, bfr);
    conv1_kernel<<<1024, 256, 0, stream>>>(features, w1t, b1, h1hi);
    conv2_fused_kernel<<<1024, 256, 0, stream>>>(h1hi, bfr, b2, seedtab, slabtab,
        points, sem_w, sem_b, off_w, off_b, out_logits, out_off, iv, bad);
    finalize_kernel<<<1024, 256, 0, stream>>>(iv, bad, out_pl);
}

// Round 15
// 222.669 us; speedup vs baseline: 7.7847x; 1.1963x over previous
//
#include <hip/hip_runtime.h>

#define GRID 64
#define NVOX (GRID*GRID*GRID)
#define NCLS 20
#define NSEED 512

typedef __attribute__((ext_vector_type(8))) short short8_t;
typedef __attribute__((ext_vector_type(4))) float float4_t;

__device__ __forceinline__ unsigned short f32_to_bf16_rne(float f) {
    unsigned int x = __float_as_uint(f);
    unsigned int r = (x + 0x7fffu + ((x >> 16) & 1u)) >> 16;
    return (unsigned short)r;
}
__device__ __forceinline__ float bf16_to_f32(unsigned short u) {
    return __uint_as_float(((unsigned int)u) << 16);
}

// ------- w1 transpose + seed table prep -------
__global__ void transpose_w1(const float* __restrict__ w1, float* __restrict__ w1t,
                             const float* __restrict__ ann, float* __restrict__ seedtab,
                             int* __restrict__ slabtab) {
    int t = blockIdx.x * 256 + threadIdx.x;
    if (t < 27 * 6 * 64) {
        int oc = t & 63;
        int r  = t >> 6;            // nb*6 + ci
        int nb = r / 6, ci = r % 6;
        w1t[t] = w1[oc * 162 + ci * 27 + nb];
        return;
    }
    int i = t - 27 * 6 * 64;
    if (i < NSEED) {
        float a0 = ann[i*4+0], a1 = ann[i*4+1], a2 = ann[i*4+2];
        *reinterpret_cast<float4*>(seedtab + i * 4) =
            make_float4(a0, a1, a2, a0*a0 + a1*a1 + a2*a2);
        slabtab[i] = (int)ann[i*4+3];
    }
}

// ------- build conv2 weight MFMA fragments (hi/lo bf16), 216 frags x 1KB -------
__global__ void build_bfrags(const float* __restrict__ w2, unsigned short* __restrict__ bfr) {
    int t = blockIdx.x * 256 + threadIdx.x;      // over 216*64
    if (t >= 216 * 64) return;
    int l  = t & 63;
    int f  = t >> 6;
    int hl = f & 1;
    int tt = (f >> 1) & 1;
    int s  = (f >> 2) & 1;
    int nb = f >> 3;
    int lr = l & 15, lg = l >> 4;
    int oc = tt * 16 + lr;
    short8_t out;
    #pragma unroll
    for (int j = 0; j < 8; ++j) {
        int ci = s * 32 + lg * 8 + j;
        float wv = w2[oc * 1728 + ci * 27 + nb];
        unsigned short hi = f32_to_bf16_rne(wv);
        if (hl == 0) out[j] = (short)hi;
        else         out[j] = (short)f32_to_bf16_rne(wv - bf16_to_f32(hi));
    }
    *reinterpret_cast<short8_t*>(bfr + f * 512 + l * 8) = out;
}

// ------- conv1 (6->64): Zd=4, oc=16, all-tap LDS weights; batched loads; emits bf16-hi frag layout -------
// h1 frag layout per (z,y) plane (4096 elems): [xt(4)][s(2)][cc(4)][xl(16)][8ci]
__global__ __launch_bounds__(256, 4) void conv1_kernel(
    const float* __restrict__ feat,   // [6][NVOX]
    const float* __restrict__ w1t,    // [(nb*6+ci)][64]
    const float* __restrict__ b1,
    unsigned short* __restrict__ h1hi)
{
    __shared__ float lw[27 * 6 * 16]; // 10368 B

    int tid = threadIdx.x;
    int B = blockIdx.x;
    int zg = B & 7;
    int k  = B >> 3;
    int og = k & 3;                   // oc group of 16
    int zt = (k >> 2) & 1;
    int yt = (k >> 3) & 15;

    for (int t = tid; t < 27 * 6 * 16; t += 256)
        lw[t] = w1t[(t >> 4) * 64 + og * 16 + (t & 15)];
    __syncthreads();                  // the only barrier

    int x  = tid & 63;
    int y  = yt * 4 + (tid >> 6);     // wave-uniform
    int z0 = zg * 8 + zt * 4;

    float acc[4][16];
    #pragma unroll
    for (int r = 0; r < 4; ++r)
        #pragma unroll
        for (int o = 0; o < 16; ++o) acc[r][o] = 0.f;

    int zoffv[6]; float mzv[6];
    #pragma unroll
    for (int rz = 0; rz < 6; ++rz) {
        int gz = z0 - 1 + rz;
        int cz = gz < 0 ? 0 : (gz > 63 ? 63 : gz);
        zoffv[rz] = cz * 4096;
        mzv[rz] = ((unsigned)gz < 64u) ? 1.f : 0.f;
    }

    #pragma unroll 1
    for (int dydx = 0; dydx < 9; ++dydx) {
        int dy = dydx / 3 - 1;
        int dx = dydx % 3 - 1;
        int ny = y + dy;
        if ((unsigned)ny >= 64u) continue;             // wave-uniform zero-pad skip
        int nx = x + dx;
        float mx = ((unsigned)nx < 64u) ? 1.f : 0.f;
        int cx = nx < 0 ? 0 : (nx > 63 ? 63 : nx);
        int rowvox = ny * 64 + cx;

        float cm[6]; int voff[6];
        #pragma unroll
        for (int rz = 0; rz < 6; ++rz) { cm[rz] = mx * mzv[rz]; voff[rz] = zoffv[rz] + rowvox; }

        // 2 half-batches of 3 ci: 18 loads issued per window, then FMA
        #pragma unroll
        for (int cb = 0; cb < 2; ++cb) {
            float v[3][6];
            #pragma unroll
            for (int ci = 0; ci < 3; ++ci) {
                const float* plane = feat + (size_t)(cb * 3 + ci) * NVOX;
                #pragma unroll
                for (int rz = 0; rz < 6; ++rz) v[ci][rz] = plane[voff[rz]];
            }
            #pragma unroll
            for (int ci = 0; ci < 3; ++ci)
                #pragma unroll
                for (int rz = 0; rz < 6; ++rz) v[ci][rz] *= cm[rz];
            #pragma unroll
            for (int ci = 0; ci < 3; ++ci) {
                #pragma unroll
                for (int dzi = 0; dzi < 3; ++dzi) {
                    const float4* wp = reinterpret_cast<const float4*>(
                        &lw[(((dzi * 9 + dydx) * 6) + cb * 3 + ci) * 16]);
                    float4 w0 = wp[0], w1 = wp[1], w2 = wp[2], w3 = wp[3];
                    #pragma unroll
                    for (int r = 0; r < 4; ++r) {
                        float a = v[ci][r + dzi];
                        acc[r][0]  = fmaf(a, w0.x, acc[r][0]);
                        acc[r][1]  = fmaf(a, w0.y, acc[r][1]);
                        acc[r][2]  = fmaf(a, w0.z, acc[r][2]);
                        acc[r][3]  = fmaf(a, w0.w, acc[r][3]);
                        acc[r][4]  = fmaf(a, w1.x, acc[r][4]);
                        acc[r][5]  = fmaf(a, w1.y, acc[r][5]);
                        acc[r][6]  = fmaf(a, w1.z, acc[r][6]);
                        acc[r][7]  = fmaf(a, w1.w, acc[r][7]);
                        acc[r][8]  = fmaf(a, w2.x, acc[r][8]);
                        acc[r][9]  = fmaf(a, w2.y, acc[r][9]);
                        acc[r][10] = fmaf(a, w2.z, acc[r][10]);
                        acc[r][11] = fmaf(a, w2.w, acc[r][11]);
                        acc[r][12] = fmaf(a, w3.x, acc[r][12]);
                        acc[r][13] = fmaf(a, w3.y, acc[r][13]);
                        acc[r][14] = fmaf(a, w3.z, acc[r][14]);
                        acc[r][15] = fmaf(a, w3.w, acc[r][15]);
                    }
                }
            }
        }
    }

    float bias[16];
    #pragma unroll
    for (int o = 0; o < 16; ++o) bias[o] = b1[og * 16 + o];

    // frag-layout store (hi only): s = og>>1; cc = (og*2 + (o>>3)) & 3
    int s1 = og >> 1;
    int c0 = (og * 2) & 3;
    int c1 = (og * 2 + 1) & 3;
    #pragma unroll
    for (int zl = 0; zl < 4; ++zl) {
        size_t zy = ((size_t)((z0 + zl) * 64 + y)) * 4096;
        size_t base  = zy + (size_t)(x >> 4) * 1024 + (size_t)s1 * 512 + (size_t)(x & 15) * 8;
        short8_t hi0, hi1;
        #pragma unroll
        for (int o = 0; o < 8; ++o)
            hi0[o] = (short)f32_to_bf16_rne(fmaxf(acc[zl][o] + bias[o], 0.f));
        #pragma unroll
        for (int o = 8; o < 16; ++o)
            hi1[o - 8] = (short)f32_to_bf16_rne(fmaxf(acc[zl][o] + bias[o], 0.f));
        *reinterpret_cast<short8_t*>(h1hi + base + c0 * 128) = hi0;
        *reinterpret_cast<short8_t*>(h1hi + base + c1 * 128) = hi1;
    }
}

// ------- conv2 (64->32) MFMA + fused epilogue; NO global atomics (LDS flags -> bitmap) -------
// grid 1024 = 8 zg (XCD, fastest) x 16 yt x 8 zl (slowest)
__global__ __launch_bounds__(256) void conv2_fused_kernel(
    const unsigned short* __restrict__ h1hi, // frag layout
    const unsigned short* __restrict__ bfr,  // [27][2s][2t][2hl][64][8] bf16
    const float* __restrict__ b2,
    const float* __restrict__ seedtab,       // [512][4] (x,y,z,|s|^2)
    const int* __restrict__ slabtab,         // [512]
    const float* __restrict__ points,
    const float* __restrict__ sem_w, const float* __restrict__ sem_b,
    const float* __restrict__ off_w, const float* __restrict__ off_b,
    float* __restrict__ out_logits,
    float* __restrict__ out_off,
    int* __restrict__ iv_out,
    unsigned* __restrict__ bitmapT)          // [16 words][1024 blocks]
{
    __shared__ float pfs[256 * 36];   // [vl][36] padded, 36864 B
    __shared__ int   lbad[NSEED];     // 2048 B  (total 38912 -> 4 blocks/CU)

    int tid = threadIdx.x;
    lbad[tid] = 0;
    lbad[tid + 256] = 0;

    int w   = tid >> 6;
    int l   = tid & 63;
    int B   = blockIdx.x;
    int zg  = B & 7;
    int yt  = (B >> 3) & 15;
    int zl  = B >> 7;                 // 0..7 slowest
    int z   = zg * 8 + zl;
    int y   = yt * 4 + w;             // wave-uniform

    int lr = l & 15;
    int lg = l >> 4;

    // per-lane A offsets within a (z,y) plane for vt(4) x dxm(3), + validity
    int aoff[4][3]; bool aok[4][3];
    #pragma unroll
    for (int vt = 0; vt < 4; ++vt)
        #pragma unroll
        for (int dxm = 0; dxm < 3; ++dxm) {
            int v = vt * 16 + lr + dxm - 1;
            aok[vt][dxm] = (unsigned)v < 64u;
            int vc = v < 0 ? 0 : (v > 63 ? 63 : v);
            aoff[vt][dxm] = (vc >> 4) * 1024 + lg * 128 + (vc & 15) * 8;
        }

    const short8_t zero8 = (short8_t)0;
    float4_t acc[4][2];
    #pragma unroll
    for (int a = 0; a < 4; ++a)
        #pragma unroll
        for (int b = 0; b < 2; ++b) acc[a][b] = (float4_t)0.f;

    #pragma unroll 1
    for (int dzi = 0; dzi < 3; ++dzi) {
        int nz = z + dzi - 1;
        if ((unsigned)nz >= 64u) continue;            // wave-uniform
        #pragma unroll 1
        for (int dyi = 0; dyi < 3; ++dyi) {
            int ny = y + dyi - 1;
            if ((unsigned)ny >= 64u) continue;        // wave-uniform
            size_t zy = (size_t)(nz * 64 + ny) * 4096;
            #pragma unroll
            for (int dxm = 0; dxm < 3; ++dxm) {       // compile-time (rule #20)
                int nb = dzi * 9 + dyi * 3 + dxm;
                const unsigned short* bt = bfr + nb * 4096 + l * 8;
                #pragma unroll
                for (int s = 0; s < 2; ++s) {
                    const unsigned short* bs = bt + s * 2048;
                    short8_t bh0 = *reinterpret_cast<const short8_t*>(bs);
                    short8_t bl0 = *reinterpret_cast<const short8_t*>(bs + 512);
                    short8_t bh1 = *reinterpret_cast<const short8_t*>(bs + 1024);
                    short8_t bl1 = *reinterpret_cast<const short8_t*>(bs + 1536);

                    const unsigned short* ph = h1hi + zy + s * 512;
                    short8_t a0 = aok[0][dxm] ? *reinterpret_cast<const short8_t*>(ph + aoff[0][dxm]) : zero8;
                    short8_t a1 = aok[1][dxm] ? *reinterpret_cast<const short8_t*>(ph + aoff[1][dxm]) : zero8;
                    short8_t a2 = aok[2][dxm] ? *reinterpret_cast<const short8_t*>(ph + aoff[2][dxm]) : zero8;
                    short8_t a3 = aok[3][dxm] ? *reinterpret_cast<const short8_t*>(ph + aoff[3][dxm]) : zero8;

                    acc[0][0] = __builtin_amdgcn_mfma_f32_16x16x32_bf16(a0, bh0, acc[0][0], 0, 0, 0);
                    acc[0][0] = __builtin_amdgcn_mfma_f32_16x16x32_bf16(a0, bl0, acc[0][0], 0, 0, 0);
                    acc[0][1] = __builtin_amdgcn_mfma_f32_16x16x32_bf16(a0, bh1, acc[0][1], 0, 0, 0);
                    acc[0][1] = __builtin_amdgcn_mfma_f32_16x16x32_bf16(a0, bl1, acc[0][1], 0, 0, 0);

                    acc[1][0] = __builtin_amdgcn_mfma_f32_16x16x32_bf16(a1, bh0, acc[1][0], 0, 0, 0);
                    acc[1][0] = __builtin_amdgcn_mfma_f32_16x16x32_bf16(a1, bl0, acc[1][0], 0, 0, 0);
                    acc[1][1] = __builtin_amdgcn_mfma_f32_16x16x32_bf16(a1, bh1, acc[1][1], 0, 0, 0);
                    acc[1][1] = __builtin_amdgcn_mfma_f32_16x16x32_bf16(a1, bl1, acc[1][1], 0, 0, 0);

                    acc[2][0] = __builtin_amdgcn_mfma_f32_16x16x32_bf16(a2, bh0, acc[2][0], 0, 0, 0);
                    acc[2][0] = __builtin_amdgcn_mfma_f32_16x16x32_bf16(a2, bl0, acc[2][0], 0, 0, 0);
                    acc[2][1] = __builtin_amdgcn_mfma_f32_16x16x32_bf16(a2, bh1, acc[2][1], 0, 0, 0);
                    acc[2][1] = __builtin_amdgcn_mfma_f32_16x16x32_bf16(a2, bl1, acc[2][1], 0, 0, 0);

                    acc[3][0] = __builtin_amdgcn_mfma_f32_16x16x32_bf16(a3, bh0, acc[3][0], 0, 0, 0);
                    acc[3][0] = __builtin_amdgcn_mfma_f32_16x16x32_bf16(a3, bl0, acc[3][0], 0, 0, 0);
                    acc[3][1] = __builtin_amdgcn_mfma_f32_16x16x32_bf16(a3, bh1, acc[3][1], 0, 0, 0);
                    acc[3][1] = __builtin_amdgcn_mfma_f32_16x16x32_bf16(a3, bl1, acc[3][1], 0, 0, 0);
                }
            }
        }
    }

    // ---- bias + relu -> LDS transpose buffer ----
    #pragma unroll
    for (int vt = 0; vt < 4; ++vt) {
        #pragma unroll
        for (int t = 0; t < 2; ++t) {
            float bias = b2[t * 16 + lr];
            #pragma unroll
            for (int r = 0; r < 4; ++r) {
                int vl = w * 64 + vt * 16 + lg * 4 + r;
                pfs[vl * 36 + t * 16 + lr] = fmaxf(acc[vt][t][r] + bias, 0.f);
            }
        }
    }
    __syncthreads();   // also publishes lbad zero-init

    // ---- per-thread epilogue: voxel vl = tid ----
    int ex = tid & 63, ey = yt * 4 + (tid >> 6);
    int vox = (z * 64 + ey) * 64 + ex;

    float f[32];
    #pragma unroll
    for (int q = 0; q < 8; ++q) {
        float4 v4 = *reinterpret_cast<const float4*>(&pfs[tid * 36 + q * 4]);
        f[q*4+0] = v4.x; f[q*4+1] = v4.y; f[q*4+2] = v4.z; f[q*4+3] = v4.w;
    }

    // semantic head + argmax (wave-uniform weight indices -> s_load; strict > = first occurrence)
    float lbuf[20];
    float best = -1e30f; int am = 0;
    #pragma unroll
    for (int cc = 0; cc < NCLS; ++cc) {
        float a = sem_b[cc];
        #pragma unroll
        for (int q = 0; q < 32; ++q) a = fmaf(f[q], sem_w[cc * 32 + q], a);
        lbuf[cc] = a;
        if (a > best) { best = a; am = cc; }
    }
    #pragma unroll
    for (int q5 = 0; q5 < 5; ++q5)
        *reinterpret_cast<float4*>(out_logits + (size_t)vox * NCLS + q5 * 4) =
            make_float4(lbuf[q5*4], lbuf[q5*4+1], lbuf[q5*4+2], lbuf[q5*4+3]);

    // offset head
    float off[3];
    #pragma unroll
    for (int k3 = 0; k3 < 3; ++k3) {
        float a = off_b[k3];
        #pragma unroll
        for (int q = 0; q < 32; ++q) a = fmaf(f[q], off_w[k3 * 32 + q], a);
        out_off[(size_t)vox * 3 + k3] = a;
        off[k3] = a;
    }

    float px = points[(size_t)vox * 3 + 0] + off[0];
    float py = points[(size_t)vox * 3 + 1] + off[1];
    float pz = points[(size_t)vox * 3 + 2] + off[2];
    float c  = px*px + py*py + pz*pz;
    float mx = -2.f*px, my = -2.f*py, mz = -2.f*pz;

    // seed scan (wave-uniform s_load), strict < = first occurrence
    float bd = 1e30f; int bj = 0;
    #pragma unroll 4
    for (int j = 0; j < NSEED; ++j) {
        float4 s = *reinterpret_cast<const float4*>(seedtab + j * 4);
        float d = fmaf(mx, s.x, fmaf(my, s.y, fmaf(mz, s.z, c + s.w)));
        if (d < bd) { bd = d; bj = j; }
    }
    bool valid = sqrtf(fmaxf(bd, 0.f)) < 1.5f;

    int slab = slabtab[bj];
    if (valid && am != slab) atomicOr(&lbad[bj], 1);   // LDS atomic only
    iv_out[vox] = valid ? bj : -1;

    __syncthreads();
    // compact 512 flags -> 16 bitmap words; plain global stores (no atomics)
    if (tid < 16) {
        unsigned wd = 0;
        #pragma unroll
        for (int i = 0; i < 32; ++i)
            wd |= (lbad[tid * 32 + i] ? 1u : 0u) << i;
        bitmapT[tid * 1024 + B] = wd;
    }
}

// ------- reduce per-block bitmaps -> badw[16] -------
__global__ __launch_bounds__(256) void reduce_bad(const unsigned* __restrict__ bitmapT,
                                                  unsigned* __restrict__ badw) {
    __shared__ unsigned red[256];
    int w = blockIdx.x;      // word 0..15
    int tid = threadIdx.x;
    const unsigned* src = bitmapT + w * 1024;
    unsigned v = src[tid] | src[tid + 256] | src[tid + 512] | src[tid + 768];
    red[tid] = v;
    __syncthreads();
    #pragma unroll
    for (int s = 128; s > 0; s >>= 1) {
        if (tid < s) red[tid] |= red[tid + s];
        __syncthreads();
    }
    if (tid == 0) badw[w] = red[0];
}

// ---------------- finalize pseudo labels (bitmap test) ----------------
__global__ void finalize_kernel(const int* __restrict__ iv,
                                const unsigned* __restrict__ badw,
                                float* __restrict__ pl) {
    int t = blockIdx.x * 256 + threadIdx.x;
    if (t >= NVOX) return;
    int v = iv[t];
    float r = -1.0f;
    if (v >= 0 && !((badw[v >> 5] >> (v & 31)) & 1u)) r = (float)v;
    pl[t] = r;
}

extern "C" void kernel_launch(void* const* d_in, const int* in_sizes, int n_in,
                              void* d_out, int out_size, void* d_ws, size_t ws_size,
                              hipStream_t stream) {
    const float* points   = (const float*)d_in[0];
    const float* features = (const float*)d_in[1];
    const float* ann      = (const float*)d_in[2];
    const float* w1       = (const float*)d_in[3];
    const float* b1       = (const float*)d_in[4];
    const float* w2       = (const float*)d_in[5];
    const float* b2       = (const float*)d_in[6];
    const float* sem_w    = (const float*)d_in[7];
    const float* sem_b    = (const float*)d_in[8];
    const float* off_w    = (const float*)d_in[9];
    const float* off_b    = (const float*)d_in[10];

    float* out        = (float*)d_out;
    float* out_logits = out;
    float* out_off    = out + (size_t)NVOX * NCLS;   // N*20
    float* out_pl     = out + (size_t)NVOX * 23;     // N*23

    // workspace layout (bytes)
    char*  ws  = (char*)d_ws;
    float*          w1t     = (float*)         (ws);             //    41472 B
    unsigned*       badw    = (unsigned*)      (ws + 41472);     //       64 B
    unsigned short* bfr     = (unsigned short*)(ws + 43520);     //   221184 B
    int*            iv      = (int*)           (ws + 264704);    //  1048576 B
    float*          seedtab = (float*)         (ws + 1313280);   //     8192 B
    int*            slabtab = (int*)           (ws + 1321472);   //     2048 B
    unsigned*       bitmapT = (unsigned*)      (ws + 1323520);   //    65536 B
    unsigned short* h1hi    = (unsigned short*)(ws + 34867712);  // 33554432 B

    transpose_w1<<<43, 256, 0, stream>>>(w1, w1t, ann, seedtab, slabtab);
    build_bfrags<<<54, 256, 0, stream>>>(w2, bfr);
    conv1_kernel<<<1024, 256, 0, stream>>>(features, w1t, b1, h1hi);
    conv2_fused_kernel<<<1024, 256, 0, stream>>>(h1hi, bfr, b2, seedtab, slabtab,
        points, sem_w, sem_b, off_w, off_b, out_logits, out_off, iv, bitmapT);
    reduce_bad<<<16, 256, 0, stream>>>(bitmapT, badw);
    finalize_kernel<<<1024, 256, 0, stream>>>(iv, badw, out_pl);
}

// Round 16
// 196.600 us; speedup vs baseline: 8.8169x; 1.1326x over previous
//
#include <hip/hip_runtime.h>

#define GRID 64
#define NVOX (GRID*GRID*GRID)
#define NCLS 20
#define NSEED 512

typedef __attribute__((ext_vector_type(8))) short short8_t;
typedef __attribute__((ext_vector_type(4))) float float4_t;

__device__ __forceinline__ unsigned short f32_to_bf16_rne(float f) {
    unsigned int x = __float_as_uint(f);
    unsigned int r = (x + 0x7fffu + ((x >> 16) & 1u)) >> 16;
    return (unsigned short)r;
}
__device__ __forceinline__ float bf16_to_f32(unsigned short u) {
    return __uint_as_float(((unsigned int)u) << 16);
}

// ------- w1 transpose + seed table prep -------
__global__ void transpose_w1(const float* __restrict__ w1, float* __restrict__ w1t,
                             const float* __restrict__ ann, float* __restrict__ seedtab,
                             int* __restrict__ slabtab) {
    int t = blockIdx.x * 256 + threadIdx.x;
    if (t < 27 * 6 * 64) {
        int oc = t & 63;
        int r  = t >> 6;            // nb*6 + ci
        int nb = r / 6, ci = r % 6;
        w1t[t] = w1[oc * 162 + ci * 27 + nb];
        return;
    }
    int i = t - 27 * 6 * 64;
    if (i < NSEED) {
        float a0 = ann[i*4+0], a1 = ann[i*4+1], a2 = ann[i*4+2];
        *reinterpret_cast<float4*>(seedtab + i * 4) =
            make_float4(a0, a1, a2, a0*a0 + a1*a1 + a2*a2);
        slabtab[i] = (int)ann[i*4+3];
    }
}

// ------- build conv2 weight MFMA fragments (hi/lo bf16), 216 frags x 1KB -------
__global__ void build_bfrags(const float* __restrict__ w2, unsigned short* __restrict__ bfr) {
    int t = blockIdx.x * 256 + threadIdx.x;      // over 216*64
    if (t >= 216 * 64) return;
    int l  = t & 63;
    int f  = t >> 6;
    int hl = f & 1;
    int tt = (f >> 1) & 1;
    int s  = (f >> 2) & 1;
    int nb = f >> 3;
    int lr = l & 15, lg = l >> 4;
    int oc = tt * 16 + lr;
    short8_t out;
    #pragma unroll
    for (int j = 0; j < 8; ++j) {
        int ci = s * 32 + lg * 8 + j;
        float wv = w2[oc * 1728 + ci * 27 + nb];
        unsigned short hi = f32_to_bf16_rne(wv);
        if (hl == 0) out[j] = (short)hi;
        else         out[j] = (short)f32_to_bf16_rne(wv - bf16_to_f32(hi));
    }
    *reinterpret_cast<short8_t*>(bfr + f * 512 + l * 8) = out;
}

// ------- conv1 (6->64): Zd=4, oc=16, all-tap LDS weights; batched loads; emits bf16-hi frag layout -------
// h1 frag layout per (z,y) plane (4096 elems): [xt(4)][s(2)][cc(4)][xl(16)][8ci]
__global__ __launch_bounds__(256, 4) void conv1_kernel(
    const float* __restrict__ feat,   // [6][NVOX]
    const float* __restrict__ w1t,    // [(nb*6+ci)][64]
    const float* __restrict__ b1,
    unsigned short* __restrict__ h1hi)
{
    __shared__ float lw[27 * 6 * 16]; // 10368 B

    int tid = threadIdx.x;
    int B = blockIdx.x;
    int zg = B & 7;
    int k  = B >> 3;
    int og = k & 3;                   // oc group of 16
    int zt = (k >> 2) & 1;
    int yt = (k >> 3) & 15;

    for (int t = tid; t < 27 * 6 * 16; t += 256)
        lw[t] = w1t[(t >> 4) * 64 + og * 16 + (t & 15)];
    __syncthreads();                  // the only barrier

    int x  = tid & 63;
    int y  = yt * 4 + (tid >> 6);     // wave-uniform
    int z0 = zg * 8 + zt * 4;

    float acc[4][16];
    #pragma unroll
    for (int r = 0; r < 4; ++r)
        #pragma unroll
        for (int o = 0; o < 16; ++o) acc[r][o] = 0.f;

    int zoffv[6]; float mzv[6];
    #pragma unroll
    for (int rz = 0; rz < 6; ++rz) {
        int gz = z0 - 1 + rz;
        int cz = gz < 0 ? 0 : (gz > 63 ? 63 : gz);
        zoffv[rz] = cz * 4096;
        mzv[rz] = ((unsigned)gz < 64u) ? 1.f : 0.f;
    }

    #pragma unroll 1
    for (int dydx = 0; dydx < 9; ++dydx) {
        int dy = dydx / 3 - 1;
        int dx = dydx % 3 - 1;
        int ny = y + dy;
        if ((unsigned)ny >= 64u) continue;             // wave-uniform zero-pad skip
        int nx = x + dx;
        float mx = ((unsigned)nx < 64u) ? 1.f : 0.f;
        int cx = nx < 0 ? 0 : (nx > 63 ? 63 : nx);
        int rowvox = ny * 64 + cx;

        float cm[6]; int voff[6];
        #pragma unroll
        for (int rz = 0; rz < 6; ++rz) { cm[rz] = mx * mzv[rz]; voff[rz] = zoffv[rz] + rowvox; }

        // 2 half-batches of 3 ci: 18 loads issued per window, then FMA
        #pragma unroll
        for (int cb = 0; cb < 2; ++cb) {
            float v[3][6];
            #pragma unroll
            for (int ci = 0; ci < 3; ++ci) {
                const float* plane = feat + (size_t)(cb * 3 + ci) * NVOX;
                #pragma unroll
                for (int rz = 0; rz < 6; ++rz) v[ci][rz] = plane[voff[rz]];
            }
            #pragma unroll
            for (int ci = 0; ci < 3; ++ci)
                #pragma unroll
                for (int rz = 0; rz < 6; ++rz) v[ci][rz] *= cm[rz];
            #pragma unroll
            for (int ci = 0; ci < 3; ++ci) {
                #pragma unroll
                for (int dzi = 0; dzi < 3; ++dzi) {
                    const float4* wp = reinterpret_cast<const float4*>(
                        &lw[(((dzi * 9 + dydx) * 6) + cb * 3 + ci) * 16]);
                    float4 w0 = wp[0], w1 = wp[1], w2 = wp[2], w3 = wp[3];
                    #pragma unroll
                    for (int r = 0; r < 4; ++r) {
                        float a = v[ci][r + dzi];
                        acc[r][0]  = fmaf(a, w0.x, acc[r][0]);
                        acc[r][1]  = fmaf(a, w0.y, acc[r][1]);
                        acc[r][2]  = fmaf(a, w0.z, acc[r][2]);
                        acc[r][3]  = fmaf(a, w0.w, acc[r][3]);
                        acc[r][4]  = fmaf(a, w1.x, acc[r][4]);
                        acc[r][5]  = fmaf(a, w1.y, acc[r][5]);
                        acc[r][6]  = fmaf(a, w1.z, acc[r][6]);
                        acc[r][7]  = fmaf(a, w1.w, acc[r][7]);
                        acc[r][8]  = fmaf(a, w2.x, acc[r][8]);
                        acc[r][9]  = fmaf(a, w2.y, acc[r][9]);
                        acc[r][10] = fmaf(a, w2.z, acc[r][10]);
                        acc[r][11] = fmaf(a, w2.w, acc[r][11]);
                        acc[r][12] = fmaf(a, w3.x, acc[r][12]);
                        acc[r][13] = fmaf(a, w3.y, acc[r][13]);
                        acc[r][14] = fmaf(a, w3.z, acc[r][14]);
                        acc[r][15] = fmaf(a, w3.w, acc[r][15]);
                    }
                }
            }
        }
    }

    float bias[16];
    #pragma unroll
    for (int o = 0; o < 16; ++o) bias[o] = b1[og * 16 + o];

    // frag-layout store (hi only): s = og>>1; cc = (og*2 + (o>>3)) & 3
    int s1 = og >> 1;
    int c0 = (og * 2) & 3;
    int c1 = (og * 2 + 1) & 3;
    #pragma unroll
    for (int zl = 0; zl < 4; ++zl) {
        size_t zy = ((size_t)((z0 + zl) * 64 + y)) * 4096;
        size_t base  = zy + (size_t)(x >> 4) * 1024 + (size_t)s1 * 512 + (size_t)(x & 15) * 8;
        short8_t hi0, hi1;
        #pragma unroll
        for (int o = 0; o < 8; ++o)
            hi0[o] = (short)f32_to_bf16_rne(fmaxf(acc[zl][o] + bias[o], 0.f));
        #pragma unroll
        for (int o = 8; o < 16; ++o)
            hi1[o - 8] = (short)f32_to_bf16_rne(fmaxf(acc[zl][o] + bias[o], 0.f));
        *reinterpret_cast<short8_t*>(h1hi + base + c0 * 128) = hi0;
        *reinterpret_cast<short8_t*>(h1hi + base + c1 * 128) = hi1;
    }
}

// ------- conv2 (64->32) MFMA + fused epilogue; bf16 LDS transpose (22.5KB); 4-chain argmin -------
// grid 1024 = 8 zg (XCD, fastest) x 16 yt x 8 zl (slowest)
__global__ __launch_bounds__(256) void conv2_fused_kernel(
    const unsigned short* __restrict__ h1hi, // frag layout
    const unsigned short* __restrict__ bfr,  // [27][2s][2t][2hl][64][8] bf16
    const float* __restrict__ b2,
    const float* __restrict__ seedtab,       // [512][4] (x,y,z,|s|^2)
    const int* __restrict__ slabtab,         // [512]
    const float* __restrict__ points,
    const float* __restrict__ sem_w, const float* __restrict__ sem_b,
    const float* __restrict__ off_w, const float* __restrict__ off_b,
    float* __restrict__ out_logits,
    float* __restrict__ out_off,
    int* __restrict__ iv_out,
    unsigned* __restrict__ bitmapT)          // [16 words][1024 blocks]
{
    __shared__ unsigned short pfs[256 * 40]; // bf16, stride 40 (16B-aligned b128), 20480 B
    __shared__ int lbad[NSEED];              // 2048 B  (total 22528 -> up to 7 blocks/CU)

    int tid = threadIdx.x;
    lbad[tid] = 0;
    lbad[tid + 256] = 0;

    int w   = tid >> 6;
    int l   = tid & 63;
    int B   = blockIdx.x;
    int zg  = B & 7;
    int yt  = (B >> 3) & 15;
    int zl  = B >> 7;                 // 0..7 slowest
    int z   = zg * 8 + zl;
    int y   = yt * 4 + w;             // wave-uniform

    int lr = l & 15;
    int lg = l >> 4;

    // per-lane A offsets within a (z,y) plane for vt(4) x dxm(3), + validity
    int aoff[4][3]; bool aok[4][3];
    #pragma unroll
    for (int vt = 0; vt < 4; ++vt)
        #pragma unroll
        for (int dxm = 0; dxm < 3; ++dxm) {
            int v = vt * 16 + lr + dxm - 1;
            aok[vt][dxm] = (unsigned)v < 64u;
            int vc = v < 0 ? 0 : (v > 63 ? 63 : v);
            aoff[vt][dxm] = (vc >> 4) * 1024 + lg * 128 + (vc & 15) * 8;
        }

    const short8_t zero8 = (short8_t)0;
    float4_t acc[4][2];
    #pragma unroll
    for (int a = 0; a < 4; ++a)
        #pragma unroll
        for (int b = 0; b < 2; ++b) acc[a][b] = (float4_t)0.f;

    #pragma unroll 1
    for (int dzi = 0; dzi < 3; ++dzi) {
        int nz = z + dzi - 1;
        if ((unsigned)nz >= 64u) continue;            // wave-uniform
        #pragma unroll 1
        for (int dyi = 0; dyi < 3; ++dyi) {
            int ny = y + dyi - 1;
            if ((unsigned)ny >= 64u) continue;        // wave-uniform
            size_t zy = (size_t)(nz * 64 + ny) * 4096;
            #pragma unroll
            for (int dxm = 0; dxm < 3; ++dxm) {       // compile-time (rule #20)
                int nb = dzi * 9 + dyi * 3 + dxm;
                const unsigned short* bt = bfr + nb * 4096 + l * 8;
                #pragma unroll
                for (int s = 0; s < 2; ++s) {
                    const unsigned short* bs = bt + s * 2048;
                    short8_t bh0 = *reinterpret_cast<const short8_t*>(bs);
                    short8_t bl0 = *reinterpret_cast<const short8_t*>(bs + 512);
                    short8_t bh1 = *reinterpret_cast<const short8_t*>(bs + 1024);
                    short8_t bl1 = *reinterpret_cast<const short8_t*>(bs + 1536);

                    const unsigned short* ph = h1hi + zy + s * 512;
                    short8_t a0 = aok[0][dxm] ? *reinterpret_cast<const short8_t*>(ph + aoff[0][dxm]) : zero8;
                    short8_t a1 = aok[1][dxm] ? *reinterpret_cast<const short8_t*>(ph + aoff[1][dxm]) : zero8;
                    short8_t a2 = aok[2][dxm] ? *reinterpret_cast<const short8_t*>(ph + aoff[2][dxm]) : zero8;
                    short8_t a3 = aok[3][dxm] ? *reinterpret_cast<const short8_t*>(ph + aoff[3][dxm]) : zero8;

                    acc[0][0] = __builtin_amdgcn_mfma_f32_16x16x32_bf16(a0, bh0, acc[0][0], 0, 0, 0);
                    acc[0][0] = __builtin_amdgcn_mfma_f32_16x16x32_bf16(a0, bl0, acc[0][0], 0, 0, 0);
                    acc[0][1] = __builtin_amdgcn_mfma_f32_16x16x32_bf16(a0, bh1, acc[0][1], 0, 0, 0);
                    acc[0][1] = __builtin_amdgcn_mfma_f32_16x16x32_bf16(a0, bl1, acc[0][1], 0, 0, 0);

                    acc[1][0] = __builtin_amdgcn_mfma_f32_16x16x32_bf16(a1, bh0, acc[1][0], 0, 0, 0);
                    acc[1][0] = __builtin_amdgcn_mfma_f32_16x16x32_bf16(a1, bl0, acc[1][0], 0, 0, 0);
                    acc[1][1] = __builtin_amdgcn_mfma_f32_16x16x32_bf16(a1, bh1, acc[1][1], 0, 0, 0);
                    acc[1][1] = __builtin_amdgcn_mfma_f32_16x16x32_bf16(a1, bl1, acc[1][1], 0, 0, 0);

                    acc[2][0] = __builtin_amdgcn_mfma_f32_16x16x32_bf16(a2, bh0, acc[2][0], 0, 0, 0);
                    acc[2][0] = __builtin_amdgcn_mfma_f32_16x16x32_bf16(a2, bl0, acc[2][0], 0, 0, 0);
                    acc[2][1] = __builtin_amdgcn_mfma_f32_16x16x32_bf16(a2, bh1, acc[2][1], 0, 0, 0);
                    acc[2][1] = __builtin_amdgcn_mfma_f32_16x16x32_bf16(a2, bl1, acc[2][1], 0, 0, 0);

                    acc[3][0] = __builtin_amdgcn_mfma_f32_16x16x32_bf16(a3, bh0, acc[3][0], 0, 0, 0);
                    acc[3][0] = __builtin_amdgcn_mfma_f32_16x16x32_bf16(a3, bl0, acc[3][0], 0, 0, 0);
                    acc[3][1] = __builtin_amdgcn_mfma_f32_16x16x32_bf16(a3, bh1, acc[3][1], 0, 0, 0);
                    acc[3][1] = __builtin_amdgcn_mfma_f32_16x16x32_bf16(a3, bl1, acc[3][1], 0, 0, 0);
                }
            }
        }
    }

    // ---- bias + relu -> LDS transpose buffer (bf16) ----
    #pragma unroll
    for (int vt = 0; vt < 4; ++vt) {
        #pragma unroll
        for (int t = 0; t < 2; ++t) {
            float bias = b2[t * 16 + lr];
            #pragma unroll
            for (int r = 0; r < 4; ++r) {
                int vl = w * 64 + vt * 16 + lg * 4 + r;
                pfs[vl * 40 + t * 16 + lr] = f32_to_bf16_rne(fmaxf(acc[vt][t][r] + bias, 0.f));
            }
        }
    }
    __syncthreads();   // also publishes lbad zero-init

    // ---- per-thread epilogue: voxel vl = tid ----
    int ex = tid & 63, ey = yt * 4 + (tid >> 6);
    int vox = (z * 64 + ey) * 64 + ex;

    float f[32];
    #pragma unroll
    for (int q = 0; q < 4; ++q) {
        short8_t v8 = *reinterpret_cast<const short8_t*>(&pfs[tid * 40 + q * 8]);
        #pragma unroll
        for (int kk = 0; kk < 8; ++kk) f[q*8+kk] = bf16_to_f32((unsigned short)v8[kk]);
    }

    // semantic head + argmax (wave-uniform weight indices -> s_load; strict > = first occurrence)
    float lbuf[20];
    float best = -1e30f; int am = 0;
    #pragma unroll
    for (int cc = 0; cc < NCLS; ++cc) {
        float a = sem_b[cc];
        #pragma unroll
        for (int q = 0; q < 32; ++q) a = fmaf(f[q], sem_w[cc * 32 + q], a);
        lbuf[cc] = a;
        if (a > best) { best = a; am = cc; }
    }
    #pragma unroll
    for (int q5 = 0; q5 < 5; ++q5)
        *reinterpret_cast<float4*>(out_logits + (size_t)vox * NCLS + q5 * 4) =
            make_float4(lbuf[q5*4], lbuf[q5*4+1], lbuf[q5*4+2], lbuf[q5*4+3]);

    // offset head
    float off[3];
    #pragma unroll
    for (int k3 = 0; k3 < 3; ++k3) {
        float a = off_b[k3];
        #pragma unroll
        for (int q = 0; q < 32; ++q) a = fmaf(f[q], off_w[k3 * 32 + q], a);
        out_off[(size_t)vox * 3 + k3] = a;
        off[k3] = a;
    }

    float px = points[(size_t)vox * 3 + 0] + off[0];
    float py = points[(size_t)vox * 3 + 1] + off[1];
    float pz = points[(size_t)vox * 3 + 2] + off[2];
    float c  = px*px + py*py + pz*pz;
    float mx = -2.f*px, my = -2.f*py, mz = -2.f*pz;

    // seed scan: 4 interleaved chains (ILP on the min dependency), s_load seeds
    float bd0 = 1e30f, bd1 = 1e30f, bd2 = 1e30f, bd3 = 1e30f;
    int   bj0 = 0,     bj1 = 0,     bj2 = 0,     bj3 = 0;
    #pragma unroll 2
    for (int j = 0; j < NSEED; j += 4) {
        float4 s0 = *reinterpret_cast<const float4*>(seedtab + (j + 0) * 4);
        float4 s1 = *reinterpret_cast<const float4*>(seedtab + (j + 1) * 4);
        float4 s2 = *reinterpret_cast<const float4*>(seedtab + (j + 2) * 4);
        float4 s3 = *reinterpret_cast<const float4*>(seedtab + (j + 3) * 4);
        float d0 = fmaf(mx, s0.x, fmaf(my, s0.y, fmaf(mz, s0.z, c + s0.w)));
        float d1 = fmaf(mx, s1.x, fmaf(my, s1.y, fmaf(mz, s1.z, c + s1.w)));
        float d2 = fmaf(mx, s2.x, fmaf(my, s2.y, fmaf(mz, s2.z, c + s2.w)));
        float d3 = fmaf(mx, s3.x, fmaf(my, s3.y, fmaf(mz, s3.z, c + s3.w)));
        if (d0 < bd0) { bd0 = d0; bj0 = j; }          // strict < per chain
        if (d1 < bd1) { bd1 = d1; bj1 = j + 1; }
        if (d2 < bd2) { bd2 = d2; bj2 = j + 2; }
        if (d3 < bd3) { bd3 = d3; bj3 = j + 3; }
    }
    // merge with index tie-break -> global first occurrence
    bool p01 = (bd0 < bd1) || (bd0 == bd1 && bj0 < bj1);
    float bdA = p01 ? bd0 : bd1; int bjA = p01 ? bj0 : bj1;
    bool p23 = (bd2 < bd3) || (bd2 == bd3 && bj2 < bj3);
    float bdB = p23 ? bd2 : bd3; int bjB = p23 ? bj2 : bj3;
    bool pAB = (bdA < bdB) || (bdA == bdB && bjA < bjB);
    float bd = pAB ? bdA : bdB; int bj = pAB ? bjA : bjB;

    bool valid = sqrtf(fmaxf(bd, 0.f)) < 1.5f;

    int slab = slabtab[bj];
    if (valid && am != slab) atomicOr(&lbad[bj], 1);   // LDS atomic only
    iv_out[vox] = valid ? bj : -1;

    __syncthreads();
    // compact 512 flags -> 16 bitmap words; plain global stores (no atomics)
    if (tid < 16) {
        unsigned wd = 0;
        #pragma unroll
        for (int i = 0; i < 32; ++i)
            wd |= (lbad[tid * 32 + i] ? 1u : 0u) << i;
        bitmapT[tid * 1024 + B] = wd;
    }
}

// ------- reduce per-block bitmaps -> badw[16] -------
__global__ __launch_bounds__(256) void reduce_bad(const unsigned* __restrict__ bitmapT,
                                                  unsigned* __restrict__ badw) {
    __shared__ unsigned red[256];
    int w = blockIdx.x;      // word 0..15
    int tid = threadIdx.x;
    const unsigned* src = bitmapT + w * 1024;
    unsigned v = src[tid] | src[tid + 256] | src[tid + 512] | src[tid + 768];
    red[tid] = v;
    __syncthreads();
    #pragma unroll
    for (int s = 128; s > 0; s >>= 1) {
        if (tid < s) red[tid] |= red[tid + s];
        __syncthreads();
    }
    if (tid == 0) badw[w] = red[0];
}

// ---------------- finalize pseudo labels (bitmap test) ----------------
__global__ void finalize_kernel(const int* __restrict__ iv,
                                const unsigned* __restrict__ badw,
                                float* __restrict__ pl) {
    int t = blockIdx.x * 256 + threadIdx.x;
    if (t >= NVOX) return;
    int v = iv[t];
    float r = -1.0f;
    if (v >= 0 && !((badw[v >> 5] >> (v & 31)) & 1u)) r = (float)v;
    pl[t] = r;
}

extern "C" void kernel_launch(void* const* d_in, const int* in_sizes, int n_in,
                              void* d_out, int out_size, void* d_ws, size_t ws_size,
                              hipStream_t stream) {
    const float* points   = (const float*)d_in[0];
    const float* features = (const float*)d_in[1];
    const float* ann      = (const float*)d_in[2];
    const float* w1       = (const float*)d_in[3];
    const float* b1       = (const float*)d_in[4];
    const float* w2       = (const float*)d_in[5];
    const float* b2       = (const float*)d_in[6];
    const float* sem_w    = (const float*)d_in[7];
    const float* sem_b    = (const float*)d_in[8];
    const float* off_w    = (const float*)d_in[9];
    const float* off_b    = (const float*)d_in[10];

    float* out        = (float*)d_out;
    float* out_logits = out;
    float* out_off    = out + (size_t)NVOX * NCLS;   // N*20
    float* out_pl     = out + (size_t)NVOX * 23;     // N*23

    // workspace layout (bytes)
    char*  ws  = (char*)d_ws;
    float*          w1t     = (float*)         (ws);             //    41472 B
    unsigned*       badw    = (unsigned*)      (ws + 41472);     //       64 B
    unsigned short* bfr     = (unsigned short*)(ws + 43520);     //   221184 B
    int*            iv      = (int*)           (ws + 264704);    //  1048576 B
    float*          seedtab = (float*)         (ws + 1313280);   //     8192 B
    int*            slabtab = (int*)           (ws + 1321472);   //     2048 B
    unsigned*       bitmapT = (unsigned*)      (ws + 1323520);   //    65536 B
    unsigned short* h1hi    = (unsigned short*)(ws + 34867712);  // 33554432 B

    transpose_w1<<<43, 256, 0, stream>>>(w1, w1t, ann, seedtab, slabtab);
    build_bfrags<<<54, 256, 0, stream>>>(w2, bfr);
    conv1_kernel<<<1024, 256, 0, stream>>>(features, w1t, b1, h1hi);
    conv2_fused_kernel<<<1024, 256, 0, stream>>>(h1hi, bfr, b2, seedtab, slabtab,
        points, sem_w, sem_b, off_w, off_b, out_logits, out_off, iv, bitmapT);
    reduce_bad<<<16, 256, 0, stream>>>(bitmapT, badw);
    finalize_kernel<<<1024, 256, 0, stream>>>(iv, badw, out_pl);
}

// Round 17
// 179.509 us; speedup vs baseline: 9.6564x; 1.0952x over previous
//
#include <hip/hip_runtime.h>

#define GRID 64
#define NVOX (GRID*GRID*GRID)
#define NCLS 20
#define NSEED 512

typedef __attribute__((ext_vector_type(8))) short short8_t;
typedef __attribute__((ext_vector_type(4))) float float4_t;

__device__ __forceinline__ unsigned short f32_to_bf16_rne(float f) {
    unsigned int x = __float_as_uint(f);
    unsigned int r = (x + 0x7fffu + ((x >> 16) & 1u)) >> 16;
    return (unsigned short)r;
}
__device__ __forceinline__ float bf16_to_f32(unsigned short u) {
    return __uint_as_float(((unsigned int)u) << 16);
}

// ------- w1 transpose + seed table prep -------
__global__ void transpose_w1(const float* __restrict__ w1, float* __restrict__ w1t,
                             const float* __restrict__ ann, float* __restrict__ seedtab,
                             int* __restrict__ slabtab) {
    int t = blockIdx.x * 256 + threadIdx.x;
    if (t < 27 * 6 * 64) {
        int oc = t & 63;
        int r  = t >> 6;            // nb*6 + ci
        int nb = r / 6, ci = r % 6;
        w1t[t] = w1[oc * 162 + ci * 27 + nb];
        return;
    }
    int i = t - 27 * 6 * 64;
    if (i < NSEED) {
        float a0 = ann[i*4+0], a1 = ann[i*4+1], a2 = ann[i*4+2];
        *reinterpret_cast<float4*>(seedtab + i * 4) =
            make_float4(a0, a1, a2, a0*a0 + a1*a1 + a2*a2);
        slabtab[i] = (int)ann[i*4+3];
    }
}

// ------- build conv2 weight MFMA fragments (bf16 hi only), 108 frags x 1KB -------
// frag f = (nb*2+s)*2+t ; lane l elem j: B[ci=s*32+(l>>4)*8+j][oc=t*16+(l&15)]
__global__ void build_bfrags(const float* __restrict__ w2, unsigned short* __restrict__ bfr) {
    int t = blockIdx.x * 256 + threadIdx.x;      // over 108*64
    if (t >= 108 * 64) return;
    int l  = t & 63;
    int f  = t >> 6;
    int tt = f & 1;
    int s  = (f >> 1) & 1;
    int nb = f >> 2;
    int lr = l & 15, lg = l >> 4;
    int oc = tt * 16 + lr;
    short8_t out;
    #pragma unroll
    for (int j = 0; j < 8; ++j) {
        int ci = s * 32 + lg * 8 + j;
        out[j] = (short)f32_to_bf16_rne(w2[oc * 1728 + ci * 27 + nb]);
    }
    *reinterpret_cast<short8_t*>(bfr + f * 512 + l * 8) = out;
}

// ------- conv1 (6->64): Zd=4, oc=16, all-tap LDS weights; batched loads; emits bf16-hi frag layout -------
// h1 frag layout per (z,y) plane (4096 elems): [xt(4)][s(2)][cc(4)][xl(16)][8ci]
__global__ __launch_bounds__(256, 4) void conv1_kernel(
    const float* __restrict__ feat,   // [6][NVOX]
    const float* __restrict__ w1t,    // [(nb*6+ci)][64]
    const float* __restrict__ b1,
    unsigned short* __restrict__ h1hi)
{
    __shared__ float lw[27 * 6 * 16]; // 10368 B

    int tid = threadIdx.x;
    int B = blockIdx.x;
    int zg = B & 7;
    int k  = B >> 3;
    int og = k & 3;                   // oc group of 16
    int zt = (k >> 2) & 1;
    int yt = (k >> 3) & 15;

    for (int t = tid; t < 27 * 6 * 16; t += 256)
        lw[t] = w1t[(t >> 4) * 64 + og * 16 + (t & 15)];
    __syncthreads();                  // the only barrier

    int x  = tid & 63;
    int y  = yt * 4 + (tid >> 6);     // wave-uniform
    int z0 = zg * 8 + zt * 4;

    float acc[4][16];
    #pragma unroll
    for (int r = 0; r < 4; ++r)
        #pragma unroll
        for (int o = 0; o < 16; ++o) acc[r][o] = 0.f;

    int zoffv[6]; float mzv[6];
    #pragma unroll
    for (int rz = 0; rz < 6; ++rz) {
        int gz = z0 - 1 + rz;
        int cz = gz < 0 ? 0 : (gz > 63 ? 63 : gz);
        zoffv[rz] = cz * 4096;
        mzv[rz] = ((unsigned)gz < 64u) ? 1.f : 0.f;
    }

    #pragma unroll 1
    for (int dydx = 0; dydx < 9; ++dydx) {
        int dy = dydx / 3 - 1;
        int dx = dydx % 3 - 1;
        int ny = y + dy;
        if ((unsigned)ny >= 64u) continue;             // wave-uniform zero-pad skip
        int nx = x + dx;
        float mx = ((unsigned)nx < 64u) ? 1.f : 0.f;
        int cx = nx < 0 ? 0 : (nx > 63 ? 63 : nx);
        int rowvox = ny * 64 + cx;

        float cm[6]; int voff[6];
        #pragma unroll
        for (int rz = 0; rz < 6; ++rz) { cm[rz] = mx * mzv[rz]; voff[rz] = zoffv[rz] + rowvox; }

        // 2 half-batches of 3 ci: 18 loads issued per window, then FMA
        #pragma unroll
        for (int cb = 0; cb < 2; ++cb) {
            float v[3][6];
            #pragma unroll
            for (int ci = 0; ci < 3; ++ci) {
                const float* plane = feat + (size_t)(cb * 3 + ci) * NVOX;
                #pragma unroll
                for (int rz = 0; rz < 6; ++rz) v[ci][rz] = plane[voff[rz]];
            }
            #pragma unroll
            for (int ci = 0; ci < 3; ++ci)
                #pragma unroll
                for (int rz = 0; rz < 6; ++rz) v[ci][rz] *= cm[rz];
            #pragma unroll
            for (int ci = 0; ci < 3; ++ci) {
                #pragma unroll
                for (int dzi = 0; dzi < 3; ++dzi) {
                    const float4* wp = reinterpret_cast<const float4*>(
                        &lw[(((dzi * 9 + dydx) * 6) + cb * 3 + ci) * 16]);
                    float4 w0 = wp[0], w1 = wp[1], w2 = wp[2], w3 = wp[3];
                    #pragma unroll
                    for (int r = 0; r < 4; ++r) {
                        float a = v[ci][r + dzi];
                        acc[r][0]  = fmaf(a, w0.x, acc[r][0]);
                        acc[r][1]  = fmaf(a, w0.y, acc[r][1]);
                        acc[r][2]  = fmaf(a, w0.z, acc[r][2]);
                        acc[r][3]  = fmaf(a, w0.w, acc[r][3]);
                        acc[r][4]  = fmaf(a, w1.x, acc[r][4]);
                        acc[r][5]  = fmaf(a, w1.y, acc[r][5]);
                        acc[r][6]  = fmaf(a, w1.z, acc[r][6]);
                        acc[r][7]  = fmaf(a, w1.w, acc[r][7]);
                        acc[r][8]  = fmaf(a, w2.x, acc[r][8]);
                        acc[r][9]  = fmaf(a, w2.y, acc[r][9]);
                        acc[r][10] = fmaf(a, w2.z, acc[r][10]);
                        acc[r][11] = fmaf(a, w2.w, acc[r][11]);
                        acc[r][12] = fmaf(a, w3.x, acc[r][12]);
                        acc[r][13] = fmaf(a, w3.y, acc[r][13]);
                        acc[r][14] = fmaf(a, w3.z, acc[r][14]);
                        acc[r][15] = fmaf(a, w3.w, acc[r][15]);
                    }
                }
            }
        }
    }

    float bias[16];
    #pragma unroll
    for (int o = 0; o < 16; ++o) bias[o] = b1[og * 16 + o];

    // frag-layout store (hi only): s = og>>1; cc = (og*2 + (o>>3)) & 3
    int s1 = og >> 1;
    int c0 = (og * 2) & 3;
    int c1 = (og * 2 + 1) & 3;
    #pragma unroll
    for (int zl = 0; zl < 4; ++zl) {
        size_t zy = ((size_t)((z0 + zl) * 64 + y)) * 4096;
        size_t base  = zy + (size_t)(x >> 4) * 1024 + (size_t)s1 * 512 + (size_t)(x & 15) * 8;
        short8_t hi0, hi1;
        #pragma unroll
        for (int o = 0; o < 8; ++o)
            hi0[o] = (short)f32_to_bf16_rne(fmaxf(acc[zl][o] + bias[o], 0.f));
        #pragma unroll
        for (int o = 8; o < 16; ++o)
            hi1[o - 8] = (short)f32_to_bf16_rne(fmaxf(acc[zl][o] + bias[o], 0.f));
        *reinterpret_cast<short8_t*>(h1hi + base + c0 * 128) = hi0;
        *reinterpret_cast<short8_t*>(h1hi + base + c1 * 128) = hi1;
    }
}

// ------- conv2 (64->32) MFMA (B=bf16) + fused epilogue; wave-private LDS A-row dx-sharing -------
// grid 1024 = 8 zg (XCD, fastest) x 16 yt x 8 zl (slowest)
__global__ __launch_bounds__(256) void conv2_fused_kernel(
    const unsigned short* __restrict__ h1hi, // frag layout
    const unsigned short* __restrict__ bfr,  // [27][2s][2t][64][8] bf16 (hi only)
    const float* __restrict__ b2,
    const float* __restrict__ seedtab,       // [512][4] (x,y,z,|s|^2)
    const int* __restrict__ slabtab,         // [512]
    const float* __restrict__ points,
    const float* __restrict__ sem_w, const float* __restrict__ sem_b,
    const float* __restrict__ off_w, const float* __restrict__ off_b,
    float* __restrict__ out_logits,
    float* __restrict__ out_off,
    int* __restrict__ iv_out,
    unsigned* __restrict__ bitmapT)          // [16 words][1024 blocks]
{
    __shared__ unsigned short smem[4 * 4096]; // per-wave A-row staging; reused as pf store. 32 KB
    __shared__ int lbad[NSEED];               // 2048 B  (total 34 KB -> 4 blocks/CU)

    int tid = threadIdx.x;
    lbad[tid] = 0;
    lbad[tid + 256] = 0;

    int w   = tid >> 6;
    int l   = tid & 63;
    int B   = blockIdx.x;
    int zg  = B & 7;
    int yt  = (B >> 3) & 15;
    int zl  = B >> 7;                 // 0..7 slowest
    int z   = zg * 8 + zl;
    int y   = yt * 4 + w;             // wave-uniform

    int lr = l & 15;
    int lg = l >> 4;

    unsigned short* wsh = &smem[w * 4096];    // this wave's private region

    // per-lane LDS read offsets for shifted fragments: dxs=0 -> dx=-1, dxs=1 -> dx=+1
    int loff[4][2]; bool lok[4][2];
    #pragma unroll
    for (int vt = 0; vt < 4; ++vt) {
        #pragma unroll
        for (int dxs = 0; dxs < 2; ++dxs) {
            int v = vt * 16 + lr + (dxs ? 1 : -1);
            lok[vt][dxs] = (unsigned)v < 64u;
            int vc = v < 0 ? 0 : (v > 63 ? 63 : v);
            loff[vt][dxs] = (vc >> 4) * 1024 + lg * 128 + (vc & 15) * 8;
        }
    }

    const short8_t zero8 = (short8_t)0;
    float4_t acc[4][2];
    #pragma unroll
    for (int a = 0; a < 4; ++a)
        #pragma unroll
        for (int b = 0; b < 2; ++b) acc[a][b] = (float4_t)0.f;

    #pragma unroll 1
    for (int dzi = 0; dzi < 3; ++dzi) {
        int nz = z + dzi - 1;
        if ((unsigned)nz >= 64u) continue;            // wave-uniform
        #pragma unroll 1
        for (int dyi = 0; dyi < 3; ++dyi) {
            int ny = y + dyi - 1;
            if ((unsigned)ny >= 64u) continue;        // wave-uniform
            const unsigned short* ph = h1hi + (size_t)(nz * 64 + ny) * 4096;

            // ---- stage the dx=0 row: global -> regs -> wave-private LDS ----
            short8_t ar[4][2];
            #pragma unroll
            for (int vt = 0; vt < 4; ++vt) {
                #pragma unroll
                for (int s = 0; s < 2; ++s)
                    ar[vt][s] = *reinterpret_cast<const short8_t*>(ph + vt * 1024 + s * 512 + l * 8);
            }
            #pragma unroll
            for (int vt = 0; vt < 4; ++vt) {
                #pragma unroll
                for (int s = 0; s < 2; ++s)
                    *reinterpret_cast<short8_t*>(wsh + vt * 1024 + s * 512 + l * 8) = ar[vt][s];
            }
            // same-wave write->read ordered by lgkmcnt (no barrier needed)

            #pragma unroll
            for (int dxm = 0; dxm < 3; ++dxm) {       // compile-time (rule #20)
                int nb = dzi * 9 + dyi * 3 + dxm;
                const unsigned short* bt = bfr + nb * 2048 + l * 8;
                #pragma unroll
                for (int s = 0; s < 2; ++s) {
                    const unsigned short* bs = bt + s * 1024;
                    short8_t bh0 = *reinterpret_cast<const short8_t*>(bs);
                    short8_t bh1 = *reinterpret_cast<const short8_t*>(bs + 512);

                    short8_t a0, a1, a2, a3;
                    if (dxm == 1) {
                        a0 = ar[0][s]; a1 = ar[1][s]; a2 = ar[2][s]; a3 = ar[3][s];
                    } else {
                        int dxs = (dxm == 2) ? 1 : 0;
                        a0 = lok[0][dxs] ? *reinterpret_cast<const short8_t*>(wsh + loff[0][dxs] + s * 512) : zero8;
                        a1 = lok[1][dxs] ? *reinterpret_cast<const short8_t*>(wsh + loff[1][dxs] + s * 512) : zero8;
                        a2 = lok[2][dxs] ? *reinterpret_cast<const short8_t*>(wsh + loff[2][dxs] + s * 512) : zero8;
                        a3 = lok[3][dxs] ? *reinterpret_cast<const short8_t*>(wsh + loff[3][dxs] + s * 512) : zero8;
                    }

                    acc[0][0] = __builtin_amdgcn_mfma_f32_16x16x32_bf16(a0, bh0, acc[0][0], 0, 0, 0);
                    acc[0][1] = __builtin_amdgcn_mfma_f32_16x16x32_bf16(a0, bh1, acc[0][1], 0, 0, 0);
                    acc[1][0] = __builtin_amdgcn_mfma_f32_16x16x32_bf16(a1, bh0, acc[1][0], 0, 0, 0);
                    acc[1][1] = __builtin_amdgcn_mfma_f32_16x16x32_bf16(a1, bh1, acc[1][1], 0, 0, 0);
                    acc[2][0] = __builtin_amdgcn_mfma_f32_16x16x32_bf16(a2, bh0, acc[2][0], 0, 0, 0);
                    acc[2][1] = __builtin_amdgcn_mfma_f32_16x16x32_bf16(a2, bh1, acc[2][1], 0, 0, 0);
                    acc[3][0] = __builtin_amdgcn_mfma_f32_16x16x32_bf16(a3, bh0, acc[3][0], 0, 0, 0);
                    acc[3][1] = __builtin_amdgcn_mfma_f32_16x16x32_bf16(a3, bh1, acc[3][1], 0, 0, 0);
                }
            }
        }
    }

    // ---- bias + relu -> per-wave pf region (bf16, stride 40; region private to this wave) ----
    #pragma unroll
    for (int vt = 0; vt < 4; ++vt) {
        #pragma unroll
        for (int t = 0; t < 2; ++t) {
            float bias = b2[t * 16 + lr];
            #pragma unroll
            for (int r = 0; r < 4; ++r) {
                int vl = vt * 16 + lg * 4 + r;            // voxel within this wave's row
                wsh[vl * 40 + t * 16 + lr] = f32_to_bf16_rne(fmaxf(acc[vt][t][r] + bias, 0.f));
            }
        }
    }
    __syncthreads();   // publishes lbad zero-init (pf stays wave-private)

    // ---- per-thread epilogue: voxel = (z, y of own wave, x = lane) ----
    int ex = tid & 63, ey = yt * 4 + (tid >> 6);
    int vox = (z * 64 + ey) * 64 + ex;

    float f[32];
    #pragma unroll
    for (int q = 0; q < 4; ++q) {
        short8_t v8 = *reinterpret_cast<const short8_t*>(&wsh[(tid & 63) * 40 + q * 8]);
        #pragma unroll
        for (int kk = 0; kk < 8; ++kk) f[q*8+kk] = bf16_to_f32((unsigned short)v8[kk]);
    }

    // semantic head + argmax (wave-uniform weight indices -> s_load; strict > = first occurrence)
    float lbuf[20];
    float best = -1e30f; int am = 0;
    #pragma unroll
    for (int cc = 0; cc < NCLS; ++cc) {
        float a = sem_b[cc];
        #pragma unroll
        for (int q = 0; q < 32; ++q) a = fmaf(f[q], sem_w[cc * 32 + q], a);
        lbuf[cc] = a;
        if (a > best) { best = a; am = cc; }
    }
    #pragma unroll
    for (int q5 = 0; q5 < 5; ++q5)
        *reinterpret_cast<float4*>(out_logits + (size_t)vox * NCLS + q5 * 4) =
            make_float4(lbuf[q5*4], lbuf[q5*4+1], lbuf[q5*4+2], lbuf[q5*4+3]);

    // offset head
    float off[3];
    #pragma unroll
    for (int k3 = 0; k3 < 3; ++k3) {
        float a = off_b[k3];
        #pragma unroll
        for (int q = 0; q < 32; ++q) a = fmaf(f[q], off_w[k3 * 32 + q], a);
        out_off[(size_t)vox * 3 + k3] = a;
        off[k3] = a;
    }

    float px = points[(size_t)vox * 3 + 0] + off[0];
    float py = points[(size_t)vox * 3 + 1] + off[1];
    float pz = points[(size_t)vox * 3 + 2] + off[2];
    float c  = px*px + py*py + pz*pz;
    float mx = -2.f*px, my = -2.f*py, mz = -2.f*pz;

    // seed scan: 4 interleaved chains (ILP on the min dependency), s_load seeds
    float bd0 = 1e30f, bd1 = 1e30f, bd2 = 1e30f, bd3 = 1e30f;
    int   bj0 = 0,     bj1 = 0,     bj2 = 0,     bj3 = 0;
    #pragma unroll 2
    for (int j = 0; j < NSEED; j += 4) {
        float4 s0 = *reinterpret_cast<const float4*>(seedtab + (j + 0) * 4);
        float4 s1 = *reinterpret_cast<const float4*>(seedtab + (j + 1) * 4);
        float4 s2 = *reinterpret_cast<const float4*>(seedtab + (j + 2) * 4);
        float4 s3 = *reinterpret_cast<const float4*>(seedtab + (j + 3) * 4);
        float d0 = fmaf(mx, s0.x, fmaf(my, s0.y, fmaf(mz, s0.z, c + s0.w)));
        float d1 = fmaf(mx, s1.x, fmaf(my, s1.y, fmaf(mz, s1.z, c + s1.w)));
        float d2 = fmaf(mx, s2.x, fmaf(my, s2.y, fmaf(mz, s2.z, c + s2.w)));
        float d3 = fmaf(mx, s3.x, fmaf(my, s3.y, fmaf(mz, s3.z, c + s3.w)));
        if (d0 < bd0) { bd0 = d0; bj0 = j; }          // strict < per chain
        if (d1 < bd1) { bd1 = d1; bj1 = j + 1; }
        if (d2 < bd2) { bd2 = d2; bj2 = j + 2; }
        if (d3 < bd3) { bd3 = d3; bj3 = j + 3; }
    }
    // merge with index tie-break -> global first occurrence
    bool p01 = (bd0 < bd1) || (bd0 == bd1 && bj0 < bj1);
    float bdA = p01 ? bd0 : bd1; int bjA = p01 ? bj0 : bj1;
    bool p23 = (bd2 < bd3) || (bd2 == bd3 && bj2 < bj3);
    float bdB = p23 ? bd2 : bd3; int bjB = p23 ? bj2 : bj3;
    bool pAB = (bdA < bdB) || (bdA == bdB && bjA < bjB);
    float bd = pAB ? bdA : bdB; int bj = pAB ? bjA : bjB;

    bool valid = sqrtf(fmaxf(bd, 0.f)) < 1.5f;

    int slab = slabtab[bj];
    if (valid && am != slab) atomicOr(&lbad[bj], 1);   // LDS atomic only
    iv_out[vox] = valid ? bj : -1;

    __syncthreads();
    // compact 512 flags -> 16 bitmap words; plain global stores (no atomics)
    if (tid < 16) {
        unsigned wd = 0;
        #pragma unroll
        for (int i = 0; i < 32; ++i)
            wd |= (lbad[tid * 32 + i] ? 1u : 0u) << i;
        bitmapT[tid * 1024 + B] = wd;
    }
}

// ------- reduce per-block bitmaps -> badw[16] -------
__global__ __launch_bounds__(256) void reduce_bad(const unsigned* __restrict__ bitmapT,
                                                  unsigned* __restrict__ badw) {
    __shared__ unsigned red[256];
    int w = blockIdx.x;      // word 0..15
    int tid = threadIdx.x;
    const unsigned* src = bitmapT + w * 1024;
    unsigned v = src[tid] | src[tid + 256] | src[tid + 512] | src[tid + 768];
    red[tid] = v;
    __syncthreads();
    #pragma unroll
    for (int s = 128; s > 0; s >>= 1) {
        if (tid < s) red[tid] |= red[tid + s];
        __syncthreads();
    }
    if (tid == 0) badw[w] = red[0];
}

// ---------------- finalize pseudo labels (bitmap test) ----------------
__global__ void finalize_kernel(const int* __restrict__ iv,
                                const unsigned* __restrict__ badw,
                                float* __restrict__ pl) {
    int t = blockIdx.x * 256 + threadIdx.x;
    if (t >= NVOX) return;
    int v = iv[t];
    float r = -1.0f;
    if (v >= 0 && !((badw[v >> 5] >> (v & 31)) & 1u)) r = (float)v;
    pl[t] = r;
}

extern "C" void kernel_launch(void* const* d_in, const int* in_sizes, int n_in,
                              void* d_out, int out_size, void* d_ws, size_t ws_size,
                              hipStream_t stream) {
    const float* points   = (const float*)d_in[0];
    const float* features = (const float*)d_in[1];
    const float* ann      = (const float*)d_in[2];
    const float* w1       = (const float*)d_in[3];
    const float* b1       = (const float*)d_in[4];
    const float* w2       = (const float*)d_in[5];
    const float* b2       = (const float*)d_in[6];
    const float* sem_w    = (const float*)d_in[7];
    const float* sem_b    = (const float*)d_in[8];
    const float* off_w    = (const float*)d_in[9];
    const float* off_b    = (const float*)d_in[10];

    float* out        = (float*)d_out;
    float* out_logits = out;
    float* out_off    = out + (size_t)NVOX * NCLS;   // N*20
    float* out_pl     = out + (size_t)NVOX * 23;     // N*23

    // workspace layout (bytes)
    char*  ws  = (char*)d_ws;
    float*          w1t     = (float*)         (ws);             //    41472 B
    unsigned*       badw    = (unsigned*)      (ws + 41472);     //       64 B
    unsigned short* bfr     = (unsigned short*)(ws + 43520);     //   110592 B (hi only)
    int*            iv      = (int*)           (ws + 264704);    //  1048576 B
    float*          seedtab = (float*)         (ws + 1313280);   //     8192 B
    int*            slabtab = (int*)           (ws + 1321472);   //     2048 B
    unsigned*       bitmapT = (unsigned*)      (ws + 1323520);   //    65536 B
    unsigned short* h1hi    = (unsigned short*)(ws + 34867712);  // 33554432 B

    transpose_w1<<<43, 256, 0, stream>>>(w1, w1t, ann, seedtab, slabtab);
    build_bfrags<<<27, 256, 0, stream>>>(w2, bfr);
    conv1_kernel<<<1024, 256, 0, stream>>>(features, w1t, b1, h1hi);
    conv2_fused_kernel<<<1024, 256, 0, stream>>>(h1hi, bfr, b2, seedtab, slabtab,
        points, sem_w, sem_b, off_w, off_b, out_logits, out_off, iv, bitmapT);
    reduce_bad<<<16, 256, 0, stream>>>(bitmapT, badw);
    finalize_kernel<<<1024, 256, 0, stream>>>(iv, badw, out_pl);
}

// Round 18
// 169.006 us; speedup vs baseline: 10.2565x; 1.0621x over previous
//
#include <hip/hip_runtime.h>

#define GRID 64
#define NVOX (GRID*GRID*GRID)
#define NCLS 20
#define NSEED 512

typedef __attribute__((ext_vector_type(8))) short short8_t;
typedef __attribute__((ext_vector_type(4))) float float4_t;

__device__ __forceinline__ unsigned short f32_to_bf16_rne(float f) {
    unsigned int x = __float_as_uint(f);
    unsigned int r = (x + 0x7fffu + ((x >> 16) & 1u)) >> 16;
    return (unsigned short)r;
}
__device__ __forceinline__ float bf16_to_f32(unsigned short u) {
    return __uint_as_float(((unsigned int)u) << 16);
}

// ------- w1 transpose + seed table prep -------
__global__ void transpose_w1(const float* __restrict__ w1, float* __restrict__ w1t,
                             const float* __restrict__ ann, float* __restrict__ seedtab,
                             int* __restrict__ slabtab) {
    int t = blockIdx.x * 256 + threadIdx.x;
    if (t < 27 * 6 * 64) {
        int oc = t & 63;
        int r  = t >> 6;            // nb*6 + ci
        int nb = r / 6, ci = r % 6;
        w1t[t] = w1[oc * 162 + ci * 27 + nb];
        return;
    }
    int i = t - 27 * 6 * 64;
    if (i < NSEED) {
        float a0 = ann[i*4+0], a1 = ann[i*4+1], a2 = ann[i*4+2];
        *reinterpret_cast<float4*>(seedtab + i * 4) =
            make_float4(a0, a1, a2, a0*a0 + a1*a1 + a2*a2);
        slabtab[i] = (int)ann[i*4+3];
    }
}

// ------- build conv2 weight MFMA fragments (bf16 hi only), 108 frags x 1KB -------
// frag f = (nb*2+s)*2+t ; lane l elem j: B[ci=s*32+(l>>4)*8+j][oc=t*16+(l&15)]
__global__ void build_bfrags(const float* __restrict__ w2, unsigned short* __restrict__ bfr) {
    int t = blockIdx.x * 256 + threadIdx.x;      // over 108*64
    if (t >= 108 * 64) return;
    int l  = t & 63;
    int f  = t >> 6;
    int tt = f & 1;
    int s  = (f >> 1) & 1;
    int nb = f >> 2;
    int lr = l & 15, lg = l >> 4;
    int oc = tt * 16 + lr;
    short8_t out;
    #pragma unroll
    for (int j = 0; j < 8; ++j) {
        int ci = s * 32 + lg * 8 + j;
        out[j] = (short)f32_to_bf16_rne(w2[oc * 1728 + ci * 27 + nb]);
    }
    *reinterpret_cast<short8_t*>(bfr + f * 512 + l * 8) = out;
}

// ------- conv1 (6->64): Zd=4, oc=16, all-tap LDS weights; 9-tap FULL UNROLL (masked) -------
// h1 frag layout per (z,y) plane (4096 elems): [xt(4)][s(2)][cc(4)][xl(16)][8ci]
__global__ __launch_bounds__(256, 4) void conv1_kernel(
    const float* __restrict__ feat,   // [6][NVOX]
    const float* __restrict__ w1t,    // [(nb*6+ci)][64]
    const float* __restrict__ b1,
    unsigned short* __restrict__ h1hi)
{
    __shared__ float lw[27 * 6 * 16]; // 10368 B

    int tid = threadIdx.x;
    int B = blockIdx.x;
    int zg = B & 7;
    int k  = B >> 3;
    int og = k & 3;                   // oc group of 16
    int zt = (k >> 2) & 1;
    int yt = (k >> 3) & 15;

    for (int t = tid; t < 27 * 6 * 16; t += 256)
        lw[t] = w1t[(t >> 4) * 64 + og * 16 + (t & 15)];
    __syncthreads();                  // the only barrier

    int x  = tid & 63;
    int y  = yt * 4 + (tid >> 6);     // wave-uniform
    int z0 = zg * 8 + zt * 4;

    float acc[4][16];
    #pragma unroll
    for (int r = 0; r < 4; ++r)
        #pragma unroll
        for (int o = 0; o < 16; ++o) acc[r][o] = 0.f;

    int zoffv[6]; float mzv[6];
    #pragma unroll
    for (int rz = 0; rz < 6; ++rz) {
        int gz = z0 - 1 + rz;
        int cz = gz < 0 ? 0 : (gz > 63 ? 63 : gz);
        zoffv[rz] = cz * 4096;
        mzv[rz] = ((unsigned)gz < 64u) ? 1.f : 0.f;
    }

    // FULL unroll: masked edges (no branches) -> compiler pipelines loads across taps
    #pragma unroll
    for (int dydx = 0; dydx < 9; ++dydx) {
        int dy = dydx / 3 - 1;
        int dx = dydx % 3 - 1;
        int ny = y + dy;
        float my = ((unsigned)ny < 64u) ? 1.f : 0.f;
        int cy = ny < 0 ? 0 : (ny > 63 ? 63 : ny);
        int nx = x + dx;
        float mxv = ((unsigned)nx < 64u) ? 1.f : 0.f;
        int cx = nx < 0 ? 0 : (nx > 63 ? 63 : nx);
        int rowvox = cy * 64 + cx;
        float mxy = mxv * my;

        float cm[6]; int voff[6];
        #pragma unroll
        for (int rz = 0; rz < 6; ++rz) { cm[rz] = mxy * mzv[rz]; voff[rz] = zoffv[rz] + rowvox; }

        #pragma unroll
        for (int cb = 0; cb < 2; ++cb) {
            float v[3][6];
            #pragma unroll
            for (int ci = 0; ci < 3; ++ci) {
                const float* plane = feat + (size_t)(cb * 3 + ci) * NVOX;
                #pragma unroll
                for (int rz = 0; rz < 6; ++rz) v[ci][rz] = plane[voff[rz]];
            }
            #pragma unroll
            for (int ci = 0; ci < 3; ++ci)
                #pragma unroll
                for (int rz = 0; rz < 6; ++rz) v[ci][rz] *= cm[rz];
            #pragma unroll
            for (int ci = 0; ci < 3; ++ci) {
                #pragma unroll
                for (int dzi = 0; dzi < 3; ++dzi) {
                    const float4* wp = reinterpret_cast<const float4*>(
                        &lw[(((dzi * 9 + dydx) * 6) + cb * 3 + ci) * 16]);
                    float4 w0 = wp[0], w1 = wp[1], w2 = wp[2], w3 = wp[3];
                    #pragma unroll
                    for (int r = 0; r < 4; ++r) {
                        float a = v[ci][r + dzi];
                        acc[r][0]  = fmaf(a, w0.x, acc[r][0]);
                        acc[r][1]  = fmaf(a, w0.y, acc[r][1]);
                        acc[r][2]  = fmaf(a, w0.z, acc[r][2]);
                        acc[r][3]  = fmaf(a, w0.w, acc[r][3]);
                        acc[r][4]  = fmaf(a, w1.x, acc[r][4]);
                        acc[r][5]  = fmaf(a, w1.y, acc[r][5]);
                        acc[r][6]  = fmaf(a, w1.z, acc[r][6]);
                        acc[r][7]  = fmaf(a, w1.w, acc[r][7]);
                        acc[r][8]  = fmaf(a, w2.x, acc[r][8]);
                        acc[r][9]  = fmaf(a, w2.y, acc[r][9]);
                        acc[r][10] = fmaf(a, w2.z, acc[r][10]);
                        acc[r][11] = fmaf(a, w2.w, acc[r][11]);
                        acc[r][12] = fmaf(a, w3.x, acc[r][12]);
                        acc[r][13] = fmaf(a, w3.y, acc[r][13]);
                        acc[r][14] = fmaf(a, w3.z, acc[r][14]);
                        acc[r][15] = fmaf(a, w3.w, acc[r][15]);
                    }
                }
            }
        }
    }

    float bias[16];
    #pragma unroll
    for (int o = 0; o < 16; ++o) bias[o] = b1[og * 16 + o];

    // frag-layout store (hi only): s = og>>1; cc = (og*2 + (o>>3)) & 3
    int s1 = og >> 1;
    int c0 = (og * 2) & 3;
    int c1 = (og * 2 + 1) & 3;
    #pragma unroll
    for (int zl = 0; zl < 4; ++zl) {
        size_t zy = ((size_t)((z0 + zl) * 64 + y)) * 4096;
        size_t base  = zy + (size_t)(x >> 4) * 1024 + (size_t)s1 * 512 + (size_t)(x & 15) * 8;
        short8_t hi0, hi1;
        #pragma unroll
        for (int o = 0; o < 8; ++o)
            hi0[o] = (short)f32_to_bf16_rne(fmaxf(acc[zl][o] + bias[o], 0.f));
        #pragma unroll
        for (int o = 8; o < 16; ++o)
            hi1[o - 8] = (short)f32_to_bf16_rne(fmaxf(acc[zl][o] + bias[o], 0.f));
        *reinterpret_cast<short8_t*>(h1hi + base + c0 * 128) = hi0;
        *reinterpret_cast<short8_t*>(h1hi + base + c1 * 128) = hi1;
    }
}

// ------- conv2 (64->32) MFMA (B=bf16) + fused epilogue; 9-row FULL UNROLL (masked) -------
// grid 1024 = 8 zg (XCD, fastest) x 16 yt x 8 zl (slowest)
__global__ __launch_bounds__(256, 4) void conv2_fused_kernel(
    const unsigned short* __restrict__ h1hi, // frag layout
    const unsigned short* __restrict__ bfr,  // [27][2s][2t][64][8] bf16 (hi only)
    const float* __restrict__ b2,
    const float* __restrict__ seedtab,       // [512][4] (x,y,z,|s|^2)
    const int* __restrict__ slabtab,         // [512]
    const float* __restrict__ points,
    const float* __restrict__ sem_w, const float* __restrict__ sem_b,
    const float* __restrict__ off_w, const float* __restrict__ off_b,
    float* __restrict__ out_logits,
    float* __restrict__ out_off,
    int* __restrict__ iv_out,
    unsigned* __restrict__ bitmapT)          // [16 words][1024 blocks]
{
    __shared__ unsigned short smem[4 * 4096]; // per-wave A-row staging; reused as pf store. 32 KB
    __shared__ int lbad[NSEED];               // 2048 B  (total 34 KB -> 4 blocks/CU)

    int tid = threadIdx.x;
    lbad[tid] = 0;
    lbad[tid + 256] = 0;

    int w   = tid >> 6;
    int l   = tid & 63;
    int B   = blockIdx.x;
    int zg  = B & 7;
    int yt  = (B >> 3) & 15;
    int zl  = B >> 7;                 // 0..7 slowest
    int z   = zg * 8 + zl;
    int y   = yt * 4 + w;             // wave-uniform

    int lr = l & 15;
    int lg = l >> 4;

    unsigned short* wsh = &smem[w * 4096];    // this wave's private region

    // per-lane LDS read offsets for shifted fragments: dxs=0 -> dx=-1, dxs=1 -> dx=+1
    int loff[4][2]; bool lok[4][2];
    #pragma unroll
    for (int vt = 0; vt < 4; ++vt) {
        #pragma unroll
        for (int dxs = 0; dxs < 2; ++dxs) {
            int v = vt * 16 + lr + (dxs ? 1 : -1);
            lok[vt][dxs] = (unsigned)v < 64u;
            int vc = v < 0 ? 0 : (v > 63 ? 63 : v);
            loff[vt][dxs] = (vc >> 4) * 1024 + lg * 128 + (vc & 15) * 8;
        }
    }

    // row clamps + validity (block/wave-uniform)
    int czv[3]; bool zokv[3];
    #pragma unroll
    for (int dzi = 0; dzi < 3; ++dzi) {
        int nz = z + dzi - 1;
        zokv[dzi] = (unsigned)nz < 64u;
        czv[dzi] = nz < 0 ? 0 : (nz > 63 ? 63 : nz);
    }
    int cyv[3]; bool yokv[3];
    #pragma unroll
    for (int dyi = 0; dyi < 3; ++dyi) {
        int ny = y + dyi - 1;
        yokv[dyi] = (unsigned)ny < 64u;
        cyv[dyi] = ny < 0 ? 0 : (ny > 63 ? 63 : ny);
    }

    const short8_t zero8 = (short8_t)0;
    float4_t acc[4][2];
    #pragma unroll
    for (int a = 0; a < 4; ++a)
        #pragma unroll
        for (int b = 0; b < 2; ++b) acc[a][b] = (float4_t)0.f;

    // FULL unroll of 9 row-pairs: straight-line code, loads masked not skipped ->
    // compiler hoists next row's global loads into current row's MFMA region.
    #pragma unroll
    for (int dzi = 0; dzi < 3; ++dzi) {
        #pragma unroll
        for (int dyi = 0; dyi < 3; ++dyi) {
            bool rv = zokv[dzi] && yokv[dyi];
            const unsigned short* ph = h1hi + (size_t)(czv[dzi] * 64 + cyv[dyi]) * 4096;

            // ---- stage the dx=0 row: global -> regs (masked) -> wave-private LDS ----
            short8_t ar[4][2];
            #pragma unroll
            for (int vt = 0; vt < 4; ++vt) {
                #pragma unroll
                for (int s = 0; s < 2; ++s) {
                    short8_t t8 = *reinterpret_cast<const short8_t*>(ph + vt * 1024 + s * 512 + l * 8);
                    ar[vt][s] = rv ? t8 : zero8;
                }
            }
            #pragma unroll
            for (int vt = 0; vt < 4; ++vt) {
                #pragma unroll
                for (int s = 0; s < 2; ++s)
                    *reinterpret_cast<short8_t*>(wsh + vt * 1024 + s * 512 + l * 8) = ar[vt][s];
            }
            // same-wave write->read ordered by in-order lgkmcnt (no barrier needed)

            #pragma unroll
            for (int dxm = 0; dxm < 3; ++dxm) {       // compile-time (rule #20)
                int nb = dzi * 9 + dyi * 3 + dxm;
                const unsigned short* bt = bfr + nb * 2048 + l * 8;
                #pragma unroll
                for (int s = 0; s < 2; ++s) {
                    const unsigned short* bs = bt + s * 1024;
                    short8_t bh0 = *reinterpret_cast<const short8_t*>(bs);
                    short8_t bh1 = *reinterpret_cast<const short8_t*>(bs + 512);

                    short8_t a0, a1, a2, a3;
                    if (dxm == 1) {
                        a0 = ar[0][s]; a1 = ar[1][s]; a2 = ar[2][s]; a3 = ar[3][s];
                    } else {
                        int dxs = (dxm == 2) ? 1 : 0;
                        a0 = lok[0][dxs] ? *reinterpret_cast<const short8_t*>(wsh + loff[0][dxs] + s * 512) : zero8;
                        a1 = lok[1][dxs] ? *reinterpret_cast<const short8_t*>(wsh + loff[1][dxs] + s * 512) : zero8;
                        a2 = lok[2][dxs] ? *reinterpret_cast<const short8_t*>(wsh + loff[2][dxs] + s * 512) : zero8;
                        a3 = lok[3][dxs] ? *reinterpret_cast<const short8_t*>(wsh + loff[3][dxs] + s * 512) : zero8;
                    }

                    acc[0][0] = __builtin_amdgcn_mfma_f32_16x16x32_bf16(a0, bh0, acc[0][0], 0, 0, 0);
                    acc[0][1] = __builtin_amdgcn_mfma_f32_16x16x32_bf16(a0, bh1, acc[0][1], 0, 0, 0);
                    acc[1][0] = __builtin_amdgcn_mfma_f32_16x16x32_bf16(a1, bh0, acc[1][0], 0, 0, 0);
                    acc[1][1] = __builtin_amdgcn_mfma_f32_16x16x32_bf16(a1, bh1, acc[1][1], 0, 0, 0);
                    acc[2][0] = __builtin_amdgcn_mfma_f32_16x16x32_bf16(a2, bh0, acc[2][0], 0, 0, 0);
                    acc[2][1] = __builtin_amdgcn_mfma_f32_16x16x32_bf16(a2, bh1, acc[2][1], 0, 0, 0);
                    acc[3][0] = __builtin_amdgcn_mfma_f32_16x16x32_bf16(a3, bh0, acc[3][0], 0, 0, 0);
                    acc[3][1] = __builtin_amdgcn_mfma_f32_16x16x32_bf16(a3, bh1, acc[3][1], 0, 0, 0);
                }
            }
        }
    }

    // ---- bias + relu -> per-wave pf region (bf16, stride 40; region private to this wave) ----
    #pragma unroll
    for (int vt = 0; vt < 4; ++vt) {
        #pragma unroll
        for (int t = 0; t < 2; ++t) {
            float bias = b2[t * 16 + lr];
            #pragma unroll
            for (int r = 0; r < 4; ++r) {
                int vl = vt * 16 + lg * 4 + r;            // voxel within this wave's row
                wsh[vl * 40 + t * 16 + lr] = f32_to_bf16_rne(fmaxf(acc[vt][t][r] + bias, 0.f));
            }
        }
    }
    __syncthreads();   // publishes lbad zero-init (pf stays wave-private)

    // ---- per-thread epilogue: voxel = (z, y of own wave, x = lane) ----
    int ex = tid & 63, ey = yt * 4 + (tid >> 6);
    int vox = (z * 64 + ey) * 64 + ex;

    float f[32];
    #pragma unroll
    for (int q = 0; q < 4; ++q) {
        short8_t v8 = *reinterpret_cast<const short8_t*>(&wsh[(tid & 63) * 40 + q * 8]);
        #pragma unroll
        for (int kk = 0; kk < 8; ++kk) f[q*8+kk] = bf16_to_f32((unsigned short)v8[kk]);
    }

    // semantic head + argmax (wave-uniform weight indices -> s_load; strict > = first occurrence)
    float lbuf[20];
    float best = -1e30f; int am = 0;
    #pragma unroll
    for (int cc = 0; cc < NCLS; ++cc) {
        float a = sem_b[cc];
        #pragma unroll
        for (int q = 0; q < 32; ++q) a = fmaf(f[q], sem_w[cc * 32 + q], a);
        lbuf[cc] = a;
        if (a > best) { best = a; am = cc; }
    }
    #pragma unroll
    for (int q5 = 0; q5 < 5; ++q5)
        *reinterpret_cast<float4*>(out_logits + (size_t)vox * NCLS + q5 * 4) =
            make_float4(lbuf[q5*4], lbuf[q5*4+1], lbuf[q5*4+2], lbuf[q5*4+3]);

    // offset head
    float off[3];
    #pragma unroll
    for (int k3 = 0; k3 < 3; ++k3) {
        float a = off_b[k3];
        #pragma unroll
        for (int q = 0; q < 32; ++q) a = fmaf(f[q], off_w[k3 * 32 + q], a);
        out_off[(size_t)vox * 3 + k3] = a;
        off[k3] = a;
    }

    float px = points[(size_t)vox * 3 + 0] + off[0];
    float py = points[(size_t)vox * 3 + 1] + off[1];
    float pz = points[(size_t)vox * 3 + 2] + off[2];
    float c  = px*px + py*py + pz*pz;
    float mx = -2.f*px, my = -2.f*py, mz = -2.f*pz;

    // seed scan: 4 interleaved chains (ILP on the min dependency), s_load seeds
    float bd0 = 1e30f, bd1 = 1e30f, bd2 = 1e30f, bd3 = 1e30f;
    int   bj0 = 0,     bj1 = 0,     bj2 = 0,     bj3 = 0;
    #pragma unroll 2
    for (int j = 0; j < NSEED; j += 4) {
        float4 s0 = *reinterpret_cast<const float4*>(seedtab + (j + 0) * 4);
        float4 s1 = *reinterpret_cast<const float4*>(seedtab + (j + 1) * 4);
        float4 s2 = *reinterpret_cast<const float4*>(seedtab + (j + 2) * 4);
        float4 s3 = *reinterpret_cast<const float4*>(seedtab + (j + 3) * 4);
        float d0 = fmaf(mx, s0.x, fmaf(my, s0.y, fmaf(mz, s0.z, c + s0.w)));
        float d1 = fmaf(mx, s1.x, fmaf(my, s1.y, fmaf(mz, s1.z, c + s1.w)));
        float d2 = fmaf(mx, s2.x, fmaf(my, s2.y, fmaf(mz, s2.z, c + s2.w)));
        float d3 = fmaf(mx, s3.x, fmaf(my, s3.y, fmaf(mz, s3.z, c + s3.w)));
        if (d0 < bd0) { bd0 = d0; bj0 = j; }          // strict < per chain
        if (d1 < bd1) { bd1 = d1; bj1 = j + 1; }
        if (d2 < bd2) { bd2 = d2; bj2 = j + 2; }
        if (d3 < bd3) { bd3 = d3; bj3 = j + 3; }
    }
    // merge with index tie-break -> global first occurrence
    bool p01 = (bd0 < bd1) || (bd0 == bd1 && bj0 < bj1);
    float bdA = p01 ? bd0 : bd1; int bjA = p01 ? bj0 : bj1;
    bool p23 = (bd2 < bd3) || (bd2 == bd3 && bj2 < bj3);
    float bdB = p23 ? bd2 : bd3; int bjB = p23 ? bj2 : bj3;
    bool pAB = (bdA < bdB) || (bdA == bdB && bjA < bjB);
    float bd = pAB ? bdA : bdB; int bj = pAB ? bjA : bjB;

    bool valid = sqrtf(fmaxf(bd, 0.f)) < 1.5f;

    int slab = slabtab[bj];
    if (valid && am != slab) atomicOr(&lbad[bj], 1);   // LDS atomic only
    iv_out[vox] = valid ? bj : -1;

    __syncthreads();
    // compact 512 flags -> 16 bitmap words; plain global stores (no atomics)
    if (tid < 16) {
        unsigned wd = 0;
        #pragma unroll
        for (int i = 0; i < 32; ++i)
            wd |= (lbad[tid * 32 + i] ? 1u : 0u) << i;
        bitmapT[tid * 1024 + B] = wd;
    }
}

// ------- reduce per-block bitmaps -> badw[16] -------
__global__ __launch_bounds__(256) void reduce_bad(const unsigned* __restrict__ bitmapT,
                                                  unsigned* __restrict__ badw) {
    __shared__ unsigned red[256];
    int w = blockIdx.x;      // word 0..15
    int tid = threadIdx.x;
    const unsigned* src = bitmapT + w * 1024;
    unsigned v = src[tid] | src[tid + 256] | src[tid + 512] | src[tid + 768];
    red[tid] = v;
    __syncthreads();
    #pragma unroll
    for (int s = 128; s > 0; s >>= 1) {
        if (tid < s) red[tid] |= red[tid + s];
        __syncthreads();
    }
    if (tid == 0) badw[w] = red[0];
}

// ---------------- finalize pseudo labels (bitmap test) ----------------
__global__ void finalize_kernel(const int* __restrict__ iv,
                                const unsigned* __restrict__ badw,
                                float* __restrict__ pl) {
    int t = blockIdx.x * 256 + threadIdx.x;
    if (t >= NVOX) return;
    int v = iv[t];
    float r = -1.0f;
    if (v >= 0 && !((badw[v >> 5] >> (v & 31)) & 1u)) r = (float)v;
    pl[t] = r;
}

extern "C" void kernel_launch(void* const* d_in, const int* in_sizes, int n_in,
                              void* d_out, int out_size, void* d_ws, size_t ws_size,
                              hipStream_t stream) {
    const float* points   = (const float*)d_in[0];
    const float* features = (const float*)d_in[1];
    const float* ann      = (const float*)d_in[2];
    const float* w1       = (const float*)d_in[3];
    const float* b1       = (const float*)d_in[4];
    const float* w2       = (const float*)d_in[5];
    const float* b2       = (const float*)d_in[6];
    const float* sem_w    = (const float*)d_in[7];
    const float* sem_b    = (const float*)d_in[8];
    const float* off_w    = (const float*)d_in[9];
    const float* off_b    = (const float*)d_in[10];

    float* out        = (float*)d_out;
    float* out_logits = out;
    float* out_off    = out + (size_t)NVOX * NCLS;   // N*20
    float* out_pl     = out + (size_t)NVOX * 23;     // N*23

    // workspace layout (bytes)
    char*  ws  = (char*)d_ws;
    float*          w1t     = (float*)         (ws);             //    41472 B
    unsigned*       badw    = (unsigned*)      (ws + 41472);     //       64 B
    unsigned short* bfr     = (unsigned short*)(ws + 43520);     //   110592 B (hi only)
    int*            iv      = (int*)           (ws + 264704);    //  1048576 B
    float*          seedtab = (float*)         (ws + 1313280);   //     8192 B
    int*            slabtab = (int*)           (ws + 1321472);   //     2048 B
    unsigned*       bitmapT = (unsigned*)      (ws + 1323520);   //    65536 B
    unsigned short* h1hi    = (unsigned short*)(ws + 34867712);  // 33554432 B

    transpose_w1<<<43, 256, 0, stream>>>(w1, w1t, ann, seedtab, slabtab);
    build_bfrags<<<27, 256, 0, stream>>>(w2, bfr);
    conv1_kernel<<<1024, 256, 0, stream>>>(features, w1t, b1, h1hi);
    conv2_fused_kernel<<<1024, 256, 0, stream>>>(h1hi, bfr, b2, seedtab, slabtab,
        points, sem_w, sem_b, off_w, off_b, out_logits, out_off, iv, bitmapT);
    reduce_bad<<<16, 256, 0, stream>>>(bitmapT, badw);
    finalize_kernel<<<1024, 256, 0, stream>>>(iv, badw, out_pl);
}